// Round 6
// baseline (285.450 us; speedup 1.0000x reference)
//
#include <hip/hip_runtime.h>
#include <math.h>

// Problem constants
#define NB   4      // batch
#define CIN  64     // channels everywhere (I=CR=CA=CO=64)
#define HH   48
#define WW   48
#define HW   2304   // 48*48
#define DH   46
#define DW   46
#define DD   2116   // 46*46
#define NHEAD 4
#define HC   16
#define NT   136    // padded d-tiles (2176 = 136*16; 60 zero-pads)
#define QTL  144    // q-tiles (2304 = 144*16)

typedef short  s4 __attribute__((ext_vector_type(4)));
typedef float  f4 __attribute__((ext_vector_type(4)));

// ---------------------------------------------------------------------------
// xin[n,o,p] = sum_c W_in[o,c] * x[n,c,p] + b_in[o]
__global__ __launch_bounds__(256) void k_xin(const float* __restrict__ x,
                                             const float* __restrict__ Win,
                                             const float* __restrict__ bin,
                                             float* __restrict__ xin) {
    int px  = blockIdx.x * 256 + threadIdx.x;
    int n   = blockIdx.y;
    int ocg = blockIdx.z * 4;
    const float* xp = x + (size_t)(n * CIN) * HW + px;
    float a0 = bin[ocg + 0], a1 = bin[ocg + 1], a2 = bin[ocg + 2], a3 = bin[ocg + 3];
    #pragma unroll 8
    for (int ic = 0; ic < CIN; ++ic) {
        float xv = xp[ic * HW];
        a0 += Win[(ocg + 0) * CIN + ic] * xv;
        a1 += Win[(ocg + 1) * CIN + ic] * xv;
        a2 += Win[(ocg + 2) * CIN + ic] * xv;
        a3 += Win[(ocg + 3) * CIN + ic] * xv;
    }
    float* op = xin + (size_t)(n * CIN + ocg) * HW + px;
    op[0] = a0; op[HW] = a1; op[2 * HW] = a2; op[3 * HW] = a3;
}

// ---------------------------------------------------------------------------
// Four 3x3 convs from xin — lane = PIXEL mapping.
// Block: 256 thr = one 16x16 output tile, 16 output channels (ocq).
// Per ic: 9 lane-distributed LDS reads feed 16oc x 9 = 144 FMAs; weight
// indices are wave-uniform -> compiler emits scalar (SGPR) loads, off the
// vector-memory path entirely. grid (9 tiles, 4 n, 16 = cv*4+ocq).
__global__ __launch_bounds__(256) void k_conv(const float* __restrict__ xin,
                                              const float* __restrict__ Wq,
                                              const float* __restrict__ Wk,
                                              const float* __restrict__ Wv,
                                              float* __restrict__ q0, float* __restrict__ k0,
                                              float* __restrict__ v0, float* __restrict__ v2) {
    __shared__ float sx[16][18][18];   // 16 ic x (16+2)^2 halo tile, 20.7 KB
    int cv = blockIdx.z >> 2, ocq = blockIdx.z & 3, oc0 = ocq * 16;
    int n = blockIdx.y;
    int ty = (blockIdx.x / 3) * 16, tx = (blockIdx.x % 3) * 16;
    const float* wb; float* ob; int outw, ioff;
    if (cv == 0)      { wb = Wq;               ob = q0; outw = 48; ioff = -1; }
    else if (cv == 1) { wb = Wk;               ob = k0; outw = 46; ioff = 0;  }
    else if (cv == 2) { wb = Wv;               ob = v0; outw = 46; ioff = 0;  }
    else              { wb = Wv + 2 * CIN * CIN * 9; ob = v2; outw = 46; ioff = 0; }
    int tid = threadIdx.x;
    int px = tid & 15, py = tid >> 4;

    float acc[16];
    #pragma unroll
    for (int oc = 0; oc < 16; ++oc) acc[oc] = 0.f;

    for (int icb = 0; icb < CIN; icb += 16) {
        __syncthreads();
        for (int idx = tid; idx < 5184; idx += 256) {   // 16 ic x 18 x 18
            int ic = idx / 324; int rem = idx - ic * 324;
            int r = rem / 18;   int c = rem - r * 18;
            int gy = ty + r + ioff, gx = tx + c + ioff;
            float v = 0.f;
            if ((unsigned)gy < 48u && (unsigned)gx < 48u)
                v = xin[(size_t)(n * CIN + icb + ic) * HW + gy * WW + gx];
            sx[ic][r][c] = v;
        }
        __syncthreads();
        #pragma unroll 2
        for (int ic = 0; ic < 16; ++ic) {
            float xv[9];
            #pragma unroll
            for (int dy = 0; dy < 3; ++dy)
                #pragma unroll
                for (int dx = 0; dx < 3; ++dx)
                    xv[dy * 3 + dx] = sx[ic][py + dy][px + dx];  // lane-distributed
            const float* wic = wb + ((size_t)oc0 * CIN + icb + ic) * 9;
            #pragma unroll
            for (int oc = 0; oc < 16; ++oc) {
                const float* w = wic + (size_t)oc * CIN * 9;     // wave-uniform -> s_load
                acc[oc] += w[0] * xv[0] + w[1] * xv[1] + w[2] * xv[2]
                         + w[3] * xv[3] + w[4] * xv[4] + w[5] * xv[5]
                         + w[6] * xv[6] + w[7] * xv[7] + w[8] * xv[8];
            }
        }
    }

    int oy = ty + py, ox = tx + px;
    if (oy < outw && ox < outw) {
        int outsz = outw * outw;
        float* op = ob + (size_t)(n * CIN + oc0) * outsz + oy * outw + ox;
        #pragma unroll
        for (int oc = 0; oc < 16; ++oc)
            op[(size_t)oc * outsz] = acc[oc];                    // coalesced per oc
    }
}

// ---------------------------------------------------------------------------
// Convert q0/k0/v0 fp32 -> MFMA-tiled bf16x2 (hi/lo planes, truncation split).
// Qb tile [q16][c16] (B-frag for QK);  Kb tile [d16][c16] (A-frag for QK);
// Vb tile [c16][d16] (A-frag for PV).  K/V padded with zeros to 136 d-tiles.
// grid (144, 16 nh), block 256.
__global__ __launch_bounds__(256) void k_cvt(const float* __restrict__ q0,
                                             const float* __restrict__ k0,
                                             const float* __restrict__ v0,
                                             unsigned short* __restrict__ Qb,
                                             unsigned short* __restrict__ Kb,
                                             unsigned short* __restrict__ Vb) {
    __shared__ float sm[272];            // 16x16 transpose pad 17
    int bx = blockIdx.x, nh = blockIdx.y;
    int n = nh >> 2, h = nh & 3;
    int t = threadIdx.x;
    // ---- Q tile (qt = bx), transpose [c][q] -> [q][c]
    {
        int c = t >> 4, q = t & 15;
        float val = q0[(size_t)(n * CIN + h * HC + c) * HW + bx * 16 + q];
        sm[c * 17 + q] = val;
        __syncthreads();
        int q2 = t >> 4, c2 = t & 15;
        float v = sm[c2 * 17 + q2];
        unsigned u = __builtin_bit_cast(unsigned, v);
        unsigned short* dst = Qb + (size_t)(nh * QTL + bx) * 512;
        dst[t] = (unsigned short)(u >> 16);
        float lo = v - __builtin_bit_cast(float, u & 0xffff0000u);
        dst[256 + t] = (unsigned short)(__builtin_bit_cast(unsigned, lo) >> 16);
    }
    if (bx < NT) {
        // ---- K tile (dt = bx), transpose [c][d] -> [d][c], zero-pad
        __syncthreads();
        int c = t >> 4, d = t & 15;
        int dgl = bx * 16 + d;
        float kv = (dgl < DD) ? k0[(size_t)(n * CIN + h * HC + c) * DD + dgl] : 0.f;
        sm[c * 17 + d] = kv;
        __syncthreads();
        {
            int d2 = t >> 4, c2 = t & 15;
            float v = sm[c2 * 17 + d2];
            unsigned u = __builtin_bit_cast(unsigned, v);
            unsigned short* dst = Kb + (size_t)(nh * NT + bx) * 512;
            dst[t] = (unsigned short)(u >> 16);
            float lo = v - __builtin_bit_cast(float, u & 0xffff0000u);
            dst[256 + t] = (unsigned short)(__builtin_bit_cast(unsigned, lo) >> 16);
        }
        // ---- V tile: already [c][d] orientation, direct
        {
            float vv = (dgl < DD) ? v0[(size_t)(n * CIN + h * HC + c) * DD + dgl] : 0.f;
            unsigned u = __builtin_bit_cast(unsigned, vv);
            unsigned short* dst = Vb + (size_t)(nh * NT + bx) * 512;
            dst[t] = (unsigned short)(u >> 16);
            float lo = vv - __builtin_bit_cast(float, u & 0xffff0000u);
            dst[256 + t] = (unsigned short)(__builtin_bit_cast(unsigned, lo) >> 16);
        }
    }
}

// ---------------------------------------------------------------------------
// MFMA attention. Wave = (64-q strip, 1/8 of D = 17 d-tiles). Per d-tile,
// per q-tile: S^T[d][q] = KhiQhi+KloQhi+KhiQlo (3 mfma 16x16x16 bf16, exact to
// ~2^-16); exp in-register (no-max softmax, scores provably small); split P
// to bf16x2 per-lane (C/D layout == next B layout for K=16 mfma — no data
// movement); O[c][q] += VhiPh+VloPh+VhiPl. K/V frags prefetched 1 tile ahead
// from L2. Block = 4 waves combine partials via LDS; k_acomb finishes.
// Zero-padded d (60 of them) contribute exp(0)=1 to l -> fixed by -60 later.
// grid (72 = 36 strips x 2 hb, 16 nh), block 256.
__global__ __launch_bounds__(256) void k_mattn(const unsigned short* __restrict__ Qb,
                                               const unsigned short* __restrict__ Kb,
                                               const unsigned short* __restrict__ Vb,
                                               float* __restrict__ part) {
    __shared__ float sO[4][4][256];
    __shared__ float sl[4][4][64];
    int strip = blockIdx.x >> 1, hb = blockIdx.x & 1, nh = blockIdx.y;
    int lane = threadIdx.x & 63, wv = threadIdx.x >> 6;
    int ds = hb * 4 + wv;
    int q16 = lane & 15, quad = lane >> 4;
    int foff = q16 * 16 + quad * 4;          // fragment offset within 256-elem plane

    s4 qh[4], ql[4];
    #pragma unroll
    for (int j = 0; j < 4; ++j) {
        const unsigned short* Qp = Qb + (size_t)(nh * QTL + strip * 4 + j) * 512 + foff;
        qh[j] = *(const s4*)(Qp);
        ql[j] = *(const s4*)(Qp + 256);
    }
    f4 O[4];
    float l[4];
    #pragma unroll
    for (int j = 0; j < 4; ++j) { O[j] = (f4){0.f, 0.f, 0.f, 0.f}; l[j] = 0.f; }

    const unsigned short* Kp = Kb + (size_t)(nh * NT + ds * 17) * 512 + foff;
    const unsigned short* Vp = Vb + (size_t)(nh * NT + ds * 17) * 512 + foff;
    s4 khi = *(const s4*)(Kp);
    s4 klo = *(const s4*)(Kp + 256);
    s4 vhi = *(const s4*)(Vp);
    s4 vlo = *(const s4*)(Vp + 256);

    for (int it = 0; it < 17; ++it) {
        int nxt = (it < 16) ? (it + 1) * 512 : 0;    // last prefetch discarded
        s4 nkhi = *(const s4*)(Kp + nxt);
        s4 nklo = *(const s4*)(Kp + nxt + 256);
        s4 nvhi = *(const s4*)(Vp + nxt);
        s4 nvlo = *(const s4*)(Vp + nxt + 256);

        #pragma unroll
        for (int j = 0; j < 4; ++j) {
            f4 c1 = (f4){0.f, 0.f, 0.f, 0.f};
            c1 = __builtin_amdgcn_mfma_f32_16x16x16bf16_1k(khi, qh[j], c1, 0, 0, 0);
            c1 = __builtin_amdgcn_mfma_f32_16x16x16bf16_1k(klo, qh[j], c1, 0, 0, 0);
            c1 = __builtin_amdgcn_mfma_f32_16x16x16bf16_1k(khi, ql[j], c1, 0, 0, 0);
            float p0 = __expf(c1.x), p1 = __expf(c1.y);
            float p2 = __expf(c1.z), p3 = __expf(c1.w);
            l[j] += (p0 + p1) + (p2 + p3);
            unsigned u0 = __builtin_bit_cast(unsigned, p0);
            unsigned u1 = __builtin_bit_cast(unsigned, p1);
            unsigned u2 = __builtin_bit_cast(unsigned, p2);
            unsigned u3 = __builtin_bit_cast(unsigned, p3);
            s4 ph;
            ph.x = (short)(u0 >> 16); ph.y = (short)(u1 >> 16);
            ph.z = (short)(u2 >> 16); ph.w = (short)(u3 >> 16);
            float r0 = p0 - __builtin_bit_cast(float, u0 & 0xffff0000u);
            float r1 = p1 - __builtin_bit_cast(float, u1 & 0xffff0000u);
            float r2 = p2 - __builtin_bit_cast(float, u2 & 0xffff0000u);
            float r3 = p3 - __builtin_bit_cast(float, u3 & 0xffff0000u);
            s4 pl;
            pl.x = (short)(__builtin_bit_cast(unsigned, r0) >> 16);
            pl.y = (short)(__builtin_bit_cast(unsigned, r1) >> 16);
            pl.z = (short)(__builtin_bit_cast(unsigned, r2) >> 16);
            pl.w = (short)(__builtin_bit_cast(unsigned, r3) >> 16);
            O[j] = __builtin_amdgcn_mfma_f32_16x16x16bf16_1k(vhi, ph, O[j], 0, 0, 0);
            O[j] = __builtin_amdgcn_mfma_f32_16x16x16bf16_1k(vlo, ph, O[j], 0, 0, 0);
            O[j] = __builtin_amdgcn_mfma_f32_16x16x16bf16_1k(vhi, pl, O[j], 0, 0, 0);
        }
        khi = nkhi; klo = nklo; vhi = nvhi; vlo = nvlo;
    }

    // combine the block's 4 wave-partials through LDS
    #pragma unroll
    for (int j = 0; j < 4; ++j) {
        sO[wv][j][(quad * 4 + 0) * 16 + q16] = O[j].x;
        sO[wv][j][(quad * 4 + 1) * 16 + q16] = O[j].y;
        sO[wv][j][(quad * 4 + 2) * 16 + q16] = O[j].z;
        sO[wv][j][(quad * 4 + 3) * 16 + q16] = O[j].w;
        sl[wv][j][quad * 16 + q16] = l[j];
    }
    __syncthreads();
    int t = threadIdx.x;
    float* pb = part + (size_t)((nh * 36 + strip) * 2 + hb) * 1280;
    #pragma unroll
    for (int j = 0; j < 4; ++j)
        pb[j * 256 + t] = (sO[0][j][t] + sO[1][j][t]) + (sO[2][j][t] + sO[3][j][t]);
    {
        int j2 = t >> 6, i2 = t & 63;
        pb[1024 + t] = (sl[0][j2][i2] + sl[1][j2][i2]) + (sl[2][j2][i2] + sl[3][j2][i2]);
    }
}

// ---------------------------------------------------------------------------
// Combine the 2 D-half partials, subtract the 60 pad-exp(0) terms, normalize.
// grid (36, 16 nh), block 256.
__global__ __launch_bounds__(256) void k_acomb(const float* __restrict__ part,
                                               float* __restrict__ a0) {
    int strip = blockIdx.x, nh = blockIdx.y;
    int n = nh >> 2, h = nh & 3;
    const float* b0 = part + (size_t)((nh * 36 + strip) * 2) * 1280;
    const float* b1 = b0 + 1280;
    int t = threadIdx.x;
    int q = t & 15, c = t >> 4;
    #pragma unroll
    for (int j = 0; j < 4; ++j) {
        float lsum = 0.f;
        #pragma unroll
        for (int qd = 0; qd < 4; ++qd)
            lsum += b0[1024 + j * 64 + qd * 16 + q] + b1[1024 + j * 64 + qd * 16 + q];
        float inv = 1.f / (lsum - 60.f);
        float v = (b0[j * 256 + c * 16 + q] + b1[j * 256 + c * 16 + q]) * inv;
        a0[(size_t)(n * CIN + h * HC + c) * HW + strip * 64 + j * 16 + q] = v;
    }
}

// ---------------------------------------------------------------------------
// A2mean[n,c] = mean over 2116 positions of v2[n,c,:]
__global__ __launch_bounds__(256) void k_mean(const float* __restrict__ v2,
                                              float* __restrict__ a2m) {
    int n = blockIdx.x >> 6, c = blockIdx.x & 63;
    const float* p = v2 + (size_t)(n * CIN + c) * DD;
    float s = 0.f;
    for (int d = threadIdx.x; d < DD; d += 256) s += p[d];
    #pragma unroll
    for (int off = 32; off > 0; off >>= 1) s += __shfl_down(s, off);
    __shared__ float red[4];
    int lane = threadIdx.x & 63, wv = threadIdx.x >> 6;
    if (lane == 0) red[wv] = s;
    __syncthreads();
    if (threadIdx.x == 0)
        a2m[blockIdx.x] = (red[0] + red[1] + red[2] + red[3]) * (1.f / 2116.f);
}

// ---------------------------------------------------------------------------
__global__ __launch_bounds__(256) void k_const2(const float* __restrict__ Wproj,
                                                const float* __restrict__ bg,
                                                const float* __restrict__ a2m,
                                                float* __restrict__ c2) {
    int n = blockIdx.x;
    int t = threadIdx.x;
    if (t >= 192) return;
    int gi = t >> 6, o = t & 63;
    int g = (gi == 0) ? 0 : (gi == 1) ? 2 : 3;
    float acc = bg[g * CIN + o];
    const float* wp = Wproj + ((size_t)(g * 4 + 2) * CIN + o) * CIN;
    for (int c = 0; c < CIN; ++c) acc += wp[c] * a2m[n * CIN + c];
    c2[(gi * NB + n) * CIN + o] = acc;
}

// ---------------------------------------------------------------------------
// Gates + LSTM nonlinearity + output 1x1 conv, fused (unchanged).
__global__ __launch_bounds__(256) void k_gates(const float* __restrict__ a0,
                                               const float* __restrict__ c2,
                                               const float* __restrict__ Wproj,
                                               const float* __restrict__ Wout,
                                               const float* __restrict__ bout,
                                               float* __restrict__ out) {
    __shared__ float a0s[64][16];
    __shared__ float wps[3][64][64];
    __shared__ float hs[16][68];
    int n = blockIdx.y;
    int p0 = blockIdx.x * 16;
    int tid = threadIdx.x;

    for (int idx = tid; idx < 1024; idx += 256) {
        int c = idx >> 4, px = idx & 15;
        a0s[c][px] = a0[(size_t)(n * CIN + c) * HW + p0 + px];
    }
    for (int idx = tid; idx < 12288; idx += 256) {
        int o = idx & 63; int rest = idx >> 6; int c = rest & 63; int gi = rest >> 6;
        int g = (gi == 0) ? 0 : (gi == 1) ? 2 : 3;
        wps[gi][c][o] = Wproj[((size_t)(g * 4 + 0) * CIN + o) * CIN + c];
    }
    __syncthreads();

    int o = tid & 63, pg = tid >> 6;
    float pi[4], pgt[4], po[4];
    {
        float ci = c2[(0 * NB + n) * CIN + o];
        float cg = c2[(1 * NB + n) * CIN + o];
        float co = c2[(2 * NB + n) * CIN + o];
        #pragma unroll
        for (int j = 0; j < 4; ++j) { pi[j] = ci; pgt[j] = cg; po[j] = co; }
    }
    const float4* a4 = (const float4*)&a0s[0][0];
    #pragma unroll 4
    for (int c = 0; c < 64; ++c) {
        float4 av = a4[c * 4 + pg];
        float w0 = wps[0][c][o], w1 = wps[1][c][o], w2 = wps[2][c][o];
        pi[0]  += w0 * av.x; pi[1]  += w0 * av.y; pi[2]  += w0 * av.z; pi[3]  += w0 * av.w;
        pgt[0] += w1 * av.x; pgt[1] += w1 * av.y; pgt[2] += w1 * av.z; pgt[3] += w1 * av.w;
        po[0]  += w2 * av.x; po[1]  += w2 * av.y; po[2]  += w2 * av.z; po[3]  += w2 * av.w;
    }
    #pragma unroll
    for (int j = 0; j < 4; ++j) {
        float ii = 1.f / (1.f + __expf(-pi[j]));
        float gg = tanhf(pgt[j]);
        float oo = 1.f / (1.f + __expf(-po[j]));
        float cc = ii * gg;
        hs[pg * 4 + j][o] = oo * tanhf(cc);
    }
    __syncthreads();
    float acc[4];
    float bo = bout[o];
    #pragma unroll
    for (int j = 0; j < 4; ++j) acc[j] = bo;
    const float* wo = Wout + o * CIN;
    #pragma unroll 2
    for (int cg_ = 0; cg_ < 16; ++cg_) {
        float w0 = wo[cg_ * 4 + 0], w1 = wo[cg_ * 4 + 1], w2 = wo[cg_ * 4 + 2], w3 = wo[cg_ * 4 + 3];
        #pragma unroll
        for (int j = 0; j < 4; ++j) {
            const float4 hv = *(const float4*)&hs[pg * 4 + j][cg_ * 4];
            acc[j] += w0 * hv.x + w1 * hv.y + w2 * hv.z + w3 * hv.w;
        }
    }
    #pragma unroll
    for (int j = 0; j < 4; ++j)
        out[(size_t)(n * CIN + o) * HW + p0 + pg * 4 + j] = acc[j];
}

// ---------------------------------------------------------------------------
extern "C" void kernel_launch(void* const* d_in, const int* in_sizes, int n_in,
                              void* d_out, int out_size, void* d_ws, size_t ws_size,
                              hipStream_t stream) {
    const float* x     = (const float*)d_in[0];
    const float* W_in  = (const float*)d_in[1];
    const float* b_in  = (const float*)d_in[2];
    const float* Wq    = (const float*)d_in[3];
    const float* Wk    = (const float*)d_in[4];
    const float* Wv    = (const float*)d_in[5];
    const float* Wproj = (const float*)d_in[6];
    const float* b_g   = (const float*)d_in[7];
    const float* W_out = (const float*)d_in[8];
    const float* b_out = (const float*)d_in[9];
    float* out = (float*)d_out;

    float* xin  = (float*)d_ws;          // 589824
    float* q0   = xin + 589824;          // 589824
    float* k0   = q0 + 589824;           // 541696
    float* v0   = k0 + 541696;           // 541696
    float* v2   = v0 + 541696;           // 541696
    float* a0   = v2 + 541696;           // 589824
    float* a2m  = a0 + 589824;           // 256
    float* c2   = a2m + 256;             // 768
    float* fend = c2 + 768;
    unsigned short* Qb = (unsigned short*)fend;            // 16*144*512 = 1179648 ush
    unsigned short* Kb = Qb + (size_t)16 * QTL * 512;      // 16*136*512 = 1114112 ush
    unsigned short* Vb = Kb + (size_t)16 * NT * 512;       // 1114112 ush
    float* part = (float*)(Vb + (size_t)16 * NT * 512);    // 16*36*2*1280 = 1474560 f
    // total ~26.4 MB of workspace

    k_xin   <<<dim3(9, 4, 16), 256, 0, stream>>>(x, W_in, b_in, xin);
    k_conv  <<<dim3(9, 4, 16), 256, 0, stream>>>(xin, Wq, Wk, Wv, q0, k0, v0, v2);
    k_cvt   <<<dim3(144, 16), 256, 0, stream>>>(q0, k0, v0, Qb, Kb, Vb);
    k_mattn <<<dim3(72, 16), 256, 0, stream>>>(Qb, Kb, Vb, part);
    k_acomb <<<dim3(36, 16), 256, 0, stream>>>(part, a0);
    k_mean  <<<dim3(256), 256, 0, stream>>>(v2, a2m);
    k_const2<<<dim3(4), 256, 0, stream>>>(Wproj, b_g, a2m, c2);
    k_gates <<<dim3(144, 4), 256, 0, stream>>>(a0, c2, Wproj, W_out, b_out, out);
}

// Round 7
// 229.784 us; speedup vs baseline: 1.2423x; 1.2423x over previous
//
#include <hip/hip_runtime.h>
#include <math.h>

// Problem constants
#define NB   4      // batch
#define CIN  64     // channels everywhere (I=CR=CA=CO=64)
#define HH   48
#define WW   48
#define HW   2304   // 48*48
#define DH   46
#define DW   46
#define DD   2116   // 46*46
#define NHEAD 4
#define HC   16
#define NT   136    // padded d-tiles (2176 = 136*16; 60 zero-pads)
#define QTL  144    // q-tiles (2304 = 144*16)

typedef short  s4 __attribute__((ext_vector_type(4)));
typedef short  s8 __attribute__((ext_vector_type(8)));
typedef float  f4 __attribute__((ext_vector_type(4)));

// ---------------------------------------------------------------------------
// Input 1x1 conv, emitted directly as conv-ready bf16x2:
// xb[n][cell(50x50, 1-px zero border)][128] where the 128 shorts per cell are
// 16 fragment-groups of 8: group (kq,quad) = {hi[ic=kq*16+quad*4 ..+3],
// lo[same]} — exactly the per-lane b128 a conv B-fragment load needs.
// grid (10, 4 n, 16 ocg), block 256. Border cells = zeros (conv padding).
__global__ __launch_bounds__(256) void k_xin(const float* __restrict__ x,
                                             const float* __restrict__ Win,
                                             const float* __restrict__ bin,
                                             unsigned short* __restrict__ xb) {
    int cell = blockIdx.x * 256 + threadIdx.x;
    if (cell >= 2500) return;
    int n = blockIdx.y, ocg = blockIdx.z;        // oc = ocg*4 .. +3
    int cy = cell / 50, cx = cell - cy * 50;
    float a[4] = {0.f, 0.f, 0.f, 0.f};
    if (cy >= 1 && cy <= 48 && cx >= 1 && cx <= 48) {
        int px = (cy - 1) * 48 + (cx - 1);
        const float* xp = x + (size_t)(n * CIN) * HW + px;
        #pragma unroll
        for (int j = 0; j < 4; ++j) a[j] = bin[ocg * 4 + j];
        #pragma unroll 8
        for (int ic = 0; ic < CIN; ++ic) {
            float xv = xp[ic * HW];
            a[0] += Win[(ocg * 4 + 0) * CIN + ic] * xv;
            a[1] += Win[(ocg * 4 + 1) * CIN + ic] * xv;
            a[2] += Win[(ocg * 4 + 2) * CIN + ic] * xv;
            a[3] += Win[(ocg * 4 + 3) * CIN + ic] * xv;
        }
    }
    s8 st;
    #pragma unroll
    for (int j = 0; j < 4; ++j) {
        unsigned u = __builtin_bit_cast(unsigned, a[j]);
        st[j] = (short)(u >> 16);
        float lo = a[j] - __builtin_bit_cast(float, u & 0xffff0000u);
        st[4 + j] = (short)(__builtin_bit_cast(unsigned, lo) >> 16);
    }
    *(s8*)(xb + ((size_t)(n * 2500 + cell)) * 128 + ocg * 8) = st;
}

// ---------------------------------------------------------------------------
// Repack conv weights into MFMA A-fragment order, bf16x2:
// Wb[cq=cv*4+ocq][tap][kq][512] ; per lane(m16,quad): 8 shorts =
// {hi[k=quad*4..+3], lo[same]} of W[oc0+m16][ic=kq*16+k][tap].
// grid (144 = cq*9+tap), block 256.
__global__ __launch_bounds__(256) void k_wcvt(const float* __restrict__ Wq,
                                              const float* __restrict__ Wk,
                                              const float* __restrict__ Wv,
                                              unsigned short* __restrict__ Wb) {
    int bx = blockIdx.x;
    int cq = bx / 9, tap = bx - cq * 9;
    int cv = cq >> 2, ocq = cq & 3;
    const float* src = (cv == 0) ? Wq : (cv == 1) ? Wk : (cv == 2) ? Wv
                                                      : (Wv + 2 * CIN * CIN * 9);
    int t = threadIdx.x;
    int m = t >> 4, kl = t & 15, quad = kl >> 2, j = kl & 3;
    #pragma unroll
    for (int kq = 0; kq < 4; ++kq) {
        float v = src[((size_t)(ocq * 16 + m) * CIN + kq * 16 + kl) * 9 + tap];
        unsigned u = __builtin_bit_cast(unsigned, v);
        float lo = v - __builtin_bit_cast(float, u & 0xffff0000u);
        size_t base = ((size_t)(cq * 9 + tap) * 4 + kq) * 512 + m * 32 + quad * 8 + j;
        Wb[base]     = (unsigned short)(u >> 16);
        Wb[base + 4] = (unsigned short)(__builtin_bit_cast(unsigned, lo) >> 16);
    }
}

// ---------------------------------------------------------------------------
// Implicit-GEMM 3x3 conv on MFMA, zero LDS, no barriers.
// Block = 4 waves = 4 oc-groups; block computes C[64oc][16px] for one
// (n, cv, y, x-tile). Per tap, per k-quarter: one b128 A-load (weights,
// L2/L1-hot), one b128 B-load (xb, padded -> no OOB), 3 compensated
// mfma_16x16x16_bf16_1k (drops only wl*xl ~2^-32).
// grid (144 = y*3+xt, 4 n, 4 cv), block 256.
__global__ __launch_bounds__(256, 4) void k_conv(const unsigned short* __restrict__ xb,
                                                 const unsigned short* __restrict__ Wb,
                                                 float* __restrict__ q0, float* __restrict__ k0,
                                                 float* __restrict__ v0, float* __restrict__ v2) {
    int sp = blockIdx.x;
    int y = sp / 3, x0 = (sp - y * 3) * 16;
    int n = blockIdx.y, cv = blockIdx.z;
    float* ob; int outw, pd;
    if (cv == 0)      { ob = q0; outw = 48; pd = 0; }   // SAME
    else if (cv == 1) { ob = k0; outw = 46; pd = 1; }   // VALID
    else if (cv == 2) { ob = v0; outw = 46; pd = 1; }
    else              { ob = v2; outw = 46; pd = 1; }
    if (y >= outw) return;
    int lane = threadIdx.x & 63, wv = threadIdx.x >> 6;
    int m16 = lane & 15, quad = lane >> 4;
    const unsigned short* Wt = Wb + (size_t)(cv * 4 + wv) * 9 * 2048 + m16 * 32 + quad * 8;
    const unsigned short* Bn = xb + (size_t)n * 2500 * 128 + quad * 8;
    f4 acc = {0.f, 0.f, 0.f, 0.f};
    #pragma unroll
    for (int tap = 0; tap < 9; ++tap) {
        int dy = tap / 3, dx = tap - dy * 3;
        int yy = y + dy + pd;
        int xx = x0 + dx + pd + m16;
        const unsigned short* bp = Bn + (size_t)(yy * 50 + xx) * 128;
        const unsigned short* wp = Wt + tap * 2048;
        #pragma unroll
        for (int kq = 0; kq < 4; ++kq) {
            s8 w8 = *(const s8*)(wp + kq * 512);
            s8 b8 = *(const s8*)(bp + kq * 32);
            s4 ah = __builtin_shufflevector(w8, w8, 0, 1, 2, 3);
            s4 al = __builtin_shufflevector(w8, w8, 4, 5, 6, 7);
            s4 bh = __builtin_shufflevector(b8, b8, 0, 1, 2, 3);
            s4 bl = __builtin_shufflevector(b8, b8, 4, 5, 6, 7);
            acc = __builtin_amdgcn_mfma_f32_16x16x16bf16_1k(ah, bh, acc, 0, 0, 0);
            acc = __builtin_amdgcn_mfma_f32_16x16x16bf16_1k(al, bh, acc, 0, 0, 0);
            acc = __builtin_amdgcn_mfma_f32_16x16x16bf16_1k(ah, bl, acc, 0, 0, 0);
        }
    }
    int ox = x0 + m16;
    if (ox < outw) {
        size_t outsz = (size_t)outw * outw;
        float* op = ob + (size_t)(n * CIN + wv * 16 + quad * 4) * outsz + (size_t)y * outw + ox;
        op[0] = acc.x; op[outsz] = acc.y; op[2 * outsz] = acc.z; op[3 * outsz] = acc.w;
    }
}

// ---------------------------------------------------------------------------
// Convert q0/k0/v0 fp32 -> MFMA-tiled bf16x2 (hi/lo planes, truncation split).
// grid (144, 16 nh), block 256.
__global__ __launch_bounds__(256) void k_cvt(const float* __restrict__ q0,
                                             const float* __restrict__ k0,
                                             const float* __restrict__ v0,
                                             unsigned short* __restrict__ Qb,
                                             unsigned short* __restrict__ Kb,
                                             unsigned short* __restrict__ Vb) {
    __shared__ float sm[272];            // 16x16 transpose pad 17
    int bx = blockIdx.x, nh = blockIdx.y;
    int n = nh >> 2, h = nh & 3;
    int t = threadIdx.x;
    {
        int c = t >> 4, q = t & 15;
        float val = q0[(size_t)(n * CIN + h * HC + c) * HW + bx * 16 + q];
        sm[c * 17 + q] = val;
        __syncthreads();
        int q2 = t >> 4, c2 = t & 15;
        float v = sm[c2 * 17 + q2];
        unsigned u = __builtin_bit_cast(unsigned, v);
        unsigned short* dst = Qb + (size_t)(nh * QTL + bx) * 512;
        dst[t] = (unsigned short)(u >> 16);
        float lo = v - __builtin_bit_cast(float, u & 0xffff0000u);
        dst[256 + t] = (unsigned short)(__builtin_bit_cast(unsigned, lo) >> 16);
    }
    if (bx < NT) {
        __syncthreads();
        int c = t >> 4, d = t & 15;
        int dgl = bx * 16 + d;
        float kv = (dgl < DD) ? k0[(size_t)(n * CIN + h * HC + c) * DD + dgl] : 0.f;
        sm[c * 17 + d] = kv;
        __syncthreads();
        {
            int d2 = t >> 4, c2 = t & 15;
            float v = sm[c2 * 17 + d2];
            unsigned u = __builtin_bit_cast(unsigned, v);
            unsigned short* dst = Kb + (size_t)(nh * NT + bx) * 512;
            dst[t] = (unsigned short)(u >> 16);
            float lo = v - __builtin_bit_cast(float, u & 0xffff0000u);
            dst[256 + t] = (unsigned short)(__builtin_bit_cast(unsigned, lo) >> 16);
        }
        {
            float vv = (dgl < DD) ? v0[(size_t)(n * CIN + h * HC + c) * DD + dgl] : 0.f;
            unsigned u = __builtin_bit_cast(unsigned, vv);
            unsigned short* dst = Vb + (size_t)(nh * NT + bx) * 512;
            dst[t] = (unsigned short)(u >> 16);
            float lo = vv - __builtin_bit_cast(float, u & 0xffff0000u);
            dst[256 + t] = (unsigned short)(__builtin_bit_cast(unsigned, lo) >> 16);
        }
    }
}

// ---------------------------------------------------------------------------
// MFMA attention (validated round 5). grid (72, 16 nh), block 256.
__global__ __launch_bounds__(256) void k_mattn(const unsigned short* __restrict__ Qb,
                                               const unsigned short* __restrict__ Kb,
                                               const unsigned short* __restrict__ Vb,
                                               float* __restrict__ part) {
    __shared__ float sO[4][4][256];
    __shared__ float sl[4][4][64];
    int strip = blockIdx.x >> 1, hb = blockIdx.x & 1, nh = blockIdx.y;
    int lane = threadIdx.x & 63, wv = threadIdx.x >> 6;
    int ds = hb * 4 + wv;
    int q16 = lane & 15, quad = lane >> 4;
    int foff = q16 * 16 + quad * 4;

    s4 qh[4], ql[4];
    #pragma unroll
    for (int j = 0; j < 4; ++j) {
        const unsigned short* Qp = Qb + (size_t)(nh * QTL + strip * 4 + j) * 512 + foff;
        qh[j] = *(const s4*)(Qp);
        ql[j] = *(const s4*)(Qp + 256);
    }
    f4 O[4];
    float l[4];
    #pragma unroll
    for (int j = 0; j < 4; ++j) { O[j] = (f4){0.f, 0.f, 0.f, 0.f}; l[j] = 0.f; }

    const unsigned short* Kp = Kb + (size_t)(nh * NT + ds * 17) * 512 + foff;
    const unsigned short* Vp = Vb + (size_t)(nh * NT + ds * 17) * 512 + foff;
    s4 khi = *(const s4*)(Kp);
    s4 klo = *(const s4*)(Kp + 256);
    s4 vhi = *(const s4*)(Vp);
    s4 vlo = *(const s4*)(Vp + 256);

    for (int it = 0; it < 17; ++it) {
        int nxt = (it < 16) ? (it + 1) * 512 : 0;
        s4 nkhi = *(const s4*)(Kp + nxt);
        s4 nklo = *(const s4*)(Kp + nxt + 256);
        s4 nvhi = *(const s4*)(Vp + nxt);
        s4 nvlo = *(const s4*)(Vp + nxt + 256);

        #pragma unroll
        for (int j = 0; j < 4; ++j) {
            f4 c1 = (f4){0.f, 0.f, 0.f, 0.f};
            c1 = __builtin_amdgcn_mfma_f32_16x16x16bf16_1k(khi, qh[j], c1, 0, 0, 0);
            c1 = __builtin_amdgcn_mfma_f32_16x16x16bf16_1k(klo, qh[j], c1, 0, 0, 0);
            c1 = __builtin_amdgcn_mfma_f32_16x16x16bf16_1k(khi, ql[j], c1, 0, 0, 0);
            float p0 = __expf(c1.x), p1 = __expf(c1.y);
            float p2 = __expf(c1.z), p3 = __expf(c1.w);
            l[j] += (p0 + p1) + (p2 + p3);
            unsigned u0 = __builtin_bit_cast(unsigned, p0);
            unsigned u1 = __builtin_bit_cast(unsigned, p1);
            unsigned u2 = __builtin_bit_cast(unsigned, p2);
            unsigned u3 = __builtin_bit_cast(unsigned, p3);
            s4 ph;
            ph.x = (short)(u0 >> 16); ph.y = (short)(u1 >> 16);
            ph.z = (short)(u2 >> 16); ph.w = (short)(u3 >> 16);
            float r0 = p0 - __builtin_bit_cast(float, u0 & 0xffff0000u);
            float r1 = p1 - __builtin_bit_cast(float, u1 & 0xffff0000u);
            float r2 = p2 - __builtin_bit_cast(float, u2 & 0xffff0000u);
            float r3 = p3 - __builtin_bit_cast(float, u3 & 0xffff0000u);
            s4 pl;
            pl.x = (short)(__builtin_bit_cast(unsigned, r0) >> 16);
            pl.y = (short)(__builtin_bit_cast(unsigned, r1) >> 16);
            pl.z = (short)(__builtin_bit_cast(unsigned, r2) >> 16);
            pl.w = (short)(__builtin_bit_cast(unsigned, r3) >> 16);
            O[j] = __builtin_amdgcn_mfma_f32_16x16x16bf16_1k(vhi, ph, O[j], 0, 0, 0);
            O[j] = __builtin_amdgcn_mfma_f32_16x16x16bf16_1k(vlo, ph, O[j], 0, 0, 0);
            O[j] = __builtin_amdgcn_mfma_f32_16x16x16bf16_1k(vhi, pl, O[j], 0, 0, 0);
        }
        khi = nkhi; klo = nklo; vhi = nvhi; vlo = nvlo;
    }

    #pragma unroll
    for (int j = 0; j < 4; ++j) {
        sO[wv][j][(quad * 4 + 0) * 16 + q16] = O[j].x;
        sO[wv][j][(quad * 4 + 1) * 16 + q16] = O[j].y;
        sO[wv][j][(quad * 4 + 2) * 16 + q16] = O[j].z;
        sO[wv][j][(quad * 4 + 3) * 16 + q16] = O[j].w;
        sl[wv][j][quad * 16 + q16] = l[j];
    }
    __syncthreads();
    int t = threadIdx.x;
    float* pb = part + (size_t)((nh * 36 + strip) * 2 + hb) * 1280;
    #pragma unroll
    for (int j = 0; j < 4; ++j)
        pb[j * 256 + t] = (sO[0][j][t] + sO[1][j][t]) + (sO[2][j][t] + sO[3][j][t]);
    {
        int j2 = t >> 6, i2 = t & 63;
        pb[1024 + t] = (sl[0][j2][i2] + sl[1][j2][i2]) + (sl[2][j2][i2] + sl[3][j2][i2]);
    }
}

// ---------------------------------------------------------------------------
// Combine the 2 D-half partials, subtract the 60 pad-exp(0) terms, normalize.
__global__ __launch_bounds__(256) void k_acomb(const float* __restrict__ part,
                                               float* __restrict__ a0) {
    int strip = blockIdx.x, nh = blockIdx.y;
    int n = nh >> 2, h = nh & 3;
    const float* b0 = part + (size_t)((nh * 36 + strip) * 2) * 1280;
    const float* b1 = b0 + 1280;
    int t = threadIdx.x;
    int q = t & 15, c = t >> 4;
    #pragma unroll
    for (int j = 0; j < 4; ++j) {
        float lsum = 0.f;
        #pragma unroll
        for (int qd = 0; qd < 4; ++qd)
            lsum += b0[1024 + j * 64 + qd * 16 + q] + b1[1024 + j * 64 + qd * 16 + q];
        float inv = 1.f / (lsum - 60.f);
        float v = (b0[j * 256 + c * 16 + q] + b1[j * 256 + c * 16 + q]) * inv;
        a0[(size_t)(n * CIN + h * HC + c) * HW + strip * 64 + j * 16 + q] = v;
    }
}

// ---------------------------------------------------------------------------
// A2mean[n,c] = mean over 2116 positions of v2[n,c,:]
__global__ __launch_bounds__(256) void k_mean(const float* __restrict__ v2,
                                              float* __restrict__ a2m) {
    int n = blockIdx.x >> 6, c = blockIdx.x & 63;
    const float* p = v2 + (size_t)(n * CIN + c) * DD;
    float s = 0.f;
    for (int d = threadIdx.x; d < DD; d += 256) s += p[d];
    #pragma unroll
    for (int off = 32; off > 0; off >>= 1) s += __shfl_down(s, off);
    __shared__ float red[4];
    int lane = threadIdx.x & 63, wv = threadIdx.x >> 6;
    if (lane == 0) red[wv] = s;
    __syncthreads();
    if (threadIdx.x == 0)
        a2m[blockIdx.x] = (red[0] + red[1] + red[2] + red[3]) * (1.f / 2116.f);
}

// ---------------------------------------------------------------------------
__global__ __launch_bounds__(256) void k_const2(const float* __restrict__ Wproj,
                                                const float* __restrict__ bg,
                                                const float* __restrict__ a2m,
                                                float* __restrict__ c2) {
    int n = blockIdx.x;
    int t = threadIdx.x;
    if (t >= 192) return;
    int gi = t >> 6, o = t & 63;
    int g = (gi == 0) ? 0 : (gi == 1) ? 2 : 3;
    float acc = bg[g * CIN + o];
    const float* wp = Wproj + ((size_t)(g * 4 + 2) * CIN + o) * CIN;
    for (int c = 0; c < CIN; ++c) acc += wp[c] * a2m[n * CIN + c];
    c2[(gi * NB + n) * CIN + o] = acc;
}

// ---------------------------------------------------------------------------
// Gates + LSTM nonlinearity + output 1x1 conv, fused (unchanged).
__global__ __launch_bounds__(256) void k_gates(const float* __restrict__ a0,
                                               const float* __restrict__ c2,
                                               const float* __restrict__ Wproj,
                                               const float* __restrict__ Wout,
                                               const float* __restrict__ bout,
                                               float* __restrict__ out) {
    __shared__ float a0s[64][16];
    __shared__ float wps[3][64][64];
    __shared__ float hs[16][68];
    int n = blockIdx.y;
    int p0 = blockIdx.x * 16;
    int tid = threadIdx.x;

    for (int idx = tid; idx < 1024; idx += 256) {
        int c = idx >> 4, px = idx & 15;
        a0s[c][px] = a0[(size_t)(n * CIN + c) * HW + p0 + px];
    }
    for (int idx = tid; idx < 12288; idx += 256) {
        int o = idx & 63; int rest = idx >> 6; int c = rest & 63; int gi = rest >> 6;
        int g = (gi == 0) ? 0 : (gi == 1) ? 2 : 3;
        wps[gi][c][o] = Wproj[((size_t)(g * 4 + 0) * CIN + o) * CIN + c];
    }
    __syncthreads();

    int o = tid & 63, pg = tid >> 6;
    float pi[4], pgt[4], po[4];
    {
        float ci = c2[(0 * NB + n) * CIN + o];
        float cg = c2[(1 * NB + n) * CIN + o];
        float co = c2[(2 * NB + n) * CIN + o];
        #pragma unroll
        for (int j = 0; j < 4; ++j) { pi[j] = ci; pgt[j] = cg; po[j] = co; }
    }
    const float4* a4 = (const float4*)&a0s[0][0];
    #pragma unroll 4
    for (int c = 0; c < 64; ++c) {
        float4 av = a4[c * 4 + pg];
        float w0 = wps[0][c][o], w1 = wps[1][c][o], w2 = wps[2][c][o];
        pi[0]  += w0 * av.x; pi[1]  += w0 * av.y; pi[2]  += w0 * av.z; pi[3]  += w0 * av.w;
        pgt[0] += w1 * av.x; pgt[1] += w1 * av.y; pgt[2] += w1 * av.z; pgt[3] += w1 * av.w;
        po[0]  += w2 * av.x; po[1]  += w2 * av.y; po[2]  += w2 * av.z; po[3]  += w2 * av.w;
    }
    #pragma unroll
    for (int j = 0; j < 4; ++j) {
        float ii = 1.f / (1.f + __expf(-pi[j]));
        float gg = tanhf(pgt[j]);
        float oo = 1.f / (1.f + __expf(-po[j]));
        float cc = ii * gg;
        hs[pg * 4 + j][o] = oo * tanhf(cc);
    }
    __syncthreads();
    float acc[4];
    float bo = bout[o];
    #pragma unroll
    for (int j = 0; j < 4; ++j) acc[j] = bo;
    const float* wo = Wout + o * CIN;
    #pragma unroll 2
    for (int cg_ = 0; cg_ < 16; ++cg_) {
        float w0 = wo[cg_ * 4 + 0], w1 = wo[cg_ * 4 + 1], w2 = wo[cg_ * 4 + 2], w3 = wo[cg_ * 4 + 3];
        #pragma unroll
        for (int j = 0; j < 4; ++j) {
            const float4 hv = *(const float4*)&hs[pg * 4 + j][cg_ * 4];
            acc[j] += w0 * hv.x + w1 * hv.y + w2 * hv.z + w3 * hv.w;
        }
    }
    #pragma unroll
    for (int j = 0; j < 4; ++j)
        out[(size_t)(n * CIN + o) * HW + p0 + pg * 4 + j] = acc[j];
}

// ---------------------------------------------------------------------------
extern "C" void kernel_launch(void* const* d_in, const int* in_sizes, int n_in,
                              void* d_out, int out_size, void* d_ws, size_t ws_size,
                              hipStream_t stream) {
    const float* x     = (const float*)d_in[0];
    const float* W_in  = (const float*)d_in[1];
    const float* b_in  = (const float*)d_in[2];
    const float* Wq    = (const float*)d_in[3];
    const float* Wk    = (const float*)d_in[4];
    const float* Wv    = (const float*)d_in[5];
    const float* Wproj = (const float*)d_in[6];
    const float* b_g   = (const float*)d_in[7];
    const float* W_out = (const float*)d_in[8];
    const float* b_out = (const float*)d_in[9];
    float* out = (float*)d_out;

    float* q0   = (float*)d_ws;          // 589824
    float* k0   = q0 + 589824;           // 541696
    float* v0   = k0 + 541696;           // 541696
    float* v2   = v0 + 541696;           // 541696
    float* a0   = v2 + 541696;           // 589824
    float* a2m  = a0 + 589824;           // 256
    float* c2   = a2m + 256;             // 768
    float* part = c2 + 768;              // 16*36*2*1280 = 1474560
    unsigned short* Qb = (unsigned short*)(part + 1474560);  // 16*144*512
    unsigned short* Kb = Qb + (size_t)16 * QTL * 512;        // 16*136*512
    unsigned short* Vb = Kb + (size_t)16 * NT * 512;         // 16*136*512
    unsigned short* xb = Vb + (size_t)16 * NT * 512;         // 4*2500*128
    unsigned short* Wb = xb + (size_t)4 * 2500 * 128;        // 16*9*4*512
    // total ~27.2 MB of workspace

    k_xin   <<<dim3(10, 4, 16), 256, 0, stream>>>(x, W_in, b_in, xb);
    k_wcvt  <<<dim3(144), 256, 0, stream>>>(Wq, Wk, Wv, Wb);
    k_conv  <<<dim3(144, 4, 4), 256, 0, stream>>>(xb, Wb, q0, k0, v0, v2);
    k_cvt   <<<dim3(144, 16), 256, 0, stream>>>(q0, k0, v0, Qb, Kb, Vb);
    k_mattn <<<dim3(72, 16), 256, 0, stream>>>(Qb, Kb, Vb, part);
    k_acomb <<<dim3(36, 16), 256, 0, stream>>>(part, a0);
    k_mean  <<<dim3(256), 256, 0, stream>>>(v2, a2m);
    k_const2<<<dim3(4), 256, 0, stream>>>(Wproj, b_g, a2m, c2);
    k_gates <<<dim3(144, 4), 256, 0, stream>>>(a0, c2, Wproj, W_out, b_out, out);
}

// Round 8
// 208.212 us; speedup vs baseline: 1.3710x; 1.1036x over previous
//
#include <hip/hip_runtime.h>
#include <math.h>

// Problem constants
#define NB   4      // batch
#define CIN  64     // channels everywhere (I=CR=CA=CO=64)
#define HH   48
#define WW   48
#define HW   2304   // 48*48
#define DH   46
#define DW   46
#define DD   2116   // 46*46
#define NHEAD 4
#define HC   16
#define NT   136    // padded d-tiles (2176 = 136*16; 60 zero-pads)
#define QTL  144    // q-tiles (2304 = 144*16)

typedef short  s4 __attribute__((ext_vector_type(4)));
typedef short  s8 __attribute__((ext_vector_type(8)));
typedef float  f4 __attribute__((ext_vector_type(4)));

// ---------------------------------------------------------------------------
// Input 1x1 conv, emitted directly as conv-ready bf16x2:
// xb[n][cell(50x50, 1-px zero border)][128]; per cell 16 groups of 8 shorts:
// group (kq,quad) = {hi[ic=kq*16+quad*4 ..+3], lo[same]}.
// grid (10, 4 n, 16 ocg), block 256. Border cells = zeros (conv padding).
__global__ __launch_bounds__(256) void k_xin(const float* __restrict__ x,
                                             const float* __restrict__ Win,
                                             const float* __restrict__ bin,
                                             unsigned short* __restrict__ xb) {
    int cell = blockIdx.x * 256 + threadIdx.x;
    if (cell >= 2500) return;
    int n = blockIdx.y, ocg = blockIdx.z;        // oc = ocg*4 .. +3
    int cy = cell / 50, cx = cell - cy * 50;
    float a[4] = {0.f, 0.f, 0.f, 0.f};
    if (cy >= 1 && cy <= 48 && cx >= 1 && cx <= 48) {
        int px = (cy - 1) * 48 + (cx - 1);
        const float* xp = x + (size_t)(n * CIN) * HW + px;
        #pragma unroll
        for (int j = 0; j < 4; ++j) a[j] = bin[ocg * 4 + j];
        #pragma unroll 8
        for (int ic = 0; ic < CIN; ++ic) {
            float xv = xp[ic * HW];
            a[0] += Win[(ocg * 4 + 0) * CIN + ic] * xv;
            a[1] += Win[(ocg * 4 + 1) * CIN + ic] * xv;
            a[2] += Win[(ocg * 4 + 2) * CIN + ic] * xv;
            a[3] += Win[(ocg * 4 + 3) * CIN + ic] * xv;
        }
    }
    s8 st;
    #pragma unroll
    for (int j = 0; j < 4; ++j) {
        unsigned u = __builtin_bit_cast(unsigned, a[j]);
        st[j] = (short)(u >> 16);
        float lo = a[j] - __builtin_bit_cast(float, u & 0xffff0000u);
        st[4 + j] = (short)(__builtin_bit_cast(unsigned, lo) >> 16);
    }
    *(s8*)(xb + ((size_t)(n * 2500 + cell)) * 128 + ocg * 8) = st;
}

// ---------------------------------------------------------------------------
// Repack conv weights into MFMA A-fragment order, bf16x2.
// grid (144 = cq*9+tap), block 256.
__global__ __launch_bounds__(256) void k_wcvt(const float* __restrict__ Wq,
                                              const float* __restrict__ Wk,
                                              const float* __restrict__ Wv,
                                              unsigned short* __restrict__ Wb) {
    int bx = blockIdx.x;
    int cq = bx / 9, tap = bx - cq * 9;
    int cv = cq >> 2, ocq = cq & 3;
    const float* src = (cv == 0) ? Wq : (cv == 1) ? Wk : (cv == 2) ? Wv
                                                      : (Wv + 2 * CIN * CIN * 9);
    int t = threadIdx.x;
    int m = t >> 4, kl = t & 15, quad = kl >> 2, j = kl & 3;
    #pragma unroll
    for (int kq = 0; kq < 4; ++kq) {
        float v = src[((size_t)(ocq * 16 + m) * CIN + kq * 16 + kl) * 9 + tap];
        unsigned u = __builtin_bit_cast(unsigned, v);
        float lo = v - __builtin_bit_cast(float, u & 0xffff0000u);
        size_t base = ((size_t)(cq * 9 + tap) * 4 + kq) * 512 + m * 32 + quad * 8 + j;
        Wb[base]     = (unsigned short)(u >> 16);
        Wb[base + 4] = (unsigned short)(__builtin_bit_cast(unsigned, lo) >> 16);
    }
}

// ---------------------------------------------------------------------------
// Implicit-GEMM 3x3 conv on MFMA — register-double-buffered (k_mattn style).
// Block = 4 waves = 4 oc-groups; block computes C[64oc][48px] = one full
// output row y (3 x-tiles of 16 -> 3 independent acc chains per wave).
// 36 flattened (tap,kq) steps; step t+1's 4 b128 loads issue before step t's
// 9 MFMAs -> latency hidden, MFMA pipe fed by 3 chains. Zero LDS/barriers.
// grid (48 y, 4 n, 4 cv), block 256.
__global__ __launch_bounds__(256) void k_conv(const unsigned short* __restrict__ xb,
                                              const unsigned short* __restrict__ Wb,
                                              float* __restrict__ q0, float* __restrict__ k0,
                                              float* __restrict__ v0, float* __restrict__ v2) {
    int y = blockIdx.x, n = blockIdx.y, cv = blockIdx.z;
    float* ob; int outw, pd;
    if (cv == 0)      { ob = q0; outw = 48; pd = 0; }   // SAME
    else if (cv == 1) { ob = k0; outw = 46; pd = 1; }   // VALID
    else if (cv == 2) { ob = v0; outw = 46; pd = 1; }
    else              { ob = v2; outw = 46; pd = 1; }
    if (y >= outw) return;
    int lane = threadIdx.x & 63, wv = threadIdx.x >> 6;
    int m16 = lane & 15, quad = lane >> 4;
    const unsigned short* Wt = Wb + (size_t)(cv * 4 + wv) * 9 * 2048 + m16 * 32 + quad * 8;
    // per-lane base cell (tile 0, tap 0): row y+pd, col pd+m16; tap adds dy*50+dx.
    // OOB impossible: worst cell index 48*50+50 = 2450 < 2500 (garbage cols are
    // masked at store; padded border cells are zeros).
    const unsigned short* B0 = xb + ((size_t)n * 2500 + (size_t)(y + pd) * 50 + pd + m16) * 128 + quad * 8;

    f4 a0 = {0.f,0.f,0.f,0.f}, a1 = a0, a2 = a0;

    s8 wc = *(const s8*)(Wt);
    s8 c0 = *(const s8*)(B0);
    s8 c1 = *(const s8*)(B0 + 16 * 128);
    s8 c2 = *(const s8*)(B0 + 32 * 128);

    for (int t = 0; t < 36; ++t) {
        int tn = (t + 1 < 36) ? t + 1 : 0;          // last prefetch discarded
        int tapn = tn >> 2, kqn = tn & 3;
        int dyn = (tapn * 11) >> 5;                  // floor(tap/3) for 0..8
        int dxn = tapn - dyn * 3;
        size_t bo = ((size_t)(dyn * 50 + dxn)) * 128 + kqn * 32;
        s8 wn = *(const s8*)(Wt + tapn * 2048 + kqn * 512);
        s8 n0 = *(const s8*)(B0 + bo);
        s8 n1 = *(const s8*)(B0 + bo + 16 * 128);
        s8 n2 = *(const s8*)(B0 + bo + 32 * 128);

        s4 ah  = __builtin_shufflevector(wc, wc, 0, 1, 2, 3);
        s4 al  = __builtin_shufflevector(wc, wc, 4, 5, 6, 7);
        s4 bh0 = __builtin_shufflevector(c0, c0, 0, 1, 2, 3);
        s4 bl0 = __builtin_shufflevector(c0, c0, 4, 5, 6, 7);
        s4 bh1 = __builtin_shufflevector(c1, c1, 0, 1, 2, 3);
        s4 bl1 = __builtin_shufflevector(c1, c1, 4, 5, 6, 7);
        s4 bh2 = __builtin_shufflevector(c2, c2, 0, 1, 2, 3);
        s4 bl2 = __builtin_shufflevector(c2, c2, 4, 5, 6, 7);
        a0 = __builtin_amdgcn_mfma_f32_16x16x16bf16_1k(ah, bh0, a0, 0, 0, 0);
        a1 = __builtin_amdgcn_mfma_f32_16x16x16bf16_1k(ah, bh1, a1, 0, 0, 0);
        a2 = __builtin_amdgcn_mfma_f32_16x16x16bf16_1k(ah, bh2, a2, 0, 0, 0);
        a0 = __builtin_amdgcn_mfma_f32_16x16x16bf16_1k(al, bh0, a0, 0, 0, 0);
        a1 = __builtin_amdgcn_mfma_f32_16x16x16bf16_1k(al, bh1, a1, 0, 0, 0);
        a2 = __builtin_amdgcn_mfma_f32_16x16x16bf16_1k(al, bh2, a2, 0, 0, 0);
        a0 = __builtin_amdgcn_mfma_f32_16x16x16bf16_1k(ah, bl0, a0, 0, 0, 0);
        a1 = __builtin_amdgcn_mfma_f32_16x16x16bf16_1k(ah, bl1, a1, 0, 0, 0);
        a2 = __builtin_amdgcn_mfma_f32_16x16x16bf16_1k(ah, bl2, a2, 0, 0, 0);
        wc = wn; c0 = n0; c1 = n1; c2 = n2;
    }

    size_t outsz = (size_t)outw * outw;
    float* opb = ob + (size_t)(n * CIN + wv * 16 + quad * 4) * outsz + (size_t)y * outw;
    {   // tiles 0,1 always in-bounds (m16<=15, 16+m16<=31 < 46)
        float* op = opb + m16;
        op[0] = a0.x; op[outsz] = a0.y; op[2 * outsz] = a0.z; op[3 * outsz] = a0.w;
        op = opb + 16 + m16;
        op[0] = a1.x; op[outsz] = a1.y; op[2 * outsz] = a1.z; op[3 * outsz] = a1.w;
    }
    if (32 + m16 < outw) {
        float* op = opb + 32 + m16;
        op[0] = a2.x; op[outsz] = a2.y; op[2 * outsz] = a2.z; op[3 * outsz] = a2.w;
    }
}

// ---------------------------------------------------------------------------
// Convert q0/k0/v0 fp32 -> MFMA-tiled bf16x2 (hi/lo planes, truncation split).
// grid (144, 16 nh), block 256.
__global__ __launch_bounds__(256) void k_cvt(const float* __restrict__ q0,
                                             const float* __restrict__ k0,
                                             const float* __restrict__ v0,
                                             unsigned short* __restrict__ Qb,
                                             unsigned short* __restrict__ Kb,
                                             unsigned short* __restrict__ Vb) {
    __shared__ float sm[272];            // 16x16 transpose pad 17
    int bx = blockIdx.x, nh = blockIdx.y;
    int n = nh >> 2, h = nh & 3;
    int t = threadIdx.x;
    {
        int c = t >> 4, q = t & 15;
        float val = q0[(size_t)(n * CIN + h * HC + c) * HW + bx * 16 + q];
        sm[c * 17 + q] = val;
        __syncthreads();
        int q2 = t >> 4, c2 = t & 15;
        float v = sm[c2 * 17 + q2];
        unsigned u = __builtin_bit_cast(unsigned, v);
        unsigned short* dst = Qb + (size_t)(nh * QTL + bx) * 512;
        dst[t] = (unsigned short)(u >> 16);
        float lo = v - __builtin_bit_cast(float, u & 0xffff0000u);
        dst[256 + t] = (unsigned short)(__builtin_bit_cast(unsigned, lo) >> 16);
    }
    if (bx < NT) {
        __syncthreads();
        int c = t >> 4, d = t & 15;
        int dgl = bx * 16 + d;
        float kv = (dgl < DD) ? k0[(size_t)(n * CIN + h * HC + c) * DD + dgl] : 0.f;
        sm[c * 17 + d] = kv;
        __syncthreads();
        {
            int d2 = t >> 4, c2 = t & 15;
            float v = sm[c2 * 17 + d2];
            unsigned u = __builtin_bit_cast(unsigned, v);
            unsigned short* dst = Kb + (size_t)(nh * NT + bx) * 512;
            dst[t] = (unsigned short)(u >> 16);
            float lo = v - __builtin_bit_cast(float, u & 0xffff0000u);
            dst[256 + t] = (unsigned short)(__builtin_bit_cast(unsigned, lo) >> 16);
        }
        {
            float vv = (dgl < DD) ? v0[(size_t)(n * CIN + h * HC + c) * DD + dgl] : 0.f;
            unsigned u = __builtin_bit_cast(unsigned, vv);
            unsigned short* dst = Vb + (size_t)(nh * NT + bx) * 512;
            dst[t] = (unsigned short)(u >> 16);
            float lo = vv - __builtin_bit_cast(float, u & 0xffff0000u);
            dst[256 + t] = (unsigned short)(__builtin_bit_cast(unsigned, lo) >> 16);
        }
    }
}

// ---------------------------------------------------------------------------
// MFMA attention (validated round 5). grid (72, 16 nh), block 256.
__global__ __launch_bounds__(256) void k_mattn(const unsigned short* __restrict__ Qb,
                                               const unsigned short* __restrict__ Kb,
                                               const unsigned short* __restrict__ Vb,
                                               float* __restrict__ part) {
    __shared__ float sO[4][4][256];
    __shared__ float sl[4][4][64];
    int strip = blockIdx.x >> 1, hb = blockIdx.x & 1, nh = blockIdx.y;
    int lane = threadIdx.x & 63, wv = threadIdx.x >> 6;
    int ds = hb * 4 + wv;
    int q16 = lane & 15, quad = lane >> 4;
    int foff = q16 * 16 + quad * 4;

    s4 qh[4], ql[4];
    #pragma unroll
    for (int j = 0; j < 4; ++j) {
        const unsigned short* Qp = Qb + (size_t)(nh * QTL + strip * 4 + j) * 512 + foff;
        qh[j] = *(const s4*)(Qp);
        ql[j] = *(const s4*)(Qp + 256);
    }
    f4 O[4];
    float l[4];
    #pragma unroll
    for (int j = 0; j < 4; ++j) { O[j] = (f4){0.f, 0.f, 0.f, 0.f}; l[j] = 0.f; }

    const unsigned short* Kp = Kb + (size_t)(nh * NT + ds * 17) * 512 + foff;
    const unsigned short* Vp = Vb + (size_t)(nh * NT + ds * 17) * 512 + foff;
    s4 khi = *(const s4*)(Kp);
    s4 klo = *(const s4*)(Kp + 256);
    s4 vhi = *(const s4*)(Vp);
    s4 vlo = *(const s4*)(Vp + 256);

    for (int it = 0; it < 17; ++it) {
        int nxt = (it < 16) ? (it + 1) * 512 : 0;
        s4 nkhi = *(const s4*)(Kp + nxt);
        s4 nklo = *(const s4*)(Kp + nxt + 256);
        s4 nvhi = *(const s4*)(Vp + nxt);
        s4 nvlo = *(const s4*)(Vp + nxt + 256);

        #pragma unroll
        for (int j = 0; j < 4; ++j) {
            f4 c1 = (f4){0.f, 0.f, 0.f, 0.f};
            c1 = __builtin_amdgcn_mfma_f32_16x16x16bf16_1k(khi, qh[j], c1, 0, 0, 0);
            c1 = __builtin_amdgcn_mfma_f32_16x16x16bf16_1k(klo, qh[j], c1, 0, 0, 0);
            c1 = __builtin_amdgcn_mfma_f32_16x16x16bf16_1k(khi, ql[j], c1, 0, 0, 0);
            float p0 = __expf(c1.x), p1 = __expf(c1.y);
            float p2 = __expf(c1.z), p3 = __expf(c1.w);
            l[j] += (p0 + p1) + (p2 + p3);
            unsigned u0 = __builtin_bit_cast(unsigned, p0);
            unsigned u1 = __builtin_bit_cast(unsigned, p1);
            unsigned u2 = __builtin_bit_cast(unsigned, p2);
            unsigned u3 = __builtin_bit_cast(unsigned, p3);
            s4 ph;
            ph.x = (short)(u0 >> 16); ph.y = (short)(u1 >> 16);
            ph.z = (short)(u2 >> 16); ph.w = (short)(u3 >> 16);
            float r0 = p0 - __builtin_bit_cast(float, u0 & 0xffff0000u);
            float r1 = p1 - __builtin_bit_cast(float, u1 & 0xffff0000u);
            float r2 = p2 - __builtin_bit_cast(float, u2 & 0xffff0000u);
            float r3 = p3 - __builtin_bit_cast(float, u3 & 0xffff0000u);
            s4 pl;
            pl.x = (short)(__builtin_bit_cast(unsigned, r0) >> 16);
            pl.y = (short)(__builtin_bit_cast(unsigned, r1) >> 16);
            pl.z = (short)(__builtin_bit_cast(unsigned, r2) >> 16);
            pl.w = (short)(__builtin_bit_cast(unsigned, r3) >> 16);
            O[j] = __builtin_amdgcn_mfma_f32_16x16x16bf16_1k(vhi, ph, O[j], 0, 0, 0);
            O[j] = __builtin_amdgcn_mfma_f32_16x16x16bf16_1k(vlo, ph, O[j], 0, 0, 0);
            O[j] = __builtin_amdgcn_mfma_f32_16x16x16bf16_1k(vhi, pl, O[j], 0, 0, 0);
        }
        khi = nkhi; klo = nklo; vhi = nvhi; vlo = nvlo;
    }

    #pragma unroll
    for (int j = 0; j < 4; ++j) {
        sO[wv][j][(quad * 4 + 0) * 16 + q16] = O[j].x;
        sO[wv][j][(quad * 4 + 1) * 16 + q16] = O[j].y;
        sO[wv][j][(quad * 4 + 2) * 16 + q16] = O[j].z;
        sO[wv][j][(quad * 4 + 3) * 16 + q16] = O[j].w;
        sl[wv][j][quad * 16 + q16] = l[j];
    }
    __syncthreads();
    int t = threadIdx.x;
    float* pb = part + (size_t)((nh * 36 + strip) * 2 + hb) * 1280;
    #pragma unroll
    for (int j = 0; j < 4; ++j)
        pb[j * 256 + t] = (sO[0][j][t] + sO[1][j][t]) + (sO[2][j][t] + sO[3][j][t]);
    {
        int j2 = t >> 6, i2 = t & 63;
        pb[1024 + t] = (sl[0][j2][i2] + sl[1][j2][i2]) + (sl[2][j2][i2] + sl[3][j2][i2]);
    }
}

// ---------------------------------------------------------------------------
// Combine the 2 D-half partials, subtract the 60 pad-exp(0) terms, normalize.
__global__ __launch_bounds__(256) void k_acomb(const float* __restrict__ part,
                                               float* __restrict__ a0) {
    int strip = blockIdx.x, nh = blockIdx.y;
    int n = nh >> 2, h = nh & 3;
    const float* b0 = part + (size_t)((nh * 36 + strip) * 2) * 1280;
    const float* b1 = b0 + 1280;
    int t = threadIdx.x;
    int q = t & 15, c = t >> 4;
    #pragma unroll
    for (int j = 0; j < 4; ++j) {
        float lsum = 0.f;
        #pragma unroll
        for (int qd = 0; qd < 4; ++qd)
            lsum += b0[1024 + j * 64 + qd * 16 + q] + b1[1024 + j * 64 + qd * 16 + q];
        float inv = 1.f / (lsum - 60.f);
        float v = (b0[j * 256 + c * 16 + q] + b1[j * 256 + c * 16 + q]) * inv;
        a0[(size_t)(n * CIN + h * HC + c) * HW + strip * 64 + j * 16 + q] = v;
    }
}

// ---------------------------------------------------------------------------
// A2mean[n,c] = mean over 2116 positions of v2[n,c,:]
__global__ __launch_bounds__(256) void k_mean(const float* __restrict__ v2,
                                              float* __restrict__ a2m) {
    int n = blockIdx.x >> 6, c = blockIdx.x & 63;
    const float* p = v2 + (size_t)(n * CIN + c) * DD;
    float s = 0.f;
    for (int d = threadIdx.x; d < DD; d += 256) s += p[d];
    #pragma unroll
    for (int off = 32; off > 0; off >>= 1) s += __shfl_down(s, off);
    __shared__ float red[4];
    int lane = threadIdx.x & 63, wv = threadIdx.x >> 6;
    if (lane == 0) red[wv] = s;
    __syncthreads();
    if (threadIdx.x == 0)
        a2m[blockIdx.x] = (red[0] + red[1] + red[2] + red[3]) * (1.f / 2116.f);
}

// ---------------------------------------------------------------------------
__global__ __launch_bounds__(256) void k_const2(const float* __restrict__ Wproj,
                                                const float* __restrict__ bg,
                                                const float* __restrict__ a2m,
                                                float* __restrict__ c2) {
    int n = blockIdx.x;
    int t = threadIdx.x;
    if (t >= 192) return;
    int gi = t >> 6, o = t & 63;
    int g = (gi == 0) ? 0 : (gi == 1) ? 2 : 3;
    float acc = bg[g * CIN + o];
    const float* wp = Wproj + ((size_t)(g * 4 + 2) * CIN + o) * CIN;
    for (int c = 0; c < CIN; ++c) acc += wp[c] * a2m[n * CIN + c];
    c2[(gi * NB + n) * CIN + o] = acc;
}

// ---------------------------------------------------------------------------
// Gates + LSTM nonlinearity + output 1x1 conv, fused (unchanged).
__global__ __launch_bounds__(256) void k_gates(const float* __restrict__ a0,
                                               const float* __restrict__ c2,
                                               const float* __restrict__ Wproj,
                                               const float* __restrict__ Wout,
                                               const float* __restrict__ bout,
                                               float* __restrict__ out) {
    __shared__ float a0s[64][16];
    __shared__ float wps[3][64][64];
    __shared__ float hs[16][68];
    int n = blockIdx.y;
    int p0 = blockIdx.x * 16;
    int tid = threadIdx.x;

    for (int idx = tid; idx < 1024; idx += 256) {
        int c = idx >> 4, px = idx & 15;
        a0s[c][px] = a0[(size_t)(n * CIN + c) * HW + p0 + px];
    }
    for (int idx = tid; idx < 12288; idx += 256) {
        int o = idx & 63; int rest = idx >> 6; int c = rest & 63; int gi = rest >> 6;
        int g = (gi == 0) ? 0 : (gi == 1) ? 2 : 3;
        wps[gi][c][o] = Wproj[((size_t)(g * 4 + 0) * CIN + o) * CIN + c];
    }
    __syncthreads();

    int o = tid & 63, pg = tid >> 6;
    float pi[4], pgt[4], po[4];
    {
        float ci = c2[(0 * NB + n) * CIN + o];
        float cg = c2[(1 * NB + n) * CIN + o];
        float co = c2[(2 * NB + n) * CIN + o];
        #pragma unroll
        for (int j = 0; j < 4; ++j) { pi[j] = ci; pgt[j] = cg; po[j] = co; }
    }
    const float4* a4 = (const float4*)&a0s[0][0];
    #pragma unroll 4
    for (int c = 0; c < 64; ++c) {
        float4 av = a4[c * 4 + pg];
        float w0 = wps[0][c][o], w1 = wps[1][c][o], w2 = wps[2][c][o];
        pi[0]  += w0 * av.x; pi[1]  += w0 * av.y; pi[2]  += w0 * av.z; pi[3]  += w0 * av.w;
        pgt[0] += w1 * av.x; pgt[1] += w1 * av.y; pgt[2] += w1 * av.z; pgt[3] += w1 * av.w;
        po[0]  += w2 * av.x; po[1]  += w2 * av.y; po[2]  += w2 * av.z; po[3]  += w2 * av.w;
    }
    #pragma unroll
    for (int j = 0; j < 4; ++j) {
        float ii = 1.f / (1.f + __expf(-pi[j]));
        float gg = tanhf(pgt[j]);
        float oo = 1.f / (1.f + __expf(-po[j]));
        float cc = ii * gg;
        hs[pg * 4 + j][o] = oo * tanhf(cc);
    }
    __syncthreads();
    float acc[4];
    float bo = bout[o];
    #pragma unroll
    for (int j = 0; j < 4; ++j) acc[j] = bo;
    const float* wo = Wout + o * CIN;
    #pragma unroll 2
    for (int cg_ = 0; cg_ < 16; ++cg_) {
        float w0 = wo[cg_ * 4 + 0], w1 = wo[cg_ * 4 + 1], w2 = wo[cg_ * 4 + 2], w3 = wo[cg_ * 4 + 3];
        #pragma unroll
        for (int j = 0; j < 4; ++j) {
            const float4 hv = *(const float4*)&hs[pg * 4 + j][cg_ * 4];
            acc[j] += w0 * hv.x + w1 * hv.y + w2 * hv.z + w3 * hv.w;
        }
    }
    #pragma unroll
    for (int j = 0; j < 4; ++j)
        out[(size_t)(n * CIN + o) * HW + p0 + pg * 4 + j] = acc[j];
}

// ---------------------------------------------------------------------------
extern "C" void kernel_launch(void* const* d_in, const int* in_sizes, int n_in,
                              void* d_out, int out_size, void* d_ws, size_t ws_size,
                              hipStream_t stream) {
    const float* x     = (const float*)d_in[0];
    const float* W_in  = (const float*)d_in[1];
    const float* b_in  = (const float*)d_in[2];
    const float* Wq    = (const float*)d_in[3];
    const float* Wk    = (const float*)d_in[4];
    const float* Wv    = (const float*)d_in[5];
    const float* Wproj = (const float*)d_in[6];
    const float* b_g   = (const float*)d_in[7];
    const float* W_out = (const float*)d_in[8];
    const float* b_out = (const float*)d_in[9];
    float* out = (float*)d_out;

    float* q0   = (float*)d_ws;          // 589824
    float* k0   = q0 + 589824;           // 541696
    float* v0   = k0 + 541696;           // 541696
    float* v2   = v0 + 541696;           // 541696
    float* a0   = v2 + 541696;           // 589824
    float* a2m  = a0 + 589824;           // 256
    float* c2   = a2m + 256;             // 768
    float* part = c2 + 768;              // 16*36*2*1280 = 1474560
    unsigned short* Qb = (unsigned short*)(part + 1474560);  // 16*144*512
    unsigned short* Kb = Qb + (size_t)16 * QTL * 512;        // 16*136*512
    unsigned short* Vb = Kb + (size_t)16 * NT * 512;         // 16*136*512
    unsigned short* xb = Vb + (size_t)16 * NT * 512;         // 4*2500*128
    unsigned short* Wb = xb + (size_t)4 * 2500 * 128;        // 16*9*4*512
    // total ~27.2 MB of workspace

    k_xin   <<<dim3(10, 4, 16), 256, 0, stream>>>(x, W_in, b_in, xb);
    k_wcvt  <<<dim3(144), 256, 0, stream>>>(Wq, Wk, Wv, Wb);
    k_conv  <<<dim3(48, 4, 4), 256, 0, stream>>>(xb, Wb, q0, k0, v0, v2);
    k_cvt   <<<dim3(144, 16), 256, 0, stream>>>(q0, k0, v0, Qb, Kb, Vb);
    k_mattn <<<dim3(72, 16), 256, 0, stream>>>(Qb, Kb, Vb, part);
    k_acomb <<<dim3(36, 16), 256, 0, stream>>>(part, a0);
    k_mean  <<<dim3(256), 256, 0, stream>>>(v2, a2m);
    k_const2<<<dim3(4), 256, 0, stream>>>(Wproj, b_g, a2m, c2);
    k_gates <<<dim3(144, 4), 256, 0, stream>>>(a0, c2, Wproj, W_out, b_out, out);
}

// Round 10
// 206.935 us; speedup vs baseline: 1.3794x; 1.0062x over previous
//
#include <hip/hip_runtime.h>
#include <math.h>

// Problem constants
#define NB   4      // batch
#define CIN  64     // channels everywhere (I=CR=CA=CO=64)
#define HH   48
#define WW   48
#define HW   2304   // 48*48
#define DH   46
#define DW   46
#define DD   2116   // 46*46
#define NHEAD 4
#define HC   16
#define NT   136    // padded d-tiles (2176 = 136*16; 60 zero-pads)
#define QTL  144    // q-tiles (2304 = 144*16)

typedef short  s4 __attribute__((ext_vector_type(4)));
typedef short  s8 __attribute__((ext_vector_type(8)));
typedef float  f4 __attribute__((ext_vector_type(4)));

// ---------------------------------------------------------------------------
// Input 1x1 conv, emitted directly as conv-ready bf16x2:
// xb[n][cell(50x50, 1-px zero border)][128]; per cell 16 groups of 8 shorts:
// group (kq,quad) = {hi[ic=kq*16+quad*4 ..+3], lo[same]}.
// grid (10, 4 n, 16 ocg), block 256. Border cells = zeros (conv padding).
__global__ __launch_bounds__(256) void k_xin(const float* __restrict__ x,
                                             const float* __restrict__ Win,
                                             const float* __restrict__ bin,
                                             unsigned short* __restrict__ xb) {
    int cell = blockIdx.x * 256 + threadIdx.x;
    if (cell >= 2500) return;
    int n = blockIdx.y, ocg = blockIdx.z;        // oc = ocg*4 .. +3
    int cy = cell / 50, cx = cell - cy * 50;
    float a[4] = {0.f, 0.f, 0.f, 0.f};
    if (cy >= 1 && cy <= 48 && cx >= 1 && cx <= 48) {
        int px = (cy - 1) * 48 + (cx - 1);
        const float* xp = x + (size_t)(n * CIN) * HW + px;
        #pragma unroll
        for (int j = 0; j < 4; ++j) a[j] = bin[ocg * 4 + j];
        #pragma unroll 8
        for (int ic = 0; ic < CIN; ++ic) {
            float xv = xp[ic * HW];
            a[0] += Win[(ocg * 4 + 0) * CIN + ic] * xv;
            a[1] += Win[(ocg * 4 + 1) * CIN + ic] * xv;
            a[2] += Win[(ocg * 4 + 2) * CIN + ic] * xv;
            a[3] += Win[(ocg * 4 + 3) * CIN + ic] * xv;
        }
    }
    s8 st;
    #pragma unroll
    for (int j = 0; j < 4; ++j) {
        unsigned u = __builtin_bit_cast(unsigned, a[j]);
        st[j] = (short)(u >> 16);
        float lo = a[j] - __builtin_bit_cast(float, u & 0xffff0000u);
        st[4 + j] = (short)(__builtin_bit_cast(unsigned, lo) >> 16);
    }
    *(s8*)(xb + ((size_t)(n * 2500 + cell)) * 128 + ocg * 8) = st;
}

// ---------------------------------------------------------------------------
// Repack conv weights into MFMA A-fragment order, bf16x2.
// grid (144 = cq*9+tap), block 256.
__global__ __launch_bounds__(256) void k_wcvt(const float* __restrict__ Wq,
                                              const float* __restrict__ Wk,
                                              const float* __restrict__ Wv,
                                              unsigned short* __restrict__ Wb) {
    int bx = blockIdx.x;
    int cq = bx / 9, tap = bx - cq * 9;
    int cv = cq >> 2, ocq = cq & 3;
    const float* src = (cv == 0) ? Wq : (cv == 1) ? Wk : (cv == 2) ? Wv
                                                      : (Wv + 2 * CIN * CIN * 9);
    int t = threadIdx.x;
    int m = t >> 4, kl = t & 15, quad = kl >> 2, j = kl & 3;
    #pragma unroll
    for (int kq = 0; kq < 4; ++kq) {
        float v = src[((size_t)(ocq * 16 + m) * CIN + kq * 16 + kl) * 9 + tap];
        unsigned u = __builtin_bit_cast(unsigned, v);
        float lo = v - __builtin_bit_cast(float, u & 0xffff0000u);
        size_t base = ((size_t)(cq * 9 + tap) * 4 + kq) * 512 + m * 32 + quad * 8 + j;
        Wb[base]     = (unsigned short)(u >> 16);
        Wb[base + 4] = (unsigned short)(__builtin_bit_cast(unsigned, lo) >> 16);
    }
}

// ---------------------------------------------------------------------------
// Implicit-GEMM 3x3 conv on MFMA, FULLY UNROLLED (9 taps x 16 b128 loads +
// 36 MFMAs straight-line; no loop-carried prefetch registers for the
// optimizer to collapse — round-8's rolled loop pinned VGPR=24 and
// serialized every step on vmcnt(0)). fp32 epilogue (round-8-proven).
// grid (48 y, 4 n, 4 cv), block 256 = 4 waves = 4 oc-groups.
__global__ __launch_bounds__(256) void k_conv(const unsigned short* __restrict__ xb,
                                              const unsigned short* __restrict__ Wb,
                                              float* __restrict__ q0, float* __restrict__ k0,
                                              float* __restrict__ v0, float* __restrict__ v2) {
    int y = blockIdx.x, n = blockIdx.y, cv = blockIdx.z;
    float* ob; int outw, pd;
    if (cv == 0)      { ob = q0; outw = 48; pd = 0; }   // SAME
    else if (cv == 1) { ob = k0; outw = 46; pd = 1; }   // VALID
    else if (cv == 2) { ob = v0; outw = 46; pd = 1; }
    else              { ob = v2; outw = 46; pd = 1; }
    if (y >= outw) return;
    int lane = threadIdx.x & 63, wv = threadIdx.x >> 6;
    int m16 = lane & 15, quad = lane >> 4;
    const unsigned short* Wt = Wb + (size_t)(cv * 4 + wv) * 9 * 2048 + m16 * 32 + quad * 8;
    // per-lane base cell (tile 0, tap 0): row y+pd, col pd+m16; tap adds dy*50+dx.
    // OOB impossible: worst cell index 48*50+50 = 2450 < 2500 (garbage cols are
    // masked at store; padded border cells are zeros).
    const unsigned short* B0 = xb + ((size_t)n * 2500 + (size_t)(y + pd) * 50 + pd + m16) * 128 + quad * 8;

    f4 a0 = {0.f, 0.f, 0.f, 0.f}, a1 = a0, a2 = a0;

    #pragma unroll
    for (int tap = 0; tap < 9; ++tap) {
        int dy = tap / 3, dx = tap - dy * 3;
        const unsigned short* bp = B0 + (size_t)(dy * 50 + dx) * 128;
        const unsigned short* wp = Wt + tap * 2048;
        s8 w[4], c0[4], c1[4], c2[4];
        #pragma unroll
        for (int kq = 0; kq < 4; ++kq) {
            w[kq]  = *(const s8*)(wp + kq * 512);
            c0[kq] = *(const s8*)(bp + kq * 32);
            c1[kq] = *(const s8*)(bp + 16 * 128 + kq * 32);
            c2[kq] = *(const s8*)(bp + 32 * 128 + kq * 32);
        }
        #pragma unroll
        for (int kq = 0; kq < 4; ++kq) {
            s4 ah  = __builtin_shufflevector(w[kq], w[kq], 0, 1, 2, 3);
            s4 al  = __builtin_shufflevector(w[kq], w[kq], 4, 5, 6, 7);
            s4 bh0 = __builtin_shufflevector(c0[kq], c0[kq], 0, 1, 2, 3);
            s4 bl0 = __builtin_shufflevector(c0[kq], c0[kq], 4, 5, 6, 7);
            s4 bh1 = __builtin_shufflevector(c1[kq], c1[kq], 0, 1, 2, 3);
            s4 bl1 = __builtin_shufflevector(c1[kq], c1[kq], 4, 5, 6, 7);
            s4 bh2 = __builtin_shufflevector(c2[kq], c2[kq], 0, 1, 2, 3);
            s4 bl2 = __builtin_shufflevector(c2[kq], c2[kq], 4, 5, 6, 7);
            a0 = __builtin_amdgcn_mfma_f32_16x16x16bf16_1k(ah, bh0, a0, 0, 0, 0);
            a1 = __builtin_amdgcn_mfma_f32_16x16x16bf16_1k(ah, bh1, a1, 0, 0, 0);
            a2 = __builtin_amdgcn_mfma_f32_16x16x16bf16_1k(ah, bh2, a2, 0, 0, 0);
            a0 = __builtin_amdgcn_mfma_f32_16x16x16bf16_1k(al, bh0, a0, 0, 0, 0);
            a1 = __builtin_amdgcn_mfma_f32_16x16x16bf16_1k(al, bh1, a1, 0, 0, 0);
            a2 = __builtin_amdgcn_mfma_f32_16x16x16bf16_1k(al, bh2, a2, 0, 0, 0);
            a0 = __builtin_amdgcn_mfma_f32_16x16x16bf16_1k(ah, bl0, a0, 0, 0, 0);
            a1 = __builtin_amdgcn_mfma_f32_16x16x16bf16_1k(ah, bl1, a1, 0, 0, 0);
            a2 = __builtin_amdgcn_mfma_f32_16x16x16bf16_1k(ah, bl2, a2, 0, 0, 0);
        }
    }

    size_t outsz = (size_t)outw * outw;
    float* opb = ob + (size_t)(n * CIN + wv * 16 + quad * 4) * outsz + (size_t)y * outw;
    {   // tiles 0,1 always in-bounds (m16<=15, 16+m16<=31 < 46)
        float* op = opb + m16;
        op[0] = a0.x; op[outsz] = a0.y; op[2 * outsz] = a0.z; op[3 * outsz] = a0.w;
        op = opb + 16 + m16;
        op[0] = a1.x; op[outsz] = a1.y; op[2 * outsz] = a1.z; op[3 * outsz] = a1.w;
    }
    if (32 + m16 < outw) {
        float* op = opb + 32 + m16;
        op[0] = a2.x; op[outsz] = a2.y; op[2 * outsz] = a2.z; op[3 * outsz] = a2.w;
    }
}

// ---------------------------------------------------------------------------
// Convert q0/k0/v0 fp32 -> MFMA-tiled bf16x2 (hi/lo planes, truncation split).
// grid (144, 16 nh), block 256.
__global__ __launch_bounds__(256) void k_cvt(const float* __restrict__ q0,
                                             const float* __restrict__ k0,
                                             const float* __restrict__ v0,
                                             unsigned short* __restrict__ Qb,
                                             unsigned short* __restrict__ Kb,
                                             unsigned short* __restrict__ Vb) {
    __shared__ float sm[272];            // 16x16 transpose pad 17
    int bx = blockIdx.x, nh = blockIdx.y;
    int n = nh >> 2, h = nh & 3;
    int t = threadIdx.x;
    {
        int c = t >> 4, q = t & 15;
        float val = q0[(size_t)(n * CIN + h * HC + c) * HW + bx * 16 + q];
        sm[c * 17 + q] = val;
        __syncthreads();
        int q2 = t >> 4, c2 = t & 15;
        float v = sm[c2 * 17 + q2];
        unsigned u = __builtin_bit_cast(unsigned, v);
        unsigned short* dst = Qb + (size_t)(nh * QTL + bx) * 512;
        dst[t] = (unsigned short)(u >> 16);
        float lo = v - __builtin_bit_cast(float, u & 0xffff0000u);
        dst[256 + t] = (unsigned short)(__builtin_bit_cast(unsigned, lo) >> 16);
    }
    if (bx < NT) {
        __syncthreads();
        int c = t >> 4, d = t & 15;
        int dgl = bx * 16 + d;
        float kv = (dgl < DD) ? k0[(size_t)(n * CIN + h * HC + c) * DD + dgl] : 0.f;
        sm[c * 17 + d] = kv;
        __syncthreads();
        {
            int d2 = t >> 4, c2 = t & 15;
            float v = sm[c2 * 17 + d2];
            unsigned u = __builtin_bit_cast(unsigned, v);
            unsigned short* dst = Kb + (size_t)(nh * NT + bx) * 512;
            dst[t] = (unsigned short)(u >> 16);
            float lo = v - __builtin_bit_cast(float, u & 0xffff0000u);
            dst[256 + t] = (unsigned short)(__builtin_bit_cast(unsigned, lo) >> 16);
        }
        {
            float vv = (dgl < DD) ? v0[(size_t)(n * CIN + h * HC + c) * DD + dgl] : 0.f;
            unsigned u = __builtin_bit_cast(unsigned, vv);
            unsigned short* dst = Vb + (size_t)(nh * NT + bx) * 512;
            dst[t] = (unsigned short)(u >> 16);
            float lo = vv - __builtin_bit_cast(float, u & 0xffff0000u);
            dst[256 + t] = (unsigned short)(__builtin_bit_cast(unsigned, lo) >> 16);
        }
    }
}

// ---------------------------------------------------------------------------
// MFMA attention (validated round 5). grid (72, 16 nh), block 256.
__global__ __launch_bounds__(256) void k_mattn(const unsigned short* __restrict__ Qb,
                                               const unsigned short* __restrict__ Kb,
                                               const unsigned short* __restrict__ Vb,
                                               float* __restrict__ part) {
    __shared__ float sO[4][4][256];
    __shared__ float sl[4][4][64];
    int strip = blockIdx.x >> 1, hb = blockIdx.x & 1, nh = blockIdx.y;
    int lane = threadIdx.x & 63, wv = threadIdx.x >> 6;
    int ds = hb * 4 + wv;
    int q16 = lane & 15, quad = lane >> 4;
    int foff = q16 * 16 + quad * 4;

    s4 qh[4], ql[4];
    #pragma unroll
    for (int j = 0; j < 4; ++j) {
        const unsigned short* Qp = Qb + (size_t)(nh * QTL + strip * 4 + j) * 512 + foff;
        qh[j] = *(const s4*)(Qp);
        ql[j] = *(const s4*)(Qp + 256);
    }
    f4 O[4];
    float l[4];
    #pragma unroll
    for (int j = 0; j < 4; ++j) { O[j] = (f4){0.f, 0.f, 0.f, 0.f}; l[j] = 0.f; }

    const unsigned short* Kp = Kb + (size_t)(nh * NT + ds * 17) * 512 + foff;
    const unsigned short* Vp = Vb + (size_t)(nh * NT + ds * 17) * 512 + foff;
    s4 khi = *(const s4*)(Kp);
    s4 klo = *(const s4*)(Kp + 256);
    s4 vhi = *(const s4*)(Vp);
    s4 vlo = *(const s4*)(Vp + 256);

    for (int it = 0; it < 17; ++it) {
        int nxt = (it < 16) ? (it + 1) * 512 : 0;
        s4 nkhi = *(const s4*)(Kp + nxt);
        s4 nklo = *(const s4*)(Kp + nxt + 256);
        s4 nvhi = *(const s4*)(Vp + nxt);
        s4 nvlo = *(const s4*)(Vp + nxt + 256);

        #pragma unroll
        for (int j = 0; j < 4; ++j) {
            f4 c1 = (f4){0.f, 0.f, 0.f, 0.f};
            c1 = __builtin_amdgcn_mfma_f32_16x16x16bf16_1k(khi, qh[j], c1, 0, 0, 0);
            c1 = __builtin_amdgcn_mfma_f32_16x16x16bf16_1k(klo, qh[j], c1, 0, 0, 0);
            c1 = __builtin_amdgcn_mfma_f32_16x16x16bf16_1k(khi, ql[j], c1, 0, 0, 0);
            float p0 = __expf(c1.x), p1 = __expf(c1.y);
            float p2 = __expf(c1.z), p3 = __expf(c1.w);
            l[j] += (p0 + p1) + (p2 + p3);
            unsigned u0 = __builtin_bit_cast(unsigned, p0);
            unsigned u1 = __builtin_bit_cast(unsigned, p1);
            unsigned u2 = __builtin_bit_cast(unsigned, p2);
            unsigned u3 = __builtin_bit_cast(unsigned, p3);
            s4 ph;
            ph.x = (short)(u0 >> 16); ph.y = (short)(u1 >> 16);
            ph.z = (short)(u2 >> 16); ph.w = (short)(u3 >> 16);
            float r0 = p0 - __builtin_bit_cast(float, u0 & 0xffff0000u);
            float r1 = p1 - __builtin_bit_cast(float, u1 & 0xffff0000u);
            float r2 = p2 - __builtin_bit_cast(float, u2 & 0xffff0000u);
            float r3 = p3 - __builtin_bit_cast(float, u3 & 0xffff0000u);
            s4 pl;
            pl.x = (short)(__builtin_bit_cast(unsigned, r0) >> 16);
            pl.y = (short)(__builtin_bit_cast(unsigned, r1) >> 16);
            pl.z = (short)(__builtin_bit_cast(unsigned, r2) >> 16);
            pl.w = (short)(__builtin_bit_cast(unsigned, r3) >> 16);
            O[j] = __builtin_amdgcn_mfma_f32_16x16x16bf16_1k(vhi, ph, O[j], 0, 0, 0);
            O[j] = __builtin_amdgcn_mfma_f32_16x16x16bf16_1k(vlo, ph, O[j], 0, 0, 0);
            O[j] = __builtin_amdgcn_mfma_f32_16x16x16bf16_1k(vhi, pl, O[j], 0, 0, 0);
        }
        khi = nkhi; klo = nklo; vhi = nvhi; vlo = nvlo;
    }

    #pragma unroll
    for (int j = 0; j < 4; ++j) {
        sO[wv][j][(quad * 4 + 0) * 16 + q16] = O[j].x;
        sO[wv][j][(quad * 4 + 1) * 16 + q16] = O[j].y;
        sO[wv][j][(quad * 4 + 2) * 16 + q16] = O[j].z;
        sO[wv][j][(quad * 4 + 3) * 16 + q16] = O[j].w;
        sl[wv][j][quad * 16 + q16] = l[j];
    }
    __syncthreads();
    int t = threadIdx.x;
    float* pb = part + (size_t)((nh * 36 + strip) * 2 + hb) * 1280;
    #pragma unroll
    for (int j = 0; j < 4; ++j)
        pb[j * 256 + t] = (sO[0][j][t] + sO[1][j][t]) + (sO[2][j][t] + sO[3][j][t]);
    {
        int j2 = t >> 6, i2 = t & 63;
        pb[1024 + t] = (sl[0][j2][i2] + sl[1][j2][i2]) + (sl[2][j2][i2] + sl[3][j2][i2]);
    }
}

// ---------------------------------------------------------------------------
// Combine the 2 D-half partials, subtract the 60 pad-exp(0) terms, normalize.
__global__ __launch_bounds__(256) void k_acomb(const float* __restrict__ part,
                                               float* __restrict__ a0) {
    int strip = blockIdx.x, nh = blockIdx.y;
    int n = nh >> 2, h = nh & 3;
    const float* b0 = part + (size_t)((nh * 36 + strip) * 2) * 1280;
    const float* b1 = b0 + 1280;
    int t = threadIdx.x;
    int q = t & 15, c = t >> 4;
    #pragma unroll
    for (int j = 0; j < 4; ++j) {
        float lsum = 0.f;
        #pragma unroll
        for (int qd = 0; qd < 4; ++qd)
            lsum += b0[1024 + j * 64 + qd * 16 + q] + b1[1024 + j * 64 + qd * 16 + q];
        float inv = 1.f / (lsum - 60.f);
        float v = (b0[j * 256 + c * 16 + q] + b1[j * 256 + c * 16 + q]) * inv;
        a0[(size_t)(n * CIN + h * HC + c) * HW + strip * 64 + j * 16 + q] = v;
    }
}

// ---------------------------------------------------------------------------
// A2mean[n,c] = mean over 2116 positions of v2[n,c,:]
__global__ __launch_bounds__(256) void k_mean(const float* __restrict__ v2,
                                              float* __restrict__ a2m) {
    int n = blockIdx.x >> 6, c = blockIdx.x & 63;
    const float* p = v2 + (size_t)(n * CIN + c) * DD;
    float s = 0.f;
    for (int d = threadIdx.x; d < DD; d += 256) s += p[d];
    #pragma unroll
    for (int off = 32; off > 0; off >>= 1) s += __shfl_down(s, off);
    __shared__ float red[4];
    int lane = threadIdx.x & 63, wv = threadIdx.x >> 6;
    if (lane == 0) red[wv] = s;
    __syncthreads();
    if (threadIdx.x == 0)
        a2m[blockIdx.x] = (red[0] + red[1] + red[2] + red[3]) * (1.f / 2116.f);
}

// ---------------------------------------------------------------------------
__global__ __launch_bounds__(256) void k_const2(const float* __restrict__ Wproj,
                                                const float* __restrict__ bg,
                                                const float* __restrict__ a2m,
                                                float* __restrict__ c2) {
    int n = blockIdx.x;
    int t = threadIdx.x;
    if (t >= 192) return;
    int gi = t >> 6, o = t & 63;
    int g = (gi == 0) ? 0 : (gi == 1) ? 2 : 3;
    float acc = bg[g * CIN + o];
    const float* wp = Wproj + ((size_t)(g * 4 + 2) * CIN + o) * CIN;
    for (int c = 0; c < CIN; ++c) acc += wp[c] * a2m[n * CIN + c];
    c2[(gi * NB + n) * CIN + o] = acc;
}

// ---------------------------------------------------------------------------
// Gates + LSTM nonlinearity + output 1x1 conv, fused (unchanged).
__global__ __launch_bounds__(256) void k_gates(const float* __restrict__ a0,
                                               const float* __restrict__ c2,
                                               const float* __restrict__ Wproj,
                                               const float* __restrict__ Wout,
                                               const float* __restrict__ bout,
                                               float* __restrict__ out) {
    __shared__ float a0s[64][16];
    __shared__ float wps[3][64][64];
    __shared__ float hs[16][68];
    int n = blockIdx.y;
    int p0 = blockIdx.x * 16;
    int tid = threadIdx.x;

    for (int idx = tid; idx < 1024; idx += 256) {
        int c = idx >> 4, px = idx & 15;
        a0s[c][px] = a0[(size_t)(n * CIN + c) * HW + p0 + px];
    }
    for (int idx = tid; idx < 12288; idx += 256) {
        int o = idx & 63; int rest = idx >> 6; int c = rest & 63; int gi = rest >> 6;
        int g = (gi == 0) ? 0 : (gi == 1) ? 2 : 3;
        wps[gi][c][o] = Wproj[((size_t)(g * 4 + 0) * CIN + o) * CIN + c];
    }
    __syncthreads();

    int o = tid & 63, pg = tid >> 6;
    float pi[4], pgt[4], po[4];
    {
        float ci = c2[(0 * NB + n) * CIN + o];
        float cg = c2[(1 * NB + n) * CIN + o];
        float co = c2[(2 * NB + n) * CIN + o];
        #pragma unroll
        for (int j = 0; j < 4; ++j) { pi[j] = ci; pgt[j] = cg; po[j] = co; }
    }
    const float4* a4 = (const float4*)&a0s[0][0];
    #pragma unroll 4
    for (int c = 0; c < 64; ++c) {
        float4 av = a4[c * 4 + pg];
        float w0 = wps[0][c][o], w1 = wps[1][c][o], w2 = wps[2][c][o];
        pi[0]  += w0 * av.x; pi[1]  += w0 * av.y; pi[2]  += w0 * av.z; pi[3]  += w0 * av.w;
        pgt[0] += w1 * av.x; pgt[1] += w1 * av.y; pgt[2] += w1 * av.z; pgt[3] += w1 * av.w;
        po[0]  += w2 * av.x; po[1]  += w2 * av.y; po[2]  += w2 * av.z; po[3]  += w2 * av.w;
    }
    #pragma unroll
    for (int j = 0; j < 4; ++j) {
        float ii = 1.f / (1.f + __expf(-pi[j]));
        float gg = tanhf(pgt[j]);
        float oo = 1.f / (1.f + __expf(-po[j]));
        float cc = ii * gg;
        hs[pg * 4 + j][o] = oo * tanhf(cc);
    }
    __syncthreads();
    float acc[4];
    float bo = bout[o];
    #pragma unroll
    for (int j = 0; j < 4; ++j) acc[j] = bo;
    const float* wo = Wout + o * CIN;
    #pragma unroll 2
    for (int cg_ = 0; cg_ < 16; ++cg_) {
        float w0 = wo[cg_ * 4 + 0], w1 = wo[cg_ * 4 + 1], w2 = wo[cg_ * 4 + 2], w3 = wo[cg_ * 4 + 3];
        #pragma unroll
        for (int j = 0; j < 4; ++j) {
            const float4 hv = *(const float4*)&hs[pg * 4 + j][cg_ * 4];
            acc[j] += w0 * hv.x + w1 * hv.y + w2 * hv.z + w3 * hv.w;
        }
    }
    #pragma unroll
    for (int j = 0; j < 4; ++j)
        out[(size_t)(n * CIN + o) * HW + p0 + pg * 4 + j] = acc[j];
}

// ---------------------------------------------------------------------------
extern "C" void kernel_launch(void* const* d_in, const int* in_sizes, int n_in,
                              void* d_out, int out_size, void* d_ws, size_t ws_size,
                              hipStream_t stream) {
    const float* x     = (const float*)d_in[0];
    const float* W_in  = (const float*)d_in[1];
    const float* b_in  = (const float*)d_in[2];
    const float* Wq    = (const float*)d_in[3];
    const float* Wk    = (const float*)d_in[4];
    const float* Wv    = (const float*)d_in[5];
    const float* Wproj = (const float*)d_in[6];
    const float* b_g   = (const float*)d_in[7];
    const float* W_out = (const float*)d_in[8];
    const float* b_out = (const float*)d_in[9];
    float* out = (float*)d_out;

    float* q0   = (float*)d_ws;          // 589824
    float* k0   = q0 + 589824;           // 541696
    float* v0   = k0 + 541696;           // 541696
    float* v2   = v0 + 541696;           // 541696
    float* a0   = v2 + 541696;           // 589824
    float* a2m  = a0 + 589824;           // 256
    float* c2   = a2m + 256;             // 768
    float* part = c2 + 768;              // 16*36*2*1280 = 1474560
    unsigned short* Qb = (unsigned short*)(part + 1474560);  // 16*144*512
    unsigned short* Kb = Qb + (size_t)16 * QTL * 512;        // 16*136*512
    unsigned short* Vb = Kb + (size_t)16 * NT * 512;         // 16*136*512
    unsigned short* xb = Vb + (size_t)16 * NT * 512;         // 4*2500*128
    unsigned short* Wb = xb + (size_t)4 * 2500 * 128;        // 16*9*4*512
    // total ~27 MB of workspace

    k_xin   <<<dim3(10, 4, 16), 256, 0, stream>>>(x, W_in, b_in, xb);
    k_wcvt  <<<dim3(144), 256, 0, stream>>>(Wq, Wk, Wv, Wb);
    k_conv  <<<dim3(48, 4, 4), 256, 0, stream>>>(xb, Wb, q0, k0, v0, v2);
    k_cvt   <<<dim3(144, 16), 256, 0, stream>>>(q0, k0, v0, Qb, Kb, Vb);
    k_mattn <<<dim3(72, 16), 256, 0, stream>>>(Qb, Kb, Vb, part);
    k_acomb <<<dim3(36, 16), 256, 0, stream>>>(part, a0);
    k_mean  <<<dim3(256), 256, 0, stream>>>(v2, a2m);
    k_const2<<<dim3(4), 256, 0, stream>>>(Wproj, b_g, a2m, c2);
    k_gates <<<dim3(144, 4), 256, 0, stream>>>(a0, c2, Wproj, W_out, b_out, out);
}

// Round 11
// 206.868 us; speedup vs baseline: 1.3799x; 1.0003x over previous
//
#include <hip/hip_runtime.h>
#include <math.h>

// Problem constants
#define NB   4      // batch
#define CIN  64     // channels everywhere (I=CR=CA=CO=64)
#define HH   48
#define WW   48
#define HW   2304   // 48*48
#define DH   46
#define DW   46
#define DD   2116   // 46*46
#define NHEAD 4
#define HC   16
#define NT   136    // padded d-tiles (2176 = 136*16; 60 zero-pads)
#define QTL  144    // q-tiles (2304 = 144*16)

typedef short  s4 __attribute__((ext_vector_type(4)));
typedef short  s8 __attribute__((ext_vector_type(8)));
typedef float  f4 __attribute__((ext_vector_type(4)));

// ---------------------------------------------------------------------------
// Input 1x1 conv, emitted directly as conv-ready bf16x2:
// xb[n][cell(50x50, 1-px zero border)][128]; per cell 16 groups of 8 shorts:
// group (kq,quad) = {hi[ic=kq*16+quad*4 ..+3], lo[same]}.
// grid (10, 4 n, 16 ocg), block 256. Border cells = zeros (conv padding).
__global__ __launch_bounds__(256) void k_xin(const float* __restrict__ x,
                                             const float* __restrict__ Win,
                                             const float* __restrict__ bin,
                                             unsigned short* __restrict__ xb) {
    int cell = blockIdx.x * 256 + threadIdx.x;
    if (cell >= 2500) return;
    int n = blockIdx.y, ocg = blockIdx.z;        // oc = ocg*4 .. +3
    int cy = cell / 50, cx = cell - cy * 50;
    float a[4] = {0.f, 0.f, 0.f, 0.f};
    if (cy >= 1 && cy <= 48 && cx >= 1 && cx <= 48) {
        int px = (cy - 1) * 48 + (cx - 1);
        const float* xp = x + (size_t)(n * CIN) * HW + px;
        #pragma unroll
        for (int j = 0; j < 4; ++j) a[j] = bin[ocg * 4 + j];
        #pragma unroll 8
        for (int ic = 0; ic < CIN; ++ic) {
            float xv = xp[ic * HW];
            a[0] += Win[(ocg * 4 + 0) * CIN + ic] * xv;
            a[1] += Win[(ocg * 4 + 1) * CIN + ic] * xv;
            a[2] += Win[(ocg * 4 + 2) * CIN + ic] * xv;
            a[3] += Win[(ocg * 4 + 3) * CIN + ic] * xv;
        }
    }
    s8 st;
    #pragma unroll
    for (int j = 0; j < 4; ++j) {
        unsigned u = __builtin_bit_cast(unsigned, a[j]);
        st[j] = (short)(u >> 16);
        float lo = a[j] - __builtin_bit_cast(float, u & 0xffff0000u);
        st[4 + j] = (short)(__builtin_bit_cast(unsigned, lo) >> 16);
    }
    *(s8*)(xb + ((size_t)(n * 2500 + cell)) * 128 + ocg * 8) = st;
}

// ---------------------------------------------------------------------------
// Repack conv weights into MFMA A-fragment order, bf16x2.
// grid (144 = cq*9+tap), block 256.
__global__ __launch_bounds__(256) void k_wcvt(const float* __restrict__ Wq,
                                              const float* __restrict__ Wk,
                                              const float* __restrict__ Wv,
                                              unsigned short* __restrict__ Wb) {
    int bx = blockIdx.x;
    int cq = bx / 9, tap = bx - cq * 9;
    int cv = cq >> 2, ocq = cq & 3;
    const float* src = (cv == 0) ? Wq : (cv == 1) ? Wk : (cv == 2) ? Wv
                                                      : (Wv + 2 * CIN * CIN * 9);
    int t = threadIdx.x;
    int m = t >> 4, kl = t & 15, quad = kl >> 2, j = kl & 3;
    #pragma unroll
    for (int kq = 0; kq < 4; ++kq) {
        float v = src[((size_t)(ocq * 16 + m) * CIN + kq * 16 + kl) * 9 + tap];
        unsigned u = __builtin_bit_cast(unsigned, v);
        float lo = v - __builtin_bit_cast(float, u & 0xffff0000u);
        size_t base = ((size_t)(cq * 9 + tap) * 4 + kq) * 512 + m * 32 + quad * 8 + j;
        Wb[base]     = (unsigned short)(u >> 16);
        Wb[base + 4] = (unsigned short)(__builtin_bit_cast(unsigned, lo) >> 16);
    }
}

// ---------------------------------------------------------------------------
// Implicit-GEMM 3x3 conv on MFMA, fully unrolled + explicit two-tap software
// pipeline. __launch_bounds__(256,3): target 3 waves/SIMD (= our real
// occupancy at 768 blocks = 3 blocks/CU) -> VGPR cap ~168, enough to hold
// the next tap's 16 b128 loads in flight (round-10's default budget sank
// every load to its use: VGPR=36, MfmaUtil 11%).
// grid (48 y, 4 n, 4 cv), block 256 = 4 waves = 4 oc-groups.
__global__ __launch_bounds__(256, 3) void k_conv(const unsigned short* __restrict__ xb,
                                                 const unsigned short* __restrict__ Wb,
                                                 float* __restrict__ q0, float* __restrict__ k0,
                                                 float* __restrict__ v0, float* __restrict__ v2) {
    int y = blockIdx.x, n = blockIdx.y, cv = blockIdx.z;
    float* ob; int outw, pd;
    if (cv == 0)      { ob = q0; outw = 48; pd = 0; }   // SAME
    else if (cv == 1) { ob = k0; outw = 46; pd = 1; }   // VALID
    else if (cv == 2) { ob = v0; outw = 46; pd = 1; }
    else              { ob = v2; outw = 46; pd = 1; }
    if (y >= outw) return;
    int lane = threadIdx.x & 63, wv = threadIdx.x >> 6;
    int m16 = lane & 15, quad = lane >> 4;
    const unsigned short* Wt = Wb + (size_t)(cv * 4 + wv) * 9 * 2048 + m16 * 32 + quad * 8;
    // per-lane base cell (tile 0, tap 0): row y+pd, col pd+m16; tap adds dy*50+dx.
    // OOB impossible: worst cell index 48*50+50 = 2450 < 2500.
    const unsigned short* B0 = xb + ((size_t)n * 2500 + (size_t)(y + pd) * 50 + pd + m16) * 128 + quad * 8;

    f4 a0 = {0.f, 0.f, 0.f, 0.f}, a1 = a0, a2 = a0;

    s8 w[4], c0[4], c1[4], c2[4];          // current tap's fragments
    #pragma unroll
    for (int kq = 0; kq < 4; ++kq) {       // prefetch tap 0
        w[kq]  = *(const s8*)(Wt + kq * 512);
        c0[kq] = *(const s8*)(B0 + kq * 32);
        c1[kq] = *(const s8*)(B0 + 16 * 128 + kq * 32);
        c2[kq] = *(const s8*)(B0 + 32 * 128 + kq * 32);
    }

    #pragma unroll
    for (int tap = 0; tap < 9; ++tap) {
        s8 wn[4], n0[4], n1[4], n2[4];     // next tap's fragments (issued first)
        if (tap < 8) {
            int tn = tap + 1;
            int dy = tn / 3, dx = tn - dy * 3;
            const unsigned short* bp = B0 + (size_t)(dy * 50 + dx) * 128;
            const unsigned short* wp = Wt + tn * 2048;
            #pragma unroll
            for (int kq = 0; kq < 4; ++kq) {
                wn[kq] = *(const s8*)(wp + kq * 512);
                n0[kq] = *(const s8*)(bp + kq * 32);
                n1[kq] = *(const s8*)(bp + 16 * 128 + kq * 32);
                n2[kq] = *(const s8*)(bp + 32 * 128 + kq * 32);
            }
        }
        #pragma unroll
        for (int kq = 0; kq < 4; ++kq) {
            s4 ah  = __builtin_shufflevector(w[kq], w[kq], 0, 1, 2, 3);
            s4 al  = __builtin_shufflevector(w[kq], w[kq], 4, 5, 6, 7);
            s4 bh0 = __builtin_shufflevector(c0[kq], c0[kq], 0, 1, 2, 3);
            s4 bl0 = __builtin_shufflevector(c0[kq], c0[kq], 4, 5, 6, 7);
            s4 bh1 = __builtin_shufflevector(c1[kq], c1[kq], 0, 1, 2, 3);
            s4 bl1 = __builtin_shufflevector(c1[kq], c1[kq], 4, 5, 6, 7);
            s4 bh2 = __builtin_shufflevector(c2[kq], c2[kq], 0, 1, 2, 3);
            s4 bl2 = __builtin_shufflevector(c2[kq], c2[kq], 4, 5, 6, 7);
            a0 = __builtin_amdgcn_mfma_f32_16x16x16bf16_1k(ah, bh0, a0, 0, 0, 0);
            a1 = __builtin_amdgcn_mfma_f32_16x16x16bf16_1k(ah, bh1, a1, 0, 0, 0);
            a2 = __builtin_amdgcn_mfma_f32_16x16x16bf16_1k(ah, bh2, a2, 0, 0, 0);
            a0 = __builtin_amdgcn_mfma_f32_16x16x16bf16_1k(al, bh0, a0, 0, 0, 0);
            a1 = __builtin_amdgcn_mfma_f32_16x16x16bf16_1k(al, bh1, a1, 0, 0, 0);
            a2 = __builtin_amdgcn_mfma_f32_16x16x16bf16_1k(al, bh2, a2, 0, 0, 0);
            a0 = __builtin_amdgcn_mfma_f32_16x16x16bf16_1k(ah, bl0, a0, 0, 0, 0);
            a1 = __builtin_amdgcn_mfma_f32_16x16x16bf16_1k(ah, bl1, a1, 0, 0, 0);
            a2 = __builtin_amdgcn_mfma_f32_16x16x16bf16_1k(ah, bl2, a2, 0, 0, 0);
        }
        if (tap < 8) {
            #pragma unroll
            for (int kq = 0; kq < 4; ++kq) {   // renames after full unroll
                w[kq] = wn[kq]; c0[kq] = n0[kq]; c1[kq] = n1[kq]; c2[kq] = n2[kq];
            }
        }
    }

    size_t outsz = (size_t)outw * outw;
    float* opb = ob + (size_t)(n * CIN + wv * 16 + quad * 4) * outsz + (size_t)y * outw;
    {   // tiles 0,1 always in-bounds (m16<=15, 16+m16<=31 < 46)
        float* op = opb + m16;
        op[0] = a0.x; op[outsz] = a0.y; op[2 * outsz] = a0.z; op[3 * outsz] = a0.w;
        op = opb + 16 + m16;
        op[0] = a1.x; op[outsz] = a1.y; op[2 * outsz] = a1.z; op[3 * outsz] = a1.w;
    }
    if (32 + m16 < outw) {
        float* op = opb + 32 + m16;
        op[0] = a2.x; op[outsz] = a2.y; op[2 * outsz] = a2.z; op[3 * outsz] = a2.w;
    }
}

// ---------------------------------------------------------------------------
// Convert q0/k0/v0 fp32 -> MFMA-tiled bf16x2 (hi/lo planes, truncation split).
// grid (144, 16 nh), block 256.
__global__ __launch_bounds__(256) void k_cvt(const float* __restrict__ q0,
                                             const float* __restrict__ k0,
                                             const float* __restrict__ v0,
                                             unsigned short* __restrict__ Qb,
                                             unsigned short* __restrict__ Kb,
                                             unsigned short* __restrict__ Vb) {
    __shared__ float sm[272];            // 16x16 transpose pad 17
    int bx = blockIdx.x, nh = blockIdx.y;
    int n = nh >> 2, h = nh & 3;
    int t = threadIdx.x;
    {
        int c = t >> 4, q = t & 15;
        float val = q0[(size_t)(n * CIN + h * HC + c) * HW + bx * 16 + q];
        sm[c * 17 + q] = val;
        __syncthreads();
        int q2 = t >> 4, c2 = t & 15;
        float v = sm[c2 * 17 + q2];
        unsigned u = __builtin_bit_cast(unsigned, v);
        unsigned short* dst = Qb + (size_t)(nh * QTL + bx) * 512;
        dst[t] = (unsigned short)(u >> 16);
        float lo = v - __builtin_bit_cast(float, u & 0xffff0000u);
        dst[256 + t] = (unsigned short)(__builtin_bit_cast(unsigned, lo) >> 16);
    }
    if (bx < NT) {
        __syncthreads();
        int c = t >> 4, d = t & 15;
        int dgl = bx * 16 + d;
        float kv = (dgl < DD) ? k0[(size_t)(n * CIN + h * HC + c) * DD + dgl] : 0.f;
        sm[c * 17 + d] = kv;
        __syncthreads();
        {
            int d2 = t >> 4, c2 = t & 15;
            float v = sm[c2 * 17 + d2];
            unsigned u = __builtin_bit_cast(unsigned, v);
            unsigned short* dst = Kb + (size_t)(nh * NT + bx) * 512;
            dst[t] = (unsigned short)(u >> 16);
            float lo = v - __builtin_bit_cast(float, u & 0xffff0000u);
            dst[256 + t] = (unsigned short)(__builtin_bit_cast(unsigned, lo) >> 16);
        }
        {
            float vv = (dgl < DD) ? v0[(size_t)(n * CIN + h * HC + c) * DD + dgl] : 0.f;
            unsigned u = __builtin_bit_cast(unsigned, vv);
            unsigned short* dst = Vb + (size_t)(nh * NT + bx) * 512;
            dst[t] = (unsigned short)(u >> 16);
            float lo = vv - __builtin_bit_cast(float, u & 0xffff0000u);
            dst[256 + t] = (unsigned short)(__builtin_bit_cast(unsigned, lo) >> 16);
        }
    }
}

// ---------------------------------------------------------------------------
// MFMA attention (validated round 5). grid (72, 16 nh), block 256.
__global__ __launch_bounds__(256) void k_mattn(const unsigned short* __restrict__ Qb,
                                               const unsigned short* __restrict__ Kb,
                                               const unsigned short* __restrict__ Vb,
                                               float* __restrict__ part) {
    __shared__ float sO[4][4][256];
    __shared__ float sl[4][4][64];
    int strip = blockIdx.x >> 1, hb = blockIdx.x & 1, nh = blockIdx.y;
    int lane = threadIdx.x & 63, wv = threadIdx.x >> 6;
    int ds = hb * 4 + wv;
    int q16 = lane & 15, quad = lane >> 4;
    int foff = q16 * 16 + quad * 4;

    s4 qh[4], ql[4];
    #pragma unroll
    for (int j = 0; j < 4; ++j) {
        const unsigned short* Qp = Qb + (size_t)(nh * QTL + strip * 4 + j) * 512 + foff;
        qh[j] = *(const s4*)(Qp);
        ql[j] = *(const s4*)(Qp + 256);
    }
    f4 O[4];
    float l[4];
    #pragma unroll
    for (int j = 0; j < 4; ++j) { O[j] = (f4){0.f, 0.f, 0.f, 0.f}; l[j] = 0.f; }

    const unsigned short* Kp = Kb + (size_t)(nh * NT + ds * 17) * 512 + foff;
    const unsigned short* Vp = Vb + (size_t)(nh * NT + ds * 17) * 512 + foff;
    s4 khi = *(const s4*)(Kp);
    s4 klo = *(const s4*)(Kp + 256);
    s4 vhi = *(const s4*)(Vp);
    s4 vlo = *(const s4*)(Vp + 256);

    for (int it = 0; it < 17; ++it) {
        int nxt = (it < 16) ? (it + 1) * 512 : 0;
        s4 nkhi = *(const s4*)(Kp + nxt);
        s4 nklo = *(const s4*)(Kp + nxt + 256);
        s4 nvhi = *(const s4*)(Vp + nxt);
        s4 nvlo = *(const s4*)(Vp + nxt + 256);

        #pragma unroll
        for (int j = 0; j < 4; ++j) {
            f4 c1 = (f4){0.f, 0.f, 0.f, 0.f};
            c1 = __builtin_amdgcn_mfma_f32_16x16x16bf16_1k(khi, qh[j], c1, 0, 0, 0);
            c1 = __builtin_amdgcn_mfma_f32_16x16x16bf16_1k(klo, qh[j], c1, 0, 0, 0);
            c1 = __builtin_amdgcn_mfma_f32_16x16x16bf16_1k(khi, ql[j], c1, 0, 0, 0);
            float p0 = __expf(c1.x), p1 = __expf(c1.y);
            float p2 = __expf(c1.z), p3 = __expf(c1.w);
            l[j] += (p0 + p1) + (p2 + p3);
            unsigned u0 = __builtin_bit_cast(unsigned, p0);
            unsigned u1 = __builtin_bit_cast(unsigned, p1);
            unsigned u2 = __builtin_bit_cast(unsigned, p2);
            unsigned u3 = __builtin_bit_cast(unsigned, p3);
            s4 ph;
            ph.x = (short)(u0 >> 16); ph.y = (short)(u1 >> 16);
            ph.z = (short)(u2 >> 16); ph.w = (short)(u3 >> 16);
            float r0 = p0 - __builtin_bit_cast(float, u0 & 0xffff0000u);
            float r1 = p1 - __builtin_bit_cast(float, u1 & 0xffff0000u);
            float r2 = p2 - __builtin_bit_cast(float, u2 & 0xffff0000u);
            float r3 = p3 - __builtin_bit_cast(float, u3 & 0xffff0000u);
            s4 pl;
            pl.x = (short)(__builtin_bit_cast(unsigned, r0) >> 16);
            pl.y = (short)(__builtin_bit_cast(unsigned, r1) >> 16);
            pl.z = (short)(__builtin_bit_cast(unsigned, r2) >> 16);
            pl.w = (short)(__builtin_bit_cast(unsigned, r3) >> 16);
            O[j] = __builtin_amdgcn_mfma_f32_16x16x16bf16_1k(vhi, ph, O[j], 0, 0, 0);
            O[j] = __builtin_amdgcn_mfma_f32_16x16x16bf16_1k(vlo, ph, O[j], 0, 0, 0);
            O[j] = __builtin_amdgcn_mfma_f32_16x16x16bf16_1k(vhi, pl, O[j], 0, 0, 0);
        }
        khi = nkhi; klo = nklo; vhi = nvhi; vlo = nvlo;
    }

    #pragma unroll
    for (int j = 0; j < 4; ++j) {
        sO[wv][j][(quad * 4 + 0) * 16 + q16] = O[j].x;
        sO[wv][j][(quad * 4 + 1) * 16 + q16] = O[j].y;
        sO[wv][j][(quad * 4 + 2) * 16 + q16] = O[j].z;
        sO[wv][j][(quad * 4 + 3) * 16 + q16] = O[j].w;
        sl[wv][j][quad * 16 + q16] = l[j];
    }
    __syncthreads();
    int t = threadIdx.x;
    float* pb = part + (size_t)((nh * 36 + strip) * 2 + hb) * 1280;
    #pragma unroll
    for (int j = 0; j < 4; ++j)
        pb[j * 256 + t] = (sO[0][j][t] + sO[1][j][t]) + (sO[2][j][t] + sO[3][j][t]);
    {
        int j2 = t >> 6, i2 = t & 63;
        pb[1024 + t] = (sl[0][j2][i2] + sl[1][j2][i2]) + (sl[2][j2][i2] + sl[3][j2][i2]);
    }
}

// ---------------------------------------------------------------------------
// Combine the 2 D-half partials, subtract the 60 pad-exp(0) terms, normalize.
__global__ __launch_bounds__(256) void k_acomb(const float* __restrict__ part,
                                               float* __restrict__ a0) {
    int strip = blockIdx.x, nh = blockIdx.y;
    int n = nh >> 2, h = nh & 3;
    const float* b0 = part + (size_t)((nh * 36 + strip) * 2) * 1280;
    const float* b1 = b0 + 1280;
    int t = threadIdx.x;
    int q = t & 15, c = t >> 4;
    #pragma unroll
    for (int j = 0; j < 4; ++j) {
        float lsum = 0.f;
        #pragma unroll
        for (int qd = 0; qd < 4; ++qd)
            lsum += b0[1024 + j * 64 + qd * 16 + q] + b1[1024 + j * 64 + qd * 16 + q];
        float inv = 1.f / (lsum - 60.f);
        float v = (b0[j * 256 + c * 16 + q] + b1[j * 256 + c * 16 + q]) * inv;
        a0[(size_t)(n * CIN + h * HC + c) * HW + strip * 64 + j * 16 + q] = v;
    }
}

// ---------------------------------------------------------------------------
// A2mean[n,c] = mean over 2116 positions of v2[n,c,:]
__global__ __launch_bounds__(256) void k_mean(const float* __restrict__ v2,
                                              float* __restrict__ a2m) {
    int n = blockIdx.x >> 6, c = blockIdx.x & 63;
    const float* p = v2 + (size_t)(n * CIN + c) * DD;
    float s = 0.f;
    for (int d = threadIdx.x; d < DD; d += 256) s += p[d];
    #pragma unroll
    for (int off = 32; off > 0; off >>= 1) s += __shfl_down(s, off);
    __shared__ float red[4];
    int lane = threadIdx.x & 63, wv = threadIdx.x >> 6;
    if (lane == 0) red[wv] = s;
    __syncthreads();
    if (threadIdx.x == 0)
        a2m[blockIdx.x] = (red[0] + red[1] + red[2] + red[3]) * (1.f / 2116.f);
}

// ---------------------------------------------------------------------------
__global__ __launch_bounds__(256) void k_const2(const float* __restrict__ Wproj,
                                                const float* __restrict__ bg,
                                                const float* __restrict__ a2m,
                                                float* __restrict__ c2) {
    int n = blockIdx.x;
    int t = threadIdx.x;
    if (t >= 192) return;
    int gi = t >> 6, o = t & 63;
    int g = (gi == 0) ? 0 : (gi == 1) ? 2 : 3;
    float acc = bg[g * CIN + o];
    const float* wp = Wproj + ((size_t)(g * 4 + 2) * CIN + o) * CIN;
    for (int c = 0; c < CIN; ++c) acc += wp[c] * a2m[n * CIN + c];
    c2[(gi * NB + n) * CIN + o] = acc;
}

// ---------------------------------------------------------------------------
// Gates + LSTM nonlinearity + output 1x1 conv, fused (unchanged).
__global__ __launch_bounds__(256) void k_gates(const float* __restrict__ a0,
                                               const float* __restrict__ c2,
                                               const float* __restrict__ Wproj,
                                               const float* __restrict__ Wout,
                                               const float* __restrict__ bout,
                                               float* __restrict__ out) {
    __shared__ float a0s[64][16];
    __shared__ float wps[3][64][64];
    __shared__ float hs[16][68];
    int n = blockIdx.y;
    int p0 = blockIdx.x * 16;
    int tid = threadIdx.x;

    for (int idx = tid; idx < 1024; idx += 256) {
        int c = idx >> 4, px = idx & 15;
        a0s[c][px] = a0[(size_t)(n * CIN + c) * HW + p0 + px];
    }
    for (int idx = tid; idx < 12288; idx += 256) {
        int o = idx & 63; int rest = idx >> 6; int c = rest & 63; int gi = rest >> 6;
        int g = (gi == 0) ? 0 : (gi == 1) ? 2 : 3;
        wps[gi][c][o] = Wproj[((size_t)(g * 4 + 0) * CIN + o) * CIN + c];
    }
    __syncthreads();

    int o = tid & 63, pg = tid >> 6;
    float pi[4], pgt[4], po[4];
    {
        float ci = c2[(0 * NB + n) * CIN + o];
        float cg = c2[(1 * NB + n) * CIN + o];
        float co = c2[(2 * NB + n) * CIN + o];
        #pragma unroll
        for (int j = 0; j < 4; ++j) { pi[j] = ci; pgt[j] = cg; po[j] = co; }
    }
    const float4* a4 = (const float4*)&a0s[0][0];
    #pragma unroll 4
    for (int c = 0; c < 64; ++c) {
        float4 av = a4[c * 4 + pg];
        float w0 = wps[0][c][o], w1 = wps[1][c][o], w2 = wps[2][c][o];
        pi[0]  += w0 * av.x; pi[1]  += w0 * av.y; pi[2]  += w0 * av.z; pi[3]  += w0 * av.w;
        pgt[0] += w1 * av.x; pgt[1] += w1 * av.y; pgt[2] += w1 * av.z; pgt[3] += w1 * av.w;
        po[0]  += w2 * av.x; po[1]  += w2 * av.y; po[2]  += w2 * av.z; po[3]  += w2 * av.w;
    }
    #pragma unroll
    for (int j = 0; j < 4; ++j) {
        float ii = 1.f / (1.f + __expf(-pi[j]));
        float gg = tanhf(pgt[j]);
        float oo = 1.f / (1.f + __expf(-po[j]));
        float cc = ii * gg;
        hs[pg * 4 + j][o] = oo * tanhf(cc);
    }
    __syncthreads();
    float acc[4];
    float bo = bout[o];
    #pragma unroll
    for (int j = 0; j < 4; ++j) acc[j] = bo;
    const float* wo = Wout + o * CIN;
    #pragma unroll 2
    for (int cg_ = 0; cg_ < 16; ++cg_) {
        float w0 = wo[cg_ * 4 + 0], w1 = wo[cg_ * 4 + 1], w2 = wo[cg_ * 4 + 2], w3 = wo[cg_ * 4 + 3];
        #pragma unroll
        for (int j = 0; j < 4; ++j) {
            const float4 hv = *(const float4*)&hs[pg * 4 + j][cg_ * 4];
            acc[j] += w0 * hv.x + w1 * hv.y + w2 * hv.z + w3 * hv.w;
        }
    }
    #pragma unroll
    for (int j = 0; j < 4; ++j)
        out[(size_t)(n * CIN + o) * HW + p0 + pg * 4 + j] = acc[j];
}

// ---------------------------------------------------------------------------
extern "C" void kernel_launch(void* const* d_in, const int* in_sizes, int n_in,
                              void* d_out, int out_size, void* d_ws, size_t ws_size,
                              hipStream_t stream) {
    const float* x     = (const float*)d_in[0];
    const float* W_in  = (const float*)d_in[1];
    const float* b_in  = (const float*)d_in[2];
    const float* Wq    = (const float*)d_in[3];
    const float* Wk    = (const float*)d_in[4];
    const float* Wv    = (const float*)d_in[5];
    const float* Wproj = (const float*)d_in[6];
    const float* b_g   = (const float*)d_in[7];
    const float* W_out = (const float*)d_in[8];
    const float* b_out = (const float*)d_in[9];
    float* out = (float*)d_out;

    float* q0   = (float*)d_ws;          // 589824
    float* k0   = q0 + 589824;           // 541696
    float* v0   = k0 + 541696;           // 541696
    float* v2   = v0 + 541696;           // 541696
    float* a0   = v2 + 541696;           // 589824
    float* a2m  = a0 + 589824;           // 256
    float* c2   = a2m + 256;             // 768
    float* part = c2 + 768;              // 16*36*2*1280 = 1474560
    unsigned short* Qb = (unsigned short*)(part + 1474560);  // 16*144*512
    unsigned short* Kb = Qb + (size_t)16 * QTL * 512;        // 16*136*512
    unsigned short* Vb = Kb + (size_t)16 * NT * 512;         // 16*136*512
    unsigned short* xb = Vb + (size_t)16 * NT * 512;         // 4*2500*128
    unsigned short* Wb = xb + (size_t)4 * 2500 * 128;        // 16*9*4*512
    // total ~27 MB of workspace

    k_xin   <<<dim3(10, 4, 16), 256, 0, stream>>>(x, W_in, b_in, xb);
    k_wcvt  <<<dim3(144), 256, 0, stream>>>(Wq, Wk, Wv, Wb);
    k_conv  <<<dim3(48, 4, 4), 256, 0, stream>>>(xb, Wb, q0, k0, v0, v2);
    k_cvt   <<<dim3(144, 16), 256, 0, stream>>>(q0, k0, v0, Qb, Kb, Vb);
    k_mattn <<<dim3(72, 16), 256, 0, stream>>>(Qb, Kb, Vb, part);
    k_acomb <<<dim3(36, 16), 256, 0, stream>>>(part, a0);
    k_mean  <<<dim3(256), 256, 0, stream>>>(v2, a2m);
    k_const2<<<dim3(4), 256, 0, stream>>>(Wproj, b_g, a2m, c2);
    k_gates <<<dim3(144, 4), 256, 0, stream>>>(a0, c2, Wproj, W_out, b_out, out);
}

// Round 12
// 205.254 us; speedup vs baseline: 1.3907x; 1.0079x over previous
//
#include <hip/hip_runtime.h>
#include <math.h>

// Problem constants
#define NB   4      // batch
#define CIN  64     // channels everywhere (I=CR=CA=CO=64)
#define HH   48
#define WW   48
#define HW   2304   // 48*48
#define DH   46
#define DW   46
#define DD   2116   // 46*46
#define NHEAD 4
#define HC   16
#define NT   136    // padded d-tiles (2176 = 136*16; 60 zero-pads)
#define QTL  144    // q-tiles (2304 = 144*16)

typedef short  s4 __attribute__((ext_vector_type(4)));
typedef short  s8 __attribute__((ext_vector_type(8)));
typedef float  f4 __attribute__((ext_vector_type(4)));

// ---------------------------------------------------------------------------
// Fused input-projection (bf16x2 conv-ready layout) + weight repack.
// Blocks 0..639: xin 1x1 conv -> xb[n][cell(50x50, 1-px zero border)][128].
// Blocks 640..783: repack conv weights into MFMA A-fragment order (Wb).
__global__ __launch_bounds__(256) void k_xw(const float* __restrict__ x,
                                            const float* __restrict__ Win,
                                            const float* __restrict__ bin,
                                            const float* __restrict__ Wq,
                                            const float* __restrict__ Wk,
                                            const float* __restrict__ Wv,
                                            unsigned short* __restrict__ xb,
                                            unsigned short* __restrict__ Wb) {
    int b = blockIdx.x;
    if (b < 640) {
        int bx = b % 10, n = (b / 10) & 3, ocg = b / 40;
        int cell = bx * 256 + threadIdx.x;
        if (cell >= 2500) return;
        int cy = cell / 50, cx = cell - cy * 50;
        float a[4] = {0.f, 0.f, 0.f, 0.f};
        if (cy >= 1 && cy <= 48 && cx >= 1 && cx <= 48) {
            int px = (cy - 1) * 48 + (cx - 1);
            const float* xp = x + (size_t)(n * CIN) * HW + px;
            #pragma unroll
            for (int j = 0; j < 4; ++j) a[j] = bin[ocg * 4 + j];
            #pragma unroll 8
            for (int ic = 0; ic < CIN; ++ic) {
                float xv = xp[ic * HW];
                a[0] += Win[(ocg * 4 + 0) * CIN + ic] * xv;
                a[1] += Win[(ocg * 4 + 1) * CIN + ic] * xv;
                a[2] += Win[(ocg * 4 + 2) * CIN + ic] * xv;
                a[3] += Win[(ocg * 4 + 3) * CIN + ic] * xv;
            }
        }
        s8 st;
        #pragma unroll
        for (int j = 0; j < 4; ++j) {
            unsigned u = __builtin_bit_cast(unsigned, a[j]);
            st[j] = (short)(u >> 16);
            float lo = a[j] - __builtin_bit_cast(float, u & 0xffff0000u);
            st[4 + j] = (short)(__builtin_bit_cast(unsigned, lo) >> 16);
        }
        *(s8*)(xb + ((size_t)(n * 2500 + cell)) * 128 + ocg * 8) = st;
    } else {
        int bx = b - 640;
        int cq = bx / 9, tap = bx - cq * 9;
        int cv = cq >> 2, ocq = cq & 3;
        const float* src = (cv == 0) ? Wq : (cv == 1) ? Wk : (cv == 2) ? Wv
                                                          : (Wv + 2 * CIN * CIN * 9);
        int t = threadIdx.x;
        int m = t >> 4, kl = t & 15, quad = kl >> 2, j = kl & 3;
        #pragma unroll
        for (int kq = 0; kq < 4; ++kq) {
            float v = src[((size_t)(ocq * 16 + m) * CIN + kq * 16 + kl) * 9 + tap];
            unsigned u = __builtin_bit_cast(unsigned, v);
            float lo = v - __builtin_bit_cast(float, u & 0xffff0000u);
            size_t base = ((size_t)(cq * 9 + tap) * 4 + kq) * 512 + m * 32 + quad * 8 + j;
            Wb[base]     = (unsigned short)(u >> 16);
            Wb[base + 4] = (unsigned short)(__builtin_bit_cast(unsigned, lo) >> 16);
        }
    }
}

// ---------------------------------------------------------------------------
// Implicit-GEMM 3x3 conv on MFMA, fully unrolled two-tap pipeline PINNED by
// sched_group_barrier: [16 VMEM-read] then per tap [16 VMEM][36 MFMA] —
// the scheduler must keep the next tap's loads in flight over the current
// tap's MFMAs (waitcnt pass then emits vmcnt(16), not vmcnt(0)).
// Round-10/11 showed the default scheduler sinks every load to its use
// (VGPR 36, MfmaUtil 12%) regardless of launch_bounds budget.
// grid (48 y, 4 n, 4 cv), block 256 = 4 waves = 4 oc-groups.
__global__ __launch_bounds__(256, 3) void k_conv(const unsigned short* __restrict__ xb,
                                                 const unsigned short* __restrict__ Wb,
                                                 float* __restrict__ q0, float* __restrict__ k0,
                                                 float* __restrict__ v0, float* __restrict__ v2) {
    int y = blockIdx.x, n = blockIdx.y, cv = blockIdx.z;
    float* ob; int outw, pd;
    if (cv == 0)      { ob = q0; outw = 48; pd = 0; }   // SAME
    else if (cv == 1) { ob = k0; outw = 46; pd = 1; }   // VALID
    else if (cv == 2) { ob = v0; outw = 46; pd = 1; }
    else              { ob = v2; outw = 46; pd = 1; }
    if (y >= outw) return;
    int lane = threadIdx.x & 63, wv = threadIdx.x >> 6;
    int m16 = lane & 15, quad = lane >> 4;
    const unsigned short* Wt = Wb + (size_t)(cv * 4 + wv) * 9 * 2048 + m16 * 32 + quad * 8;
    // OOB impossible: worst cell index 48*50+50 = 2450 < 2500.
    const unsigned short* B0 = xb + ((size_t)n * 2500 + (size_t)(y + pd) * 50 + pd + m16) * 128 + quad * 8;

    f4 a0 = {0.f, 0.f, 0.f, 0.f}, a1 = a0, a2 = a0;

    s8 w[4], c0[4], c1[4], c2[4];
    #pragma unroll
    for (int kq = 0; kq < 4; ++kq) {       // tap 0 prefetch
        w[kq]  = *(const s8*)(Wt + kq * 512);
        c0[kq] = *(const s8*)(B0 + kq * 32);
        c1[kq] = *(const s8*)(B0 + 2048 + kq * 32);
        c2[kq] = *(const s8*)(B0 + 4096 + kq * 32);
    }
    __builtin_amdgcn_sched_group_barrier(0x020, 16, 0);   // 16 VMEM reads (tap 0)

    #pragma unroll
    for (int tap = 0; tap < 9; ++tap) {
        s8 wn[4], n0[4], n1[4], n2[4];
        if (tap < 8) {
            int tn = tap + 1;
            int dy = tn / 3, dx = tn - dy * 3;
            const unsigned short* bq = B0 + (size_t)(dy * 50 + dx) * 128;
            const unsigned short* wp = Wt + tn * 2048;
            #pragma unroll
            for (int kq = 0; kq < 4; ++kq) {
                wn[kq] = *(const s8*)(wp + kq * 512);
                n0[kq] = *(const s8*)(bq + kq * 32);
                n1[kq] = *(const s8*)(bq + 2048 + kq * 32);
                n2[kq] = *(const s8*)(bq + 4096 + kq * 32);
            }
        }
        #pragma unroll
        for (int kq = 0; kq < 4; ++kq) {
            s4 ah  = __builtin_shufflevector(w[kq], w[kq], 0, 1, 2, 3);
            s4 al  = __builtin_shufflevector(w[kq], w[kq], 4, 5, 6, 7);
            s4 bh0 = __builtin_shufflevector(c0[kq], c0[kq], 0, 1, 2, 3);
            s4 bl0 = __builtin_shufflevector(c0[kq], c0[kq], 4, 5, 6, 7);
            s4 bh1 = __builtin_shufflevector(c1[kq], c1[kq], 0, 1, 2, 3);
            s4 bl1 = __builtin_shufflevector(c1[kq], c1[kq], 4, 5, 6, 7);
            s4 bh2 = __builtin_shufflevector(c2[kq], c2[kq], 0, 1, 2, 3);
            s4 bl2 = __builtin_shufflevector(c2[kq], c2[kq], 4, 5, 6, 7);
            a0 = __builtin_amdgcn_mfma_f32_16x16x16bf16_1k(ah, bh0, a0, 0, 0, 0);
            a1 = __builtin_amdgcn_mfma_f32_16x16x16bf16_1k(ah, bh1, a1, 0, 0, 0);
            a2 = __builtin_amdgcn_mfma_f32_16x16x16bf16_1k(ah, bh2, a2, 0, 0, 0);
            a0 = __builtin_amdgcn_mfma_f32_16x16x16bf16_1k(al, bh0, a0, 0, 0, 0);
            a1 = __builtin_amdgcn_mfma_f32_16x16x16bf16_1k(al, bh1, a1, 0, 0, 0);
            a2 = __builtin_amdgcn_mfma_f32_16x16x16bf16_1k(al, bh2, a2, 0, 0, 0);
            a0 = __builtin_amdgcn_mfma_f32_16x16x16bf16_1k(ah, bl0, a0, 0, 0, 0);
            a1 = __builtin_amdgcn_mfma_f32_16x16x16bf16_1k(ah, bl1, a1, 0, 0, 0);
            a2 = __builtin_amdgcn_mfma_f32_16x16x16bf16_1k(ah, bl2, a2, 0, 0, 0);
        }
        if (tap < 8) __builtin_amdgcn_sched_group_barrier(0x020, 16, 0); // next tap's loads
        __builtin_amdgcn_sched_group_barrier(0x008, 36, 0);              // this tap's MFMAs
        if (tap < 8) {
            #pragma unroll
            for (int kq = 0; kq < 4; ++kq) {
                w[kq] = wn[kq]; c0[kq] = n0[kq]; c1[kq] = n1[kq]; c2[kq] = n2[kq];
            }
        }
    }

    size_t outsz = (size_t)outw * outw;
    float* opb = ob + (size_t)(n * CIN + wv * 16 + quad * 4) * outsz + (size_t)y * outw;
    {   // tiles 0,1 always in-bounds
        float* op = opb + m16;
        op[0] = a0.x; op[outsz] = a0.y; op[2 * outsz] = a0.z; op[3 * outsz] = a0.w;
        op = opb + 16 + m16;
        op[0] = a1.x; op[outsz] = a1.y; op[2 * outsz] = a1.z; op[3 * outsz] = a1.w;
    }
    if (32 + m16 < outw) {
        float* op = opb + 32 + m16;
        op[0] = a2.x; op[outsz] = a2.y; op[2 * outsz] = a2.z; op[3 * outsz] = a2.w;
    }
}

// ---------------------------------------------------------------------------
// Convert q0/k0/v0 fp32 -> MFMA-tiled bf16x2 (hi/lo planes, truncation split).
// grid (144, 16 nh), block 256.
__global__ __launch_bounds__(256) void k_cvt(const float* __restrict__ q0,
                                             const float* __restrict__ k0,
                                             const float* __restrict__ v0,
                                             unsigned short* __restrict__ Qb,
                                             unsigned short* __restrict__ Kb,
                                             unsigned short* __restrict__ Vb) {
    __shared__ float sm[272];            // 16x16 transpose pad 17
    int bx = blockIdx.x, nh = blockIdx.y;
    int n = nh >> 2, h = nh & 3;
    int t = threadIdx.x;
    {
        int c = t >> 4, q = t & 15;
        float val = q0[(size_t)(n * CIN + h * HC + c) * HW + bx * 16 + q];
        sm[c * 17 + q] = val;
        __syncthreads();
        int q2 = t >> 4, c2 = t & 15;
        float v = sm[c2 * 17 + q2];
        unsigned u = __builtin_bit_cast(unsigned, v);
        unsigned short* dst = Qb + (size_t)(nh * QTL + bx) * 512;
        dst[t] = (unsigned short)(u >> 16);
        float lo = v - __builtin_bit_cast(float, u & 0xffff0000u);
        dst[256 + t] = (unsigned short)(__builtin_bit_cast(unsigned, lo) >> 16);
    }
    if (bx < NT) {
        __syncthreads();
        int c = t >> 4, d = t & 15;
        int dgl = bx * 16 + d;
        float kv = (dgl < DD) ? k0[(size_t)(n * CIN + h * HC + c) * DD + dgl] : 0.f;
        sm[c * 17 + d] = kv;
        __syncthreads();
        {
            int d2 = t >> 4, c2 = t & 15;
            float v = sm[c2 * 17 + d2];
            unsigned u = __builtin_bit_cast(unsigned, v);
            unsigned short* dst = Kb + (size_t)(nh * NT + bx) * 512;
            dst[t] = (unsigned short)(u >> 16);
            float lo = v - __builtin_bit_cast(float, u & 0xffff0000u);
            dst[256 + t] = (unsigned short)(__builtin_bit_cast(unsigned, lo) >> 16);
        }
        {
            float vv = (dgl < DD) ? v0[(size_t)(n * CIN + h * HC + c) * DD + dgl] : 0.f;
            unsigned u = __builtin_bit_cast(unsigned, vv);
            unsigned short* dst = Vb + (size_t)(nh * NT + bx) * 512;
            dst[t] = (unsigned short)(u >> 16);
            float lo = vv - __builtin_bit_cast(float, u & 0xffff0000u);
            dst[256 + t] = (unsigned short)(__builtin_bit_cast(unsigned, lo) >> 16);
        }
    }
}

// ---------------------------------------------------------------------------
// MFMA attention (validated round 5). grid (72, 16 nh), block 256.
__global__ __launch_bounds__(256) void k_mattn(const unsigned short* __restrict__ Qb,
                                               const unsigned short* __restrict__ Kb,
                                               const unsigned short* __restrict__ Vb,
                                               float* __restrict__ part) {
    __shared__ float sO[4][4][256];
    __shared__ float sl[4][4][64];
    int strip = blockIdx.x >> 1, hb = blockIdx.x & 1, nh = blockIdx.y;
    int lane = threadIdx.x & 63, wv = threadIdx.x >> 6;
    int ds = hb * 4 + wv;
    int q16 = lane & 15, quad = lane >> 4;
    int foff = q16 * 16 + quad * 4;

    s4 qh[4], ql[4];
    #pragma unroll
    for (int j = 0; j < 4; ++j) {
        const unsigned short* Qp = Qb + (size_t)(nh * QTL + strip * 4 + j) * 512 + foff;
        qh[j] = *(const s4*)(Qp);
        ql[j] = *(const s4*)(Qp + 256);
    }
    f4 O[4];
    float l[4];
    #pragma unroll
    for (int j = 0; j < 4; ++j) { O[j] = (f4){0.f, 0.f, 0.f, 0.f}; l[j] = 0.f; }

    const unsigned short* Kp = Kb + (size_t)(nh * NT + ds * 17) * 512 + foff;
    const unsigned short* Vp = Vb + (size_t)(nh * NT + ds * 17) * 512 + foff;
    s4 khi = *(const s4*)(Kp);
    s4 klo = *(const s4*)(Kp + 256);
    s4 vhi = *(const s4*)(Vp);
    s4 vlo = *(const s4*)(Vp + 256);

    for (int it = 0; it < 17; ++it) {
        int nxt = (it < 16) ? (it + 1) * 512 : 0;
        s4 nkhi = *(const s4*)(Kp + nxt);
        s4 nklo = *(const s4*)(Kp + nxt + 256);
        s4 nvhi = *(const s4*)(Vp + nxt);
        s4 nvlo = *(const s4*)(Vp + nxt + 256);

        #pragma unroll
        for (int j = 0; j < 4; ++j) {
            f4 c1 = (f4){0.f, 0.f, 0.f, 0.f};
            c1 = __builtin_amdgcn_mfma_f32_16x16x16bf16_1k(khi, qh[j], c1, 0, 0, 0);
            c1 = __builtin_amdgcn_mfma_f32_16x16x16bf16_1k(klo, qh[j], c1, 0, 0, 0);
            c1 = __builtin_amdgcn_mfma_f32_16x16x16bf16_1k(khi, ql[j], c1, 0, 0, 0);
            float p0 = __expf(c1.x), p1 = __expf(c1.y);
            float p2 = __expf(c1.z), p3 = __expf(c1.w);
            l[j] += (p0 + p1) + (p2 + p3);
            unsigned u0 = __builtin_bit_cast(unsigned, p0);
            unsigned u1 = __builtin_bit_cast(unsigned, p1);
            unsigned u2 = __builtin_bit_cast(unsigned, p2);
            unsigned u3 = __builtin_bit_cast(unsigned, p3);
            s4 ph;
            ph.x = (short)(u0 >> 16); ph.y = (short)(u1 >> 16);
            ph.z = (short)(u2 >> 16); ph.w = (short)(u3 >> 16);
            float r0 = p0 - __builtin_bit_cast(float, u0 & 0xffff0000u);
            float r1 = p1 - __builtin_bit_cast(float, u1 & 0xffff0000u);
            float r2 = p2 - __builtin_bit_cast(float, u2 & 0xffff0000u);
            float r3 = p3 - __builtin_bit_cast(float, u3 & 0xffff0000u);
            s4 pl;
            pl.x = (short)(__builtin_bit_cast(unsigned, r0) >> 16);
            pl.y = (short)(__builtin_bit_cast(unsigned, r1) >> 16);
            pl.z = (short)(__builtin_bit_cast(unsigned, r2) >> 16);
            pl.w = (short)(__builtin_bit_cast(unsigned, r3) >> 16);
            O[j] = __builtin_amdgcn_mfma_f32_16x16x16bf16_1k(vhi, ph, O[j], 0, 0, 0);
            O[j] = __builtin_amdgcn_mfma_f32_16x16x16bf16_1k(vlo, ph, O[j], 0, 0, 0);
            O[j] = __builtin_amdgcn_mfma_f32_16x16x16bf16_1k(vhi, pl, O[j], 0, 0, 0);
        }
        khi = nkhi; klo = nklo; vhi = nvhi; vlo = nvlo;
    }

    #pragma unroll
    for (int j = 0; j < 4; ++j) {
        sO[wv][j][(quad * 4 + 0) * 16 + q16] = O[j].x;
        sO[wv][j][(quad * 4 + 1) * 16 + q16] = O[j].y;
        sO[wv][j][(quad * 4 + 2) * 16 + q16] = O[j].z;
        sO[wv][j][(quad * 4 + 3) * 16 + q16] = O[j].w;
        sl[wv][j][quad * 16 + q16] = l[j];
    }
    __syncthreads();
    int t = threadIdx.x;
    float* pb = part + (size_t)((nh * 36 + strip) * 2 + hb) * 1280;
    #pragma unroll
    for (int j = 0; j < 4; ++j)
        pb[j * 256 + t] = (sO[0][j][t] + sO[1][j][t]) + (sO[2][j][t] + sO[3][j][t]);
    {
        int j2 = t >> 6, i2 = t & 63;
        pb[1024 + t] = (sl[0][j2][i2] + sl[1][j2][i2]) + (sl[2][j2][i2] + sl[3][j2][i2]);
    }
}

// ---------------------------------------------------------------------------
// A2mean[n,c] = mean over 2116 positions of v2[n,c,:]
__global__ __launch_bounds__(256) void k_mean(const float* __restrict__ v2,
                                              float* __restrict__ a2m) {
    int n = blockIdx.x >> 6, c = blockIdx.x & 63;
    const float* p = v2 + (size_t)(n * CIN + c) * DD;
    float s = 0.f;
    for (int d = threadIdx.x; d < DD; d += 256) s += p[d];
    #pragma unroll
    for (int off = 32; off > 0; off >>= 1) s += __shfl_down(s, off);
    __shared__ float red[4];
    int lane = threadIdx.x & 63, wv = threadIdx.x >> 6;
    if (lane == 0) red[wv] = s;
    __syncthreads();
    if (threadIdx.x == 0)
        a2m[blockIdx.x] = (red[0] + red[1] + red[2] + red[3]) * (1.f / 2116.f);
}

// ---------------------------------------------------------------------------
// Gates + LSTM nonlinearity + output 1x1 conv, now fused with the attention
// combine (ex-k_acomb) and constant-gate projection (ex-k_const2).
// Block (pt 0..143, n): strip = pt>>2, jq = pt&3 are block-constant, so the
// block's 16 px live in one (strip, q-group) of part.
__global__ __launch_bounds__(256) void k_gates(const float* __restrict__ part,
                                               const float* __restrict__ a2m,
                                               const float* __restrict__ Wproj,
                                               const float* __restrict__ bg,
                                               const float* __restrict__ Wout,
                                               const float* __restrict__ bout,
                                               float* __restrict__ out) {
    __shared__ float a0s[64][16];
    __shared__ float wps[3][64][64];   // [gi][c][o]
    __shared__ float hs[16][68];
    __shared__ float invs[4][16];      // [h][px] softmax denominators
    __shared__ float c2s[3][64];       // constant gate pre-activations
    int n = blockIdx.y;
    int pt = blockIdx.x;
    int strip = pt >> 2, jq = pt & 3;
    int p0 = pt * 16;
    int tid = threadIdx.x;

    if (tid < 64) {                    // denominators (ex-k_acomb l-sum)
        int h = tid >> 4, q = tid & 15;
        const float* b0 = part + (size_t)(((n * 4 + h) * 36 + strip) * 2) * 1280;
        const float* b1 = b0 + 1280;
        float s = 0.f;
        #pragma unroll
        for (int quad = 0; quad < 4; ++quad)
            s += b0[1024 + jq * 64 + quad * 16 + q] + b1[1024 + jq * 64 + quad * 16 + q];
        invs[h][q] = 1.f / (s - 60.f);
    } else {                           // constant gates (ex-k_const2)
        int gi = (tid - 64) >> 6, o = tid & 63;
        int g = (gi == 0) ? 0 : (gi == 1) ? 2 : 3;
        float acc = bg[g * CIN + o];
        const float* wp = Wproj + ((size_t)(g * 4 + 2) * CIN + o) * CIN;
        const float* am = a2m + n * CIN;
        #pragma unroll 8
        for (int c = 0; c < CIN; ++c) acc += wp[c] * am[c];
        c2s[gi][o] = acc;
    }
    __syncthreads();

    for (int idx = tid; idx < 1024; idx += 256) {   // a0 tile via part (ex-k_acomb O)
        int c = idx >> 4, px = idx & 15;
        int h = c >> 4, c16 = c & 15;
        const float* b0 = part + (size_t)(((n * 4 + h) * 36 + strip) * 2) * 1280;
        const float* b1 = b0 + 1280;
        int off = jq * 256 + c16 * 16 + px;
        a0s[c][px] = (b0[off] + b1[off]) * invs[h][px];
    }
    for (int idx = tid; idx < 12288; idx += 256) {
        int o = idx & 63; int rest = idx >> 6; int c = rest & 63; int gi = rest >> 6;
        int g = (gi == 0) ? 0 : (gi == 1) ? 2 : 3;
        wps[gi][c][o] = Wproj[((size_t)(g * 4 + 0) * CIN + o) * CIN + c];
    }
    __syncthreads();

    int o = tid & 63, pg = tid >> 6;
    float pi[4], pgt[4], po[4];
    {
        float ci = c2s[0][o], cg = c2s[1][o], co = c2s[2][o];
        #pragma unroll
        for (int j = 0; j < 4; ++j) { pi[j] = ci; pgt[j] = cg; po[j] = co; }
    }
    const float4* a4 = (const float4*)&a0s[0][0];
    #pragma unroll 4
    for (int c = 0; c < 64; ++c) {
        float4 av = a4[c * 4 + pg];
        float w0 = wps[0][c][o], w1 = wps[1][c][o], w2 = wps[2][c][o];
        pi[0]  += w0 * av.x; pi[1]  += w0 * av.y; pi[2]  += w0 * av.z; pi[3]  += w0 * av.w;
        pgt[0] += w1 * av.x; pgt[1] += w1 * av.y; pgt[2] += w1 * av.z; pgt[3] += w1 * av.w;
        po[0]  += w2 * av.x; po[1]  += w2 * av.y; po[2]  += w2 * av.z; po[3]  += w2 * av.w;
    }
    #pragma unroll
    for (int j = 0; j < 4; ++j) {
        float ii = 1.f / (1.f + __expf(-pi[j]));
        float gg = tanhf(pgt[j]);
        float oo = 1.f / (1.f + __expf(-po[j]));
        float cc = ii * gg;
        hs[pg * 4 + j][o] = oo * tanhf(cc);
    }
    __syncthreads();
    float acc[4];
    float bo = bout[o];
    #pragma unroll
    for (int j = 0; j < 4; ++j) acc[j] = bo;
    const float* wo = Wout + o * CIN;
    #pragma unroll 2
    for (int cg_ = 0; cg_ < 16; ++cg_) {
        float w0 = wo[cg_ * 4 + 0], w1 = wo[cg_ * 4 + 1], w2 = wo[cg_ * 4 + 2], w3 = wo[cg_ * 4 + 3];
        #pragma unroll
        for (int j = 0; j < 4; ++j) {
            const float4 hv = *(const float4*)&hs[pg * 4 + j][cg_ * 4];
            acc[j] += w0 * hv.x + w1 * hv.y + w2 * hv.z + w3 * hv.w;
        }
    }
    #pragma unroll
    for (int j = 0; j < 4; ++j)
        out[(size_t)(n * CIN + o) * HW + p0 + pg * 4 + j] = acc[j];
}

// ---------------------------------------------------------------------------
extern "C" void kernel_launch(void* const* d_in, const int* in_sizes, int n_in,
                              void* d_out, int out_size, void* d_ws, size_t ws_size,
                              hipStream_t stream) {
    const float* x     = (const float*)d_in[0];
    const float* W_in  = (const float*)d_in[1];
    const float* b_in  = (const float*)d_in[2];
    const float* Wq    = (const float*)d_in[3];
    const float* Wk    = (const float*)d_in[4];
    const float* Wv    = (const float*)d_in[5];
    const float* Wproj = (const float*)d_in[6];
    const float* b_g   = (const float*)d_in[7];
    const float* W_out = (const float*)d_in[8];
    const float* b_out = (const float*)d_in[9];
    float* out = (float*)d_out;

    float* q0   = (float*)d_ws;          // 589824
    float* k0   = q0 + 589824;           // 541696
    float* v0   = k0 + 541696;           // 541696
    float* v2   = v0 + 541696;           // 541696
    float* a2m  = v2 + 541696;           // 256
    float* part = a2m + 256;             // 16*36*2*1280 = 1474560
    unsigned short* Qb = (unsigned short*)(part + 1474560);  // 16*144*512
    unsigned short* Kb = Qb + (size_t)16 * QTL * 512;        // 16*136*512
    unsigned short* Vb = Kb + (size_t)16 * NT * 512;         // 16*136*512
    unsigned short* xb = Vb + (size_t)16 * NT * 512;         // 4*2500*128
    unsigned short* Wb = xb + (size_t)4 * 2500 * 128;        // 16*9*4*512
    // total ~25 MB of workspace

    k_xw    <<<dim3(784), 256, 0, stream>>>(x, W_in, b_in, Wq, Wk, Wv, xb, Wb);
    k_conv  <<<dim3(48, 4, 4), 256, 0, stream>>>(xb, Wb, q0, k0, v0, v2);
    k_cvt   <<<dim3(144, 16), 256, 0, stream>>>(q0, k0, v0, Qb, Kb, Vb);
    k_mattn <<<dim3(72, 16), 256, 0, stream>>>(Qb, Kb, Vb, part);
    k_mean  <<<dim3(256), 256, 0, stream>>>(v2, a2m);
    k_gates <<<dim3(144, 4), 256, 0, stream>>>(part, a2m, Wproj, b_g, W_out, b_out, out);
}

// Round 13
// 179.085 us; speedup vs baseline: 1.5939x; 1.1461x over previous
//
#include <hip/hip_runtime.h>
#include <math.h>

// Problem constants
#define NB   4      // batch
#define CIN  64     // channels everywhere (I=CR=CA=CO=64)
#define HH   48
#define WW   48
#define HW   2304   // 48*48
#define DH   46
#define DW   46
#define DD   2116   // 46*46
#define NHEAD 4
#define HC   16
#define NT   136    // padded d-tiles (2176 = 136*16; 60 zero-pads)
#define QTL  144    // q-tiles (2304 = 144*16)
#define GS   20000  // xb group stride in shorts (2500 cells * 8)

typedef short  s4 __attribute__((ext_vector_type(4)));
typedef short  s8 __attribute__((ext_vector_type(8)));
typedef float  f4 __attribute__((ext_vector_type(4)));

// ---------------------------------------------------------------------------
// Fused input-projection (bf16x2 conv-ready layout) + weight repack.
// Blocks 0..639: xin 1x1 conv -> xb[n][g][cell][8] (GROUP-MAJOR: g=kq*4+quad,
// covering channels 4g..4g+3 as {hi[4],lo[4]}; cell on 50x50 1-px zero
// border grid). Group-major makes the conv's B-fragment loads coalesced:
// lane m16 stride = 16 B (was 256 B cell-major -> 64 lines/load, the
// round-12 L1 bottleneck). Blocks 640..783: weight repack (unchanged).
__global__ __launch_bounds__(256) void k_xw(const float* __restrict__ x,
                                            const float* __restrict__ Win,
                                            const float* __restrict__ bin,
                                            const float* __restrict__ Wq,
                                            const float* __restrict__ Wk,
                                            const float* __restrict__ Wv,
                                            unsigned short* __restrict__ xb,
                                            unsigned short* __restrict__ Wb) {
    int b = blockIdx.x;
    if (b < 640) {
        int bx = b % 10, n = (b / 10) & 3, ocg = b / 40;
        int cell = bx * 256 + threadIdx.x;
        if (cell >= 2500) return;
        int cy = cell / 50, cx = cell - cy * 50;
        float a[4] = {0.f, 0.f, 0.f, 0.f};
        if (cy >= 1 && cy <= 48 && cx >= 1 && cx <= 48) {
            int px = (cy - 1) * 48 + (cx - 1);
            const float* xp = x + (size_t)(n * CIN) * HW + px;
            #pragma unroll
            for (int j = 0; j < 4; ++j) a[j] = bin[ocg * 4 + j];
            #pragma unroll 8
            for (int ic = 0; ic < CIN; ++ic) {
                float xv = xp[ic * HW];
                a[0] += Win[(ocg * 4 + 0) * CIN + ic] * xv;
                a[1] += Win[(ocg * 4 + 1) * CIN + ic] * xv;
                a[2] += Win[(ocg * 4 + 2) * CIN + ic] * xv;
                a[3] += Win[(ocg * 4 + 3) * CIN + ic] * xv;
            }
        }
        s8 st;
        #pragma unroll
        for (int j = 0; j < 4; ++j) {
            unsigned u = __builtin_bit_cast(unsigned, a[j]);
            st[j] = (short)(u >> 16);
            float lo = a[j] - __builtin_bit_cast(float, u & 0xffff0000u);
            st[4 + j] = (short)(__builtin_bit_cast(unsigned, lo) >> 16);
        }
        *(s8*)(xb + ((size_t)(n * 16 + ocg) * 2500 + cell) * 8) = st;
    } else {
        int bx = b - 640;
        int cq = bx / 9, tap = bx - cq * 9;
        int cv = cq >> 2, ocq = cq & 3;
        const float* src = (cv == 0) ? Wq : (cv == 1) ? Wk : (cv == 2) ? Wv
                                                          : (Wv + 2 * CIN * CIN * 9);
        int t = threadIdx.x;
        int m = t >> 4, kl = t & 15, quad = kl >> 2, j = kl & 3;
        #pragma unroll
        for (int kq = 0; kq < 4; ++kq) {
            float v = src[((size_t)(ocq * 16 + m) * CIN + kq * 16 + kl) * 9 + tap];
            unsigned u = __builtin_bit_cast(unsigned, v);
            float lo = v - __builtin_bit_cast(float, u & 0xffff0000u);
            size_t base = ((size_t)(cq * 9 + tap) * 4 + kq) * 512 + m * 32 + quad * 8 + j;
            Wb[base]     = (unsigned short)(u >> 16);
            Wb[base + 4] = (unsigned short)(__builtin_bit_cast(unsigned, lo) >> 16);
        }
    }
}

// ---------------------------------------------------------------------------
// Implicit-GEMM 3x3 conv on MFMA, fully unrolled two-tap pipeline pinned by
// sched_group_barrier, B-loads COALESCED via the group-major xb layout:
// lane addr = quad*40000B + m16*16B -> 4 contiguous 256B runs = 16 lines/load
// (was 64 lines/load, the measured L1 bottleneck: 83k lines/CU ~ 35us).
// grid (48 y, 4 n, 4 cv), block 256 = 4 waves = 4 oc-groups.
__global__ __launch_bounds__(256, 3) void k_conv(const unsigned short* __restrict__ xb,
                                                 const unsigned short* __restrict__ Wb,
                                                 float* __restrict__ q0, float* __restrict__ k0,
                                                 float* __restrict__ v0, float* __restrict__ v2) {
    int y = blockIdx.x, n = blockIdx.y, cv = blockIdx.z;
    float* ob; int outw, pd;
    if (cv == 0)      { ob = q0; outw = 48; pd = 0; }   // SAME
    else if (cv == 1) { ob = k0; outw = 46; pd = 1; }   // VALID
    else if (cv == 2) { ob = v0; outw = 46; pd = 1; }
    else              { ob = v2; outw = 46; pd = 1; }
    if (y >= outw) return;
    int lane = threadIdx.x & 63, wv = threadIdx.x >> 6;
    int m16 = lane & 15, quad = lane >> 4;
    const unsigned short* Wt = Wb + (size_t)(cv * 4 + wv) * 9 * 2048 + m16 * 32 + quad * 8;
    // per-lane base (tile 0, tap 0): group = quad (kq adds 4*GS), cell =
    // (y+pd)*50 + pd + m16; tap adds (dy*50+dx)*8 shorts; tiles add 128/256.
    // OOB impossible: worst cell 48*50+50 = 2450 < 2500.
    const unsigned short* B0 = xb + (size_t)(n * 16 + quad) * GS
                                  + ((size_t)(y + pd) * 50 + pd + m16) * 8;

    f4 a0 = {0.f, 0.f, 0.f, 0.f}, a1 = a0, a2 = a0;

    s8 w[4], c0[4], c1[4], c2[4];
    #pragma unroll
    for (int kq = 0; kq < 4; ++kq) {       // tap 0 prefetch
        w[kq]  = *(const s8*)(Wt + kq * 512);
        c0[kq] = *(const s8*)(B0 + (size_t)kq * 4 * GS);
        c1[kq] = *(const s8*)(B0 + (size_t)kq * 4 * GS + 128);
        c2[kq] = *(const s8*)(B0 + (size_t)kq * 4 * GS + 256);
    }
    __builtin_amdgcn_sched_group_barrier(0x020, 16, 0);   // 16 VMEM reads (tap 0)

    #pragma unroll
    for (int tap = 0; tap < 9; ++tap) {
        s8 wn[4], n0[4], n1[4], n2[4];
        if (tap < 8) {
            int tn = tap + 1;
            int dy = tn / 3, dx = tn - dy * 3;
            const unsigned short* bq = B0 + (size_t)(dy * 50 + dx) * 8;
            const unsigned short* wp = Wt + tn * 2048;
            #pragma unroll
            for (int kq = 0; kq < 4; ++kq) {
                wn[kq] = *(const s8*)(wp + kq * 512);
                n0[kq] = *(const s8*)(bq + (size_t)kq * 4 * GS);
                n1[kq] = *(const s8*)(bq + (size_t)kq * 4 * GS + 128);
                n2[kq] = *(const s8*)(bq + (size_t)kq * 4 * GS + 256);
            }
        }
        #pragma unroll
        for (int kq = 0; kq < 4; ++kq) {
            s4 ah  = __builtin_shufflevector(w[kq], w[kq], 0, 1, 2, 3);
            s4 al  = __builtin_shufflevector(w[kq], w[kq], 4, 5, 6, 7);
            s4 bh0 = __builtin_shufflevector(c0[kq], c0[kq], 0, 1, 2, 3);
            s4 bl0 = __builtin_shufflevector(c0[kq], c0[kq], 4, 5, 6, 7);
            s4 bh1 = __builtin_shufflevector(c1[kq], c1[kq], 0, 1, 2, 3);
            s4 bl1 = __builtin_shufflevector(c1[kq], c1[kq], 4, 5, 6, 7);
            s4 bh2 = __builtin_shufflevector(c2[kq], c2[kq], 0, 1, 2, 3);
            s4 bl2 = __builtin_shufflevector(c2[kq], c2[kq], 4, 5, 6, 7);
            a0 = __builtin_amdgcn_mfma_f32_16x16x16bf16_1k(ah, bh0, a0, 0, 0, 0);
            a1 = __builtin_amdgcn_mfma_f32_16x16x16bf16_1k(ah, bh1, a1, 0, 0, 0);
            a2 = __builtin_amdgcn_mfma_f32_16x16x16bf16_1k(ah, bh2, a2, 0, 0, 0);
            a0 = __builtin_amdgcn_mfma_f32_16x16x16bf16_1k(al, bh0, a0, 0, 0, 0);
            a1 = __builtin_amdgcn_mfma_f32_16x16x16bf16_1k(al, bh1, a1, 0, 0, 0);
            a2 = __builtin_amdgcn_mfma_f32_16x16x16bf16_1k(al, bh2, a2, 0, 0, 0);
            a0 = __builtin_amdgcn_mfma_f32_16x16x16bf16_1k(ah, bl0, a0, 0, 0, 0);
            a1 = __builtin_amdgcn_mfma_f32_16x16x16bf16_1k(ah, bl1, a1, 0, 0, 0);
            a2 = __builtin_amdgcn_mfma_f32_16x16x16bf16_1k(ah, bl2, a2, 0, 0, 0);
        }
        if (tap < 8) __builtin_amdgcn_sched_group_barrier(0x020, 16, 0); // next tap's loads
        __builtin_amdgcn_sched_group_barrier(0x008, 36, 0);              // this tap's MFMAs
        if (tap < 8) {
            #pragma unroll
            for (int kq = 0; kq < 4; ++kq) {
                w[kq] = wn[kq]; c0[kq] = n0[kq]; c1[kq] = n1[kq]; c2[kq] = n2[kq];
            }
        }
    }

    size_t outsz = (size_t)outw * outw;
    float* opb = ob + (size_t)(n * CIN + wv * 16 + quad * 4) * outsz + (size_t)y * outw;
    {   // tiles 0,1 always in-bounds
        float* op = opb + m16;
        op[0] = a0.x; op[outsz] = a0.y; op[2 * outsz] = a0.z; op[3 * outsz] = a0.w;
        op = opb + 16 + m16;
        op[0] = a1.x; op[outsz] = a1.y; op[2 * outsz] = a1.z; op[3 * outsz] = a1.w;
    }
    if (32 + m16 < outw) {
        float* op = opb + 32 + m16;
        op[0] = a2.x; op[outsz] = a2.y; op[2 * outsz] = a2.z; op[3 * outsz] = a2.w;
    }
}

// ---------------------------------------------------------------------------
// Convert q0/k0/v0 fp32 -> MFMA-tiled bf16x2 (hi/lo planes, truncation split).
// grid (144, 16 nh), block 256.
__global__ __launch_bounds__(256) void k_cvt(const float* __restrict__ q0,
                                             const float* __restrict__ k0,
                                             const float* __restrict__ v0,
                                             unsigned short* __restrict__ Qb,
                                             unsigned short* __restrict__ Kb,
                                             unsigned short* __restrict__ Vb) {
    __shared__ float sm[272];            // 16x16 transpose pad 17
    int bx = blockIdx.x, nh = blockIdx.y;
    int n = nh >> 2, h = nh & 3;
    int t = threadIdx.x;
    {
        int c = t >> 4, q = t & 15;
        float val = q0[(size_t)(n * CIN + h * HC + c) * HW + bx * 16 + q];
        sm[c * 17 + q] = val;
        __syncthreads();
        int q2 = t >> 4, c2 = t & 15;
        float v = sm[c2 * 17 + q2];
        unsigned u = __builtin_bit_cast(unsigned, v);
        unsigned short* dst = Qb + (size_t)(nh * QTL + bx) * 512;
        dst[t] = (unsigned short)(u >> 16);
        float lo = v - __builtin_bit_cast(float, u & 0xffff0000u);
        dst[256 + t] = (unsigned short)(__builtin_bit_cast(unsigned, lo) >> 16);
    }
    if (bx < NT) {
        __syncthreads();
        int c = t >> 4, d = t & 15;
        int dgl = bx * 16 + d;
        float kv = (dgl < DD) ? k0[(size_t)(n * CIN + h * HC + c) * DD + dgl] : 0.f;
        sm[c * 17 + d] = kv;
        __syncthreads();
        {
            int d2 = t >> 4, c2 = t & 15;
            float v = sm[c2 * 17 + d2];
            unsigned u = __builtin_bit_cast(unsigned, v);
            unsigned short* dst = Kb + (size_t)(nh * NT + bx) * 512;
            dst[t] = (unsigned short)(u >> 16);
            float lo = v - __builtin_bit_cast(float, u & 0xffff0000u);
            dst[256 + t] = (unsigned short)(__builtin_bit_cast(unsigned, lo) >> 16);
        }
        {
            float vv = (dgl < DD) ? v0[(size_t)(n * CIN + h * HC + c) * DD + dgl] : 0.f;
            unsigned u = __builtin_bit_cast(unsigned, vv);
            unsigned short* dst = Vb + (size_t)(nh * NT + bx) * 512;
            dst[t] = (unsigned short)(u >> 16);
            float lo = vv - __builtin_bit_cast(float, u & 0xffff0000u);
            dst[256 + t] = (unsigned short)(__builtin_bit_cast(unsigned, lo) >> 16);
        }
    }
}

// ---------------------------------------------------------------------------
// MFMA attention (validated round 5). grid (72, 16 nh), block 256.
__global__ __launch_bounds__(256) void k_mattn(const unsigned short* __restrict__ Qb,
                                               const unsigned short* __restrict__ Kb,
                                               const unsigned short* __restrict__ Vb,
                                               float* __restrict__ part) {
    __shared__ float sO[4][4][256];
    __shared__ float sl[4][4][64];
    int strip = blockIdx.x >> 1, hb = blockIdx.x & 1, nh = blockIdx.y;
    int lane = threadIdx.x & 63, wv = threadIdx.x >> 6;
    int ds = hb * 4 + wv;
    int q16 = lane & 15, quad = lane >> 4;
    int foff = q16 * 16 + quad * 4;

    s4 qh[4], ql[4];
    #pragma unroll
    for (int j = 0; j < 4; ++j) {
        const unsigned short* Qp = Qb + (size_t)(nh * QTL + strip * 4 + j) * 512 + foff;
        qh[j] = *(const s4*)(Qp);
        ql[j] = *(const s4*)(Qp + 256);
    }
    f4 O[4];
    float l[4];
    #pragma unroll
    for (int j = 0; j < 4; ++j) { O[j] = (f4){0.f, 0.f, 0.f, 0.f}; l[j] = 0.f; }

    const unsigned short* Kp = Kb + (size_t)(nh * NT + ds * 17) * 512 + foff;
    const unsigned short* Vp = Vb + (size_t)(nh * NT + ds * 17) * 512 + foff;
    s4 khi = *(const s4*)(Kp);
    s4 klo = *(const s4*)(Kp + 256);
    s4 vhi = *(const s4*)(Vp);
    s4 vlo = *(const s4*)(Vp + 256);

    for (int it = 0; it < 17; ++it) {
        int nxt = (it < 16) ? (it + 1) * 512 : 0;
        s4 nkhi = *(const s4*)(Kp + nxt);
        s4 nklo = *(const s4*)(Kp + nxt + 256);
        s4 nvhi = *(const s4*)(Vp + nxt);
        s4 nvlo = *(const s4*)(Vp + nxt + 256);

        #pragma unroll
        for (int j = 0; j < 4; ++j) {
            f4 c1 = (f4){0.f, 0.f, 0.f, 0.f};
            c1 = __builtin_amdgcn_mfma_f32_16x16x16bf16_1k(khi, qh[j], c1, 0, 0, 0);
            c1 = __builtin_amdgcn_mfma_f32_16x16x16bf16_1k(klo, qh[j], c1, 0, 0, 0);
            c1 = __builtin_amdgcn_mfma_f32_16x16x16bf16_1k(khi, ql[j], c1, 0, 0, 0);
            float p0 = __expf(c1.x), p1 = __expf(c1.y);
            float p2 = __expf(c1.z), p3 = __expf(c1.w);
            l[j] += (p0 + p1) + (p2 + p3);
            unsigned u0 = __builtin_bit_cast(unsigned, p0);
            unsigned u1 = __builtin_bit_cast(unsigned, p1);
            unsigned u2 = __builtin_bit_cast(unsigned, p2);
            unsigned u3 = __builtin_bit_cast(unsigned, p3);
            s4 ph;
            ph.x = (short)(u0 >> 16); ph.y = (short)(u1 >> 16);
            ph.z = (short)(u2 >> 16); ph.w = (short)(u3 >> 16);
            float r0 = p0 - __builtin_bit_cast(float, u0 & 0xffff0000u);
            float r1 = p1 - __builtin_bit_cast(float, u1 & 0xffff0000u);
            float r2 = p2 - __builtin_bit_cast(float, u2 & 0xffff0000u);
            float r3 = p3 - __builtin_bit_cast(float, u3 & 0xffff0000u);
            s4 pl;
            pl.x = (short)(__builtin_bit_cast(unsigned, r0) >> 16);
            pl.y = (short)(__builtin_bit_cast(unsigned, r1) >> 16);
            pl.z = (short)(__builtin_bit_cast(unsigned, r2) >> 16);
            pl.w = (short)(__builtin_bit_cast(unsigned, r3) >> 16);
            O[j] = __builtin_amdgcn_mfma_f32_16x16x16bf16_1k(vhi, ph, O[j], 0, 0, 0);
            O[j] = __builtin_amdgcn_mfma_f32_16x16x16bf16_1k(vlo, ph, O[j], 0, 0, 0);
            O[j] = __builtin_amdgcn_mfma_f32_16x16x16bf16_1k(vhi, pl, O[j], 0, 0, 0);
        }
        khi = nkhi; klo = nklo; vhi = nvhi; vlo = nvlo;
    }

    #pragma unroll
    for (int j = 0; j < 4; ++j) {
        sO[wv][j][(quad * 4 + 0) * 16 + q16] = O[j].x;
        sO[wv][j][(quad * 4 + 1) * 16 + q16] = O[j].y;
        sO[wv][j][(quad * 4 + 2) * 16 + q16] = O[j].z;
        sO[wv][j][(quad * 4 + 3) * 16 + q16] = O[j].w;
        sl[wv][j][quad * 16 + q16] = l[j];
    }
    __syncthreads();
    int t = threadIdx.x;
    float* pb = part + (size_t)((nh * 36 + strip) * 2 + hb) * 1280;
    #pragma unroll
    for (int j = 0; j < 4; ++j)
        pb[j * 256 + t] = (sO[0][j][t] + sO[1][j][t]) + (sO[2][j][t] + sO[3][j][t]);
    {
        int j2 = t >> 6, i2 = t & 63;
        pb[1024 + t] = (sl[0][j2][i2] + sl[1][j2][i2]) + (sl[2][j2][i2] + sl[3][j2][i2]);
    }
}

// ---------------------------------------------------------------------------
// A2mean[n,c] = mean over 2116 positions of v2[n,c,:]
__global__ __launch_bounds__(256) void k_mean(const float* __restrict__ v2,
                                              float* __restrict__ a2m) {
    int n = blockIdx.x >> 6, c = blockIdx.x & 63;
    const float* p = v2 + (size_t)(n * CIN + c) * DD;
    float s = 0.f;
    for (int d = threadIdx.x; d < DD; d += 256) s += p[d];
    #pragma unroll
    for (int off = 32; off > 0; off >>= 1) s += __shfl_down(s, off);
    __shared__ float red[4];
    int lane = threadIdx.x & 63, wv = threadIdx.x >> 6;
    if (lane == 0) red[wv] = s;
    __syncthreads();
    if (threadIdx.x == 0)
        a2m[blockIdx.x] = (red[0] + red[1] + red[2] + red[3]) * (1.f / 2116.f);
}

// ---------------------------------------------------------------------------
// Gates + LSTM nonlinearity + output 1x1 conv, fused with attention combine
// and constant-gate projection (validated round 12).
__global__ __launch_bounds__(256) void k_gates(const float* __restrict__ part,
                                               const float* __restrict__ a2m,
                                               const float* __restrict__ Wproj,
                                               const float* __restrict__ bg,
                                               const float* __restrict__ Wout,
                                               const float* __restrict__ bout,
                                               float* __restrict__ out) {
    __shared__ float a0s[64][16];
    __shared__ float wps[3][64][64];   // [gi][c][o]
    __shared__ float hs[16][68];
    __shared__ float invs[4][16];      // [h][px] softmax denominators
    __shared__ float c2s[3][64];       // constant gate pre-activations
    int n = blockIdx.y;
    int pt = blockIdx.x;
    int strip = pt >> 2, jq = pt & 3;
    int p0 = pt * 16;
    int tid = threadIdx.x;

    if (tid < 64) {                    // denominators
        int h = tid >> 4, q = tid & 15;
        const float* b0 = part + (size_t)(((n * 4 + h) * 36 + strip) * 2) * 1280;
        const float* b1 = b0 + 1280;
        float s = 0.f;
        #pragma unroll
        for (int quad = 0; quad < 4; ++quad)
            s += b0[1024 + jq * 64 + quad * 16 + q] + b1[1024 + jq * 64 + quad * 16 + q];
        invs[h][q] = 1.f / (s - 60.f);
    } else {                           // constant gates
        int gi = (tid - 64) >> 6, o = tid & 63;
        int g = (gi == 0) ? 0 : (gi == 1) ? 2 : 3;
        float acc = bg[g * CIN + o];
        const float* wp = Wproj + ((size_t)(g * 4 + 2) * CIN + o) * CIN;
        const float* am = a2m + n * CIN;
        #pragma unroll 8
        for (int c = 0; c < CIN; ++c) acc += wp[c] * am[c];
        c2s[gi][o] = acc;
    }
    __syncthreads();

    for (int idx = tid; idx < 1024; idx += 256) {   // a0 tile from part
        int c = idx >> 4, px = idx & 15;
        int h = c >> 4, c16 = c & 15;
        const float* b0 = part + (size_t)(((n * 4 + h) * 36 + strip) * 2) * 1280;
        const float* b1 = b0 + 1280;
        int off = jq * 256 + c16 * 16 + px;
        a0s[c][px] = (b0[off] + b1[off]) * invs[h][px];
    }
    for (int idx = tid; idx < 12288; idx += 256) {
        int o = idx & 63; int rest = idx >> 6; int c = rest & 63; int gi = rest >> 6;
        int g = (gi == 0) ? 0 : (gi == 1) ? 2 : 3;
        wps[gi][c][o] = Wproj[((size_t)(g * 4 + 0) * CIN + o) * CIN + c];
    }
    __syncthreads();

    int o = tid & 63, pg = tid >> 6;
    float pi[4], pgt[4], po[4];
    {
        float ci = c2s[0][o], cg = c2s[1][o], co = c2s[2][o];
        #pragma unroll
        for (int j = 0; j < 4; ++j) { pi[j] = ci; pgt[j] = cg; po[j] = co; }
    }
    const float4* a4 = (const float4*)&a0s[0][0];
    #pragma unroll 4
    for (int c = 0; c < 64; ++c) {
        float4 av = a4[c * 4 + pg];
        float w0 = wps[0][c][o], w1 = wps[1][c][o], w2 = wps[2][c][o];
        pi[0]  += w0 * av.x; pi[1]  += w0 * av.y; pi[2]  += w0 * av.z; pi[3]  += w0 * av.w;
        pgt[0] += w1 * av.x; pgt[1] += w1 * av.y; pgt[2] += w1 * av.z; pgt[3] += w1 * av.w;
        po[0]  += w2 * av.x; po[1]  += w2 * av.y; po[2]  += w2 * av.z; po[3]  += w2 * av.w;
    }
    #pragma unroll
    for (int j = 0; j < 4; ++j) {
        float ii = 1.f / (1.f + __expf(-pi[j]));
        float gg = tanhf(pgt[j]);
        float oo = 1.f / (1.f + __expf(-po[j]));
        float cc = ii * gg;
        hs[pg * 4 + j][o] = oo * tanhf(cc);
    }
    __syncthreads();
    float acc[4];
    float bo = bout[o];
    #pragma unroll
    for (int j = 0; j < 4; ++j) acc[j] = bo;
    const float* wo = Wout + o * CIN;
    #pragma unroll 2
    for (int cg_ = 0; cg_ < 16; ++cg_) {
        float w0 = wo[cg_ * 4 + 0], w1 = wo[cg_ * 4 + 1], w2 = wo[cg_ * 4 + 2], w3 = wo[cg_ * 4 + 3];
        #pragma unroll
        for (int j = 0; j < 4; ++j) {
            const float4 hv = *(const float4*)&hs[pg * 4 + j][cg_ * 4];
            acc[j] += w0 * hv.x + w1 * hv.y + w2 * hv.z + w3 * hv.w;
        }
    }
    #pragma unroll
    for (int j = 0; j < 4; ++j)
        out[(size_t)(n * CIN + o) * HW + p0 + pg * 4 + j] = acc[j];
}

// ---------------------------------------------------------------------------
extern "C" void kernel_launch(void* const* d_in, const int* in_sizes, int n_in,
                              void* d_out, int out_size, void* d_ws, size_t ws_size,
                              hipStream_t stream) {
    const float* x     = (const float*)d_in[0];
    const float* W_in  = (const float*)d_in[1];
    const float* b_in  = (const float*)d_in[2];
    const float* Wq    = (const float*)d_in[3];
    const float* Wk    = (const float*)d_in[4];
    const float* Wv    = (const float*)d_in[5];
    const float* Wproj = (const float*)d_in[6];
    const float* b_g   = (const float*)d_in[7];
    const float* W_out = (const float*)d_in[8];
    const float* b_out = (const float*)d_in[9];
    float* out = (float*)d_out;

    float* q0   = (float*)d_ws;          // 589824
    float* k0   = q0 + 589824;           // 541696
    float* v0   = k0 + 541696;           // 541696
    float* v2   = v0 + 541696;           // 541696
    float* a2m  = v2 + 541696;           // 256
    float* part = a2m + 256;             // 16*36*2*1280 = 1474560
    unsigned short* Qb = (unsigned short*)(part + 1474560);  // 16*144*512
    unsigned short* Kb = Qb + (size_t)16 * QTL * 512;        // 16*136*512
    unsigned short* Vb = Kb + (size_t)16 * NT * 512;         // 16*136*512
    unsigned short* xb = Vb + (size_t)16 * NT * 512;         // 4*16*2500*8
    unsigned short* Wb = xb + (size_t)4 * 16 * 2500 * 8;     // 16*9*4*512
    // total ~25 MB of workspace

    k_xw    <<<dim3(784), 256, 0, stream>>>(x, W_in, b_in, Wq, Wk, Wv, xb, Wb);
    k_conv  <<<dim3(48, 4, 4), 256, 0, stream>>>(xb, Wb, q0, k0, v0, v2);
    k_cvt   <<<dim3(144, 16), 256, 0, stream>>>(q0, k0, v0, Qb, Kb, Vb);
    k_mattn <<<dim3(72, 16), 256, 0, stream>>>(Qb, Kb, Vb, part);
    k_mean  <<<dim3(256), 256, 0, stream>>>(v2, a2m);
    k_gates <<<dim3(144, 4), 256, 0, stream>>>(part, a2m, Wproj, b_g, W_out, b_out, out);
}

// Round 15
// 177.845 us; speedup vs baseline: 1.6050x; 1.0070x over previous
//
#include <hip/hip_runtime.h>
#include <math.h>

// Problem constants
#define NB   4      // batch
#define CIN  64     // channels everywhere (I=CR=CA=CO=64)
#define HH   48
#define WW   48
#define HW   2304   // 48*48
#define DH   46
#define DW   46
#define DD   2116   // 46*46
#define NHEAD 4
#define HC   16
#define NT   136    // padded d-tiles (2176 = 136*16; 60 zero-pads)
#define QTL  144    // q-tiles (2304 = 144*16)
#define GS   20000  // xb group stride in shorts (2500 cells * 8)

typedef short  s4 __attribute__((ext_vector_type(4)));
typedef short  s8 __attribute__((ext_vector_type(8)));
typedef float  f4 __attribute__((ext_vector_type(4)));

__device__ __forceinline__ void split4(f4 a, s4& hi, s4& lo) {
    #pragma unroll
    for (int r = 0; r < 4; ++r) {
        unsigned u = __builtin_bit_cast(unsigned, a[r]);
        hi[r] = (short)(u >> 16);
        float l = a[r] - __builtin_bit_cast(float, u & 0xffff0000u);
        lo[r] = (short)(__builtin_bit_cast(unsigned, l) >> 16);
    }
}

// ---------------------------------------------------------------------------
// Fused input-projection (group-major bf16x2 xb) + weight repack (round-13).
__global__ __launch_bounds__(256) void k_xw(const float* __restrict__ x,
                                            const float* __restrict__ Win,
                                            const float* __restrict__ bin,
                                            const float* __restrict__ Wq,
                                            const float* __restrict__ Wk,
                                            const float* __restrict__ Wv,
                                            unsigned short* __restrict__ xb,
                                            unsigned short* __restrict__ Wb) {
    int b = blockIdx.x;
    if (b < 640) {
        int bx = b % 10, n = (b / 10) & 3, ocg = b / 40;
        int cell = bx * 256 + threadIdx.x;
        if (cell >= 2500) return;
        int cy = cell / 50, cx = cell - cy * 50;
        float a[4] = {0.f, 0.f, 0.f, 0.f};
        if (cy >= 1 && cy <= 48 && cx >= 1 && cx <= 48) {
            int px = (cy - 1) * 48 + (cx - 1);
            const float* xp = x + (size_t)(n * CIN) * HW + px;
            #pragma unroll
            for (int j = 0; j < 4; ++j) a[j] = bin[ocg * 4 + j];
            #pragma unroll 8
            for (int ic = 0; ic < CIN; ++ic) {
                float xv = xp[ic * HW];
                a[0] += Win[(ocg * 4 + 0) * CIN + ic] * xv;
                a[1] += Win[(ocg * 4 + 1) * CIN + ic] * xv;
                a[2] += Win[(ocg * 4 + 2) * CIN + ic] * xv;
                a[3] += Win[(ocg * 4 + 3) * CIN + ic] * xv;
            }
        }
        s8 st;
        #pragma unroll
        for (int j = 0; j < 4; ++j) {
            unsigned u = __builtin_bit_cast(unsigned, a[j]);
            st[j] = (short)(u >> 16);
            float lo = a[j] - __builtin_bit_cast(float, u & 0xffff0000u);
            st[4 + j] = (short)(__builtin_bit_cast(unsigned, lo) >> 16);
        }
        *(s8*)(xb + ((size_t)(n * 16 + ocg) * 2500 + cell) * 8) = st;
    } else {
        int bx = b - 640;
        int cq = bx / 9, tap = bx - cq * 9;
        int cv = cq >> 2, ocq = cq & 3;
        const float* src = (cv == 0) ? Wq : (cv == 1) ? Wk : (cv == 2) ? Wv
                                                          : (Wv + 2 * CIN * CIN * 9);
        int t = threadIdx.x;
        int m = t >> 4, kl = t & 15, quad = kl >> 2, j = kl & 3;
        #pragma unroll
        for (int kq = 0; kq < 4; ++kq) {
            float v = src[((size_t)(ocq * 16 + m) * CIN + kq * 16 + kl) * 9 + tap];
            unsigned u = __builtin_bit_cast(unsigned, v);
            float lo = v - __builtin_bit_cast(float, u & 0xffff0000u);
            size_t base = ((size_t)(cq * 9 + tap) * 4 + kq) * 512 + m * 32 + quad * 8 + j;
            Wb[base]     = (unsigned short)(u >> 16);
            Wb[base + 4] = (unsigned short)(__builtin_bit_cast(unsigned, lo) >> 16);
        }
    }
}

// ---------------------------------------------------------------------------
// Round-13 conv (coalesced group-major loads, SGB-pinned pipeline) with ONE
// change (bisect): cv==0 stores Qb fragments directly (bf16x2 split of the
// bit-identical acc; index math identical to what k_cvt's Q path produced).
// cv=1/2/3 keep the round-13 fp32 epilogue (k0/v0/v2, 46-grid).
// grid (48 y, 4 n, 4 cv), block 256 = 4 waves = 4 oc-groups.
__global__ __launch_bounds__(256, 3) void k_conv(const unsigned short* __restrict__ xb,
                                                 const unsigned short* __restrict__ Wb,
                                                 unsigned short* __restrict__ Qb,
                                                 float* __restrict__ k0,
                                                 float* __restrict__ v0,
                                                 float* __restrict__ v2) {
    int y = blockIdx.x, n = blockIdx.y, cv = blockIdx.z;
    int outw = (cv == 0) ? 48 : 46;
    int pd   = (cv == 0) ? 0 : 1;
    if (y >= outw) return;
    int lane = threadIdx.x & 63, wv = threadIdx.x >> 6;
    int m16 = lane & 15, quad = lane >> 4;
    const unsigned short* Wt = Wb + (size_t)(cv * 4 + wv) * 9 * 2048 + m16 * 32 + quad * 8;
    // OOB impossible: worst cell 48*50+50 = 2450 < 2500.
    const unsigned short* B0 = xb + (size_t)(n * 16 + quad) * GS
                                  + ((size_t)(y + pd) * 50 + pd + m16) * 8;

    f4 a0 = {0.f, 0.f, 0.f, 0.f}, a1 = a0, a2 = a0;

    s8 w[4], c0[4], c1[4], c2[4];
    #pragma unroll
    for (int kq = 0; kq < 4; ++kq) {       // tap 0 prefetch
        w[kq]  = *(const s8*)(Wt + kq * 512);
        c0[kq] = *(const s8*)(B0 + (size_t)kq * 4 * GS);
        c1[kq] = *(const s8*)(B0 + (size_t)kq * 4 * GS + 128);
        c2[kq] = *(const s8*)(B0 + (size_t)kq * 4 * GS + 256);
    }
    __builtin_amdgcn_sched_group_barrier(0x020, 16, 0);

    #pragma unroll
    for (int tap = 0; tap < 9; ++tap) {
        s8 wn[4], n0[4], n1[4], n2[4];
        if (tap < 8) {
            int tn = tap + 1;
            int dy = tn / 3, dx = tn - dy * 3;
            const unsigned short* bq = B0 + (size_t)(dy * 50 + dx) * 8;
            const unsigned short* wp = Wt + tn * 2048;
            #pragma unroll
            for (int kq = 0; kq < 4; ++kq) {
                wn[kq] = *(const s8*)(wp + kq * 512);
                n0[kq] = *(const s8*)(bq + (size_t)kq * 4 * GS);
                n1[kq] = *(const s8*)(bq + (size_t)kq * 4 * GS + 128);
                n2[kq] = *(const s8*)(bq + (size_t)kq * 4 * GS + 256);
            }
        }
        #pragma unroll
        for (int kq = 0; kq < 4; ++kq) {
            s4 ah  = __builtin_shufflevector(w[kq], w[kq], 0, 1, 2, 3);
            s4 al  = __builtin_shufflevector(w[kq], w[kq], 4, 5, 6, 7);
            s4 bh0 = __builtin_shufflevector(c0[kq], c0[kq], 0, 1, 2, 3);
            s4 bl0 = __builtin_shufflevector(c0[kq], c0[kq], 4, 5, 6, 7);
            s4 bh1 = __builtin_shufflevector(c1[kq], c1[kq], 0, 1, 2, 3);
            s4 bl1 = __builtin_shufflevector(c1[kq], c1[kq], 4, 5, 6, 7);
            s4 bh2 = __builtin_shufflevector(c2[kq], c2[kq], 0, 1, 2, 3);
            s4 bl2 = __builtin_shufflevector(c2[kq], c2[kq], 4, 5, 6, 7);
            a0 = __builtin_amdgcn_mfma_f32_16x16x16bf16_1k(ah, bh0, a0, 0, 0, 0);
            a1 = __builtin_amdgcn_mfma_f32_16x16x16bf16_1k(ah, bh1, a1, 0, 0, 0);
            a2 = __builtin_amdgcn_mfma_f32_16x16x16bf16_1k(ah, bh2, a2, 0, 0, 0);
            a0 = __builtin_amdgcn_mfma_f32_16x16x16bf16_1k(al, bh0, a0, 0, 0, 0);
            a1 = __builtin_amdgcn_mfma_f32_16x16x16bf16_1k(al, bh1, a1, 0, 0, 0);
            a2 = __builtin_amdgcn_mfma_f32_16x16x16bf16_1k(al, bh2, a2, 0, 0, 0);
            a0 = __builtin_amdgcn_mfma_f32_16x16x16bf16_1k(ah, bl0, a0, 0, 0, 0);
            a1 = __builtin_amdgcn_mfma_f32_16x16x16bf16_1k(ah, bl1, a1, 0, 0, 0);
            a2 = __builtin_amdgcn_mfma_f32_16x16x16bf16_1k(ah, bl2, a2, 0, 0, 0);
        }
        if (tap < 8) __builtin_amdgcn_sched_group_barrier(0x020, 16, 0);
        __builtin_amdgcn_sched_group_barrier(0x008, 36, 0);
        if (tap < 8) {
            #pragma unroll
            for (int kq = 0; kq < 4; ++kq) {
                w[kq] = wn[kq]; c0[kq] = n0[kq]; c1[kq] = n1[kq]; c2[kq] = n2[kq];
            }
        }
    }

    if (cv == 0) {
        // acc[r] = C[oc=quad*4+r][px=m16]; Qb tile [q][c] at q*16+c ->
        // index m16*16 + quad*4 + r. Same bytes k_cvt's Q path produced.
        int nh = n * 4 + wv;
        unsigned short* dst = Qb + ((size_t)(nh * QTL + y * 3)) * 512 + m16 * 16 + quad * 4;
        f4 accs[3] = {a0, a1, a2};
        #pragma unroll
        for (int xt = 0; xt < 3; ++xt) {
            s4 hi, lo;
            split4(accs[xt], hi, lo);
            *(s4*)(dst + xt * 512) = hi;
            *(s4*)(dst + xt * 512 + 256) = lo;
        }
    } else {
        float* ob = (cv == 1) ? k0 : (cv == 2) ? v0 : v2;
        size_t outsz = (size_t)outw * outw;
        float* opb = ob + (size_t)(n * CIN + wv * 16 + quad * 4) * outsz + (size_t)y * outw;
        {   // tiles 0,1 always in-bounds
            float* op = opb + m16;
            op[0] = a0.x; op[outsz] = a0.y; op[2 * outsz] = a0.z; op[3 * outsz] = a0.w;
            op = opb + 16 + m16;
            op[0] = a1.x; op[outsz] = a1.y; op[2 * outsz] = a1.z; op[3 * outsz] = a1.w;
        }
        if (32 + m16 < outw) {
            float* op = opb + 32 + m16;
            op[0] = a2.x; op[outsz] = a2.y; op[2 * outsz] = a2.z; op[3 * outsz] = a2.w;
        }
    }
}

// ---------------------------------------------------------------------------
// Convert k0/v0 fp32 -> MFMA-tiled bf16x2 (round-13 K/V section; Q removed).
// grid (136, 16 nh), block 256.
__global__ __launch_bounds__(256) void k_cvt(const float* __restrict__ k0,
                                             const float* __restrict__ v0,
                                             unsigned short* __restrict__ Kb,
                                             unsigned short* __restrict__ Vb) {
    __shared__ float sm[272];            // 16x16 transpose pad 17
    int bx = blockIdx.x, nh = blockIdx.y;
    int n = nh >> 2, h = nh & 3;
    int t = threadIdx.x;
    int c = t >> 4, d = t & 15;
    int dgl = bx * 16 + d;
    float kv = (dgl < DD) ? k0[(size_t)(n * CIN + h * HC + c) * DD + dgl] : 0.f;
    sm[c * 17 + d] = kv;
    __syncthreads();
    {
        int d2 = t >> 4, c2 = t & 15;
        float v = sm[c2 * 17 + d2];
        unsigned u = __builtin_bit_cast(unsigned, v);
        unsigned short* dst = Kb + (size_t)(nh * NT + bx) * 512;
        dst[t] = (unsigned short)(u >> 16);
        float lo = v - __builtin_bit_cast(float, u & 0xffff0000u);
        dst[256 + t] = (unsigned short)(__builtin_bit_cast(unsigned, lo) >> 16);
    }
    {
        float vv = (dgl < DD) ? v0[(size_t)(n * CIN + h * HC + c) * DD + dgl] : 0.f;
        unsigned u = __builtin_bit_cast(unsigned, vv);
        unsigned short* dst = Vb + (size_t)(nh * NT + bx) * 512;
        dst[t] = (unsigned short)(u >> 16);
        float lo = vv - __builtin_bit_cast(float, u & 0xffff0000u);
        dst[256 + t] = (unsigned short)(__builtin_bit_cast(unsigned, lo) >> 16);
    }
}

// ---------------------------------------------------------------------------
// MFMA attention (round-13 exact: NT=136, 17 iters). grid (72, 16), block 256.
__global__ __launch_bounds__(256) void k_mattn(const unsigned short* __restrict__ Qb,
                                               const unsigned short* __restrict__ Kb,
                                               const unsigned short* __restrict__ Vb,
                                               float* __restrict__ part) {
    __shared__ float sO[4][4][256];
    __shared__ float sl[4][4][64];
    int strip = blockIdx.x >> 1, hb = blockIdx.x & 1, nh = blockIdx.y;
    int lane = threadIdx.x & 63, wv = threadIdx.x >> 6;
    int ds = hb * 4 + wv;
    int q16 = lane & 15, quad = lane >> 4;
    int foff = q16 * 16 + quad * 4;

    s4 qh[4], ql[4];
    #pragma unroll
    for (int j = 0; j < 4; ++j) {
        const unsigned short* Qp = Qb + (size_t)(nh * QTL + strip * 4 + j) * 512 + foff;
        qh[j] = *(const s4*)(Qp);
        ql[j] = *(const s4*)(Qp + 256);
    }
    f4 O[4];
    float l[4];
    #pragma unroll
    for (int j = 0; j < 4; ++j) { O[j] = (f4){0.f, 0.f, 0.f, 0.f}; l[j] = 0.f; }

    const unsigned short* Kp = Kb + (size_t)(nh * NT + ds * 17) * 512 + foff;
    const unsigned short* Vp = Vb + (size_t)(nh * NT + ds * 17) * 512 + foff;
    s4 khi = *(const s4*)(Kp);
    s4 klo = *(const s4*)(Kp + 256);
    s4 vhi = *(const s4*)(Vp);
    s4 vlo = *(const s4*)(Vp + 256);

    for (int it = 0; it < 17; ++it) {
        int nxt = (it < 16) ? (it + 1) * 512 : 0;
        s4 nkhi = *(const s4*)(Kp + nxt);
        s4 nklo = *(const s4*)(Kp + nxt + 256);
        s4 nvhi = *(const s4*)(Vp + nxt);
        s4 nvlo = *(const s4*)(Vp + nxt + 256);

        #pragma unroll
        for (int j = 0; j < 4; ++j) {
            f4 c1 = (f4){0.f, 0.f, 0.f, 0.f};
            c1 = __builtin_amdgcn_mfma_f32_16x16x16bf16_1k(khi, qh[j], c1, 0, 0, 0);
            c1 = __builtin_amdgcn_mfma_f32_16x16x16bf16_1k(klo, qh[j], c1, 0, 0, 0);
            c1 = __builtin_amdgcn_mfma_f32_16x16x16bf16_1k(khi, ql[j], c1, 0, 0, 0);
            float p0 = __expf(c1.x), p1 = __expf(c1.y);
            float p2 = __expf(c1.z), p3 = __expf(c1.w);
            l[j] += (p0 + p1) + (p2 + p3);
            unsigned u0 = __builtin_bit_cast(unsigned, p0);
            unsigned u1 = __builtin_bit_cast(unsigned, p1);
            unsigned u2 = __builtin_bit_cast(unsigned, p2);
            unsigned u3 = __builtin_bit_cast(unsigned, p3);
            s4 ph;
            ph.x = (short)(u0 >> 16); ph.y = (short)(u1 >> 16);
            ph.z = (short)(u2 >> 16); ph.w = (short)(u3 >> 16);
            float r0 = p0 - __builtin_bit_cast(float, u0 & 0xffff0000u);
            float r1 = p1 - __builtin_bit_cast(float, u1 & 0xffff0000u);
            float r2 = p2 - __builtin_bit_cast(float, u2 & 0xffff0000u);
            float r3 = p3 - __builtin_bit_cast(float, u3 & 0xffff0000u);
            s4 pl;
            pl.x = (short)(__builtin_bit_cast(unsigned, r0) >> 16);
            pl.y = (short)(__builtin_bit_cast(unsigned, r1) >> 16);
            pl.z = (short)(__builtin_bit_cast(unsigned, r2) >> 16);
            pl.w = (short)(__builtin_bit_cast(unsigned, r3) >> 16);
            O[j] = __builtin_amdgcn_mfma_f32_16x16x16bf16_1k(vhi, ph, O[j], 0, 0, 0);
            O[j] = __builtin_amdgcn_mfma_f32_16x16x16bf16_1k(vlo, ph, O[j], 0, 0, 0);
            O[j] = __builtin_amdgcn_mfma_f32_16x16x16bf16_1k(vhi, pl, O[j], 0, 0, 0);
        }
        khi = nkhi; klo = nklo; vhi = nvhi; vlo = nvlo;
    }

    #pragma unroll
    for (int j = 0; j < 4; ++j) {
        sO[wv][j][(quad * 4 + 0) * 16 + q16] = O[j].x;
        sO[wv][j][(quad * 4 + 1) * 16 + q16] = O[j].y;
        sO[wv][j][(quad * 4 + 2) * 16 + q16] = O[j].z;
        sO[wv][j][(quad * 4 + 3) * 16 + q16] = O[j].w;
        sl[wv][j][quad * 16 + q16] = l[j];
    }
    __syncthreads();
    int t = threadIdx.x;
    float* pb = part + (size_t)((nh * 36 + strip) * 2 + hb) * 1280;
    #pragma unroll
    for (int j = 0; j < 4; ++j)
        pb[j * 256 + t] = (sO[0][j][t] + sO[1][j][t]) + (sO[2][j][t] + sO[3][j][t]);
    {
        int j2 = t >> 6, i2 = t & 63;
        pb[1024 + t] = (sl[0][j2][i2] + sl[1][j2][i2]) + (sl[2][j2][i2] + sl[3][j2][i2]);
    }
}

// ---------------------------------------------------------------------------
// A2mean[n,c] = mean over 2116 positions of v2[n,c,:]  (round-13 exact)
__global__ __launch_bounds__(256) void k_mean(const float* __restrict__ v2,
                                              float* __restrict__ a2m) {
    int n = blockIdx.x >> 6, c = blockIdx.x & 63;
    const float* p = v2 + (size_t)(n * CIN + c) * DD;
    float s = 0.f;
    for (int d = threadIdx.x; d < DD; d += 256) s += p[d];
    #pragma unroll
    for (int off = 32; off > 0; off >>= 1) s += __shfl_down(s, off);
    __shared__ float red[4];
    int lane = threadIdx.x & 63, wv = threadIdx.x >> 6;
    if (lane == 0) red[wv] = s;
    __syncthreads();
    if (threadIdx.x == 0)
        a2m[blockIdx.x] = (red[0] + red[1] + red[2] + red[3]) * (1.f / 2116.f);
}

// ---------------------------------------------------------------------------
// Gates + LSTM + output 1x1 conv, fused with attention combine (-60) and
// constant-gate projection (round-13 exact).
__global__ __launch_bounds__(256) void k_gates(const float* __restrict__ part,
                                               const float* __restrict__ a2m,
                                               const float* __restrict__ Wproj,
                                               const float* __restrict__ bg,
                                               const float* __restrict__ Wout,
                                               const float* __restrict__ bout,
                                               float* __restrict__ out) {
    __shared__ float a0s[64][16];
    __shared__ float wps[3][64][64];   // [gi][c][o]
    __shared__ float hs[16][68];
    __shared__ float invs[4][16];      // [h][px] softmax denominators
    __shared__ float c2s[3][64];       // constant gate pre-activations
    int n = blockIdx.y;
    int pt = blockIdx.x;
    int strip = pt >> 2, jq = pt & 3;
    int p0 = pt * 16;
    int tid = threadIdx.x;

    if (tid < 64) {                    // denominators
        int h = tid >> 4, q = tid & 15;
        const float* b0 = part + (size_t)(((n * 4 + h) * 36 + strip) * 2) * 1280;
        const float* b1 = b0 + 1280;
        float s = 0.f;
        #pragma unroll
        for (int quad = 0; quad < 4; ++quad)
            s += b0[1024 + jq * 64 + quad * 16 + q] + b1[1024 + jq * 64 + quad * 16 + q];
        invs[h][q] = 1.f / (s - 60.f);
    } else {                           // constant gates
        int gi = (tid - 64) >> 6, o = tid & 63;
        int g = (gi == 0) ? 0 : (gi == 1) ? 2 : 3;
        float acc = bg[g * CIN + o];
        const float* wp = Wproj + ((size_t)(g * 4 + 2) * CIN + o) * CIN;
        const float* am = a2m + n * CIN;
        #pragma unroll 8
        for (int c = 0; c < CIN; ++c) acc += wp[c] * am[c];
        c2s[gi][o] = acc;
    }
    __syncthreads();

    for (int idx = tid; idx < 1024; idx += 256) {   // a0 tile from part
        int c = idx >> 4, px = idx & 15;
        int h = c >> 4, c16 = c & 15;
        const float* b0 = part + (size_t)(((n * 4 + h) * 36 + strip) * 2) * 1280;
        const float* b1 = b0 + 1280;
        int off = jq * 256 + c16 * 16 + px;
        a0s[c][px] = (b0[off] + b1[off]) * invs[h][px];
    }
    for (int idx = tid; idx < 12288; idx += 256) {
        int o = idx & 63; int rest = idx >> 6; int c = rest & 63; int gi = rest >> 6;
        int g = (gi == 0) ? 0 : (gi == 1) ? 2 : 3;
        wps[gi][c][o] = Wproj[((size_t)(g * 4 + 0) * CIN + o) * CIN + c];
    }
    __syncthreads();

    int o = tid & 63, pg = tid >> 6;
    float pi[4], pgt[4], po[4];
    {
        float ci = c2s[0][o], cg = c2s[1][o], co = c2s[2][o];
        #pragma unroll
        for (int j = 0; j < 4; ++j) { pi[j] = ci; pgt[j] = cg; po[j] = co; }
    }
    const float4* a4 = (const float4*)&a0s[0][0];
    #pragma unroll 4
    for (int c = 0; c < 64; ++c) {
        float4 av = a4[c * 4 + pg];
        float w0 = wps[0][c][o], w1 = wps[1][c][o], w2 = wps[2][c][o];
        pi[0]  += w0 * av.x; pi[1]  += w0 * av.y; pi[2]  += w0 * av.z; pi[3]  += w0 * av.w;
        pgt[0] += w1 * av.x; pgt[1] += w1 * av.y; pgt[2] += w1 * av.z; pgt[3] += w1 * av.w;
        po[0]  += w2 * av.x; po[1]  += w2 * av.y; po[2]  += w2 * av.z; po[3]  += w2 * av.w;
    }
    #pragma unroll
    for (int j = 0; j < 4; ++j) {
        float ii = 1.f / (1.f + __expf(-pi[j]));
        float gg = tanhf(pgt[j]);
        float oo = 1.f / (1.f + __expf(-po[j]));
        float cc = ii * gg;
        hs[pg * 4 + j][o] = oo * tanhf(cc);
    }
    __syncthreads();
    float acc[4];
    float bo = bout[o];
    #pragma unroll
    for (int j = 0; j < 4; ++j) acc[j] = bo;
    const float* wo = Wout + o * CIN;
    #pragma unroll 2
    for (int cg_ = 0; cg_ < 16; ++cg_) {
        float w0 = wo[cg_ * 4 + 0], w1 = wo[cg_ * 4 + 1], w2 = wo[cg_ * 4 + 2], w3 = wo[cg_ * 4 + 3];
        #pragma unroll
        for (int j = 0; j < 4; ++j) {
            const float4 hv = *(const float4*)&hs[pg * 4 + j][cg_ * 4];
            acc[j] += w0 * hv.x + w1 * hv.y + w2 * hv.z + w3 * hv.w;
        }
    }
    #pragma unroll
    for (int j = 0; j < 4; ++j)
        out[(size_t)(n * CIN + o) * HW + p0 + pg * 4 + j] = acc[j];
}

// ---------------------------------------------------------------------------
extern "C" void kernel_launch(void* const* d_in, const int* in_sizes, int n_in,
                              void* d_out, int out_size, void* d_ws, size_t ws_size,
                              hipStream_t stream) {
    const float* x     = (const float*)d_in[0];
    const float* W_in  = (const float*)d_in[1];
    const float* b_in  = (const float*)d_in[2];
    const float* Wq    = (const float*)d_in[3];
    const float* Wk    = (const float*)d_in[4];
    const float* Wv    = (const float*)d_in[5];
    const float* Wproj = (const float*)d_in[6];
    const float* b_g   = (const float*)d_in[7];
    const float* W_out = (const float*)d_in[8];
    const float* b_out = (const float*)d_in[9];
    float* out = (float*)d_out;

    float* k0   = (float*)d_ws;          // 541696
    float* v0   = k0 + 541696;           // 541696
    float* v2   = v0 + 541696;           // 541696
    float* a2m  = v2 + 541696;           // 256
    float* part = a2m + 256;             // 16*36*2*1280 = 1474560
    unsigned short* Qb = (unsigned short*)(part + 1474560);  // 16*144*512
    unsigned short* Kb = Qb + (size_t)16 * QTL * 512;        // 16*136*512
    unsigned short* Vb = Kb + (size_t)16 * NT * 512;         // 16*136*512
    unsigned short* xb = Vb + (size_t)16 * NT * 512;         // 4*16*2500*8
    unsigned short* Wb = xb + (size_t)4 * 16 * 2500 * 8;     // 16*9*4*512
    // total ~25 MB of workspace

    k_xw    <<<dim3(784), 256, 0, stream>>>(x, W_in, b_in, Wq, Wk, Wv, xb, Wb);
    k_conv  <<<dim3(48, 4, 4), 256, 0, stream>>>(xb, Wb, Qb, k0, v0, v2);
    k_cvt   <<<dim3(136, 16), 256, 0, stream>>>(k0, v0, Kb, Vb);
    k_mattn <<<dim3(72, 16), 256, 0, stream>>>(Qb, Kb, Vb, part);
    k_mean  <<<dim3(256), 256, 0, stream>>>(v2, a2m);
    k_gates <<<dim3(144, 4), 256, 0, stream>>>(part, a2m, Wproj, b_g, W_out, b_out, out);
}

// Round 16
// 174.630 us; speedup vs baseline: 1.6346x; 1.0184x over previous
//
#include <hip/hip_runtime.h>
#include <math.h>

// Problem constants
#define NB   4      // batch
#define CIN  64     // channels everywhere (I=CR=CA=CO=64)
#define HH   48
#define WW   48
#define HW   2304   // 48*48
#define DH   46
#define DW   46
#define DD   2116   // 46*46
#define NHEAD 4
#define HC   16
#define NT   136    // padded d-tiles (2176 = 136*16; 60 zero-pads)
#define QTL  144    // q-tiles (2304 = 144*16)
#define GS   20000  // xb group stride in shorts (2500 cells * 8)

typedef short  s4 __attribute__((ext_vector_type(4)));
typedef short  s8 __attribute__((ext_vector_type(8)));
typedef float  f4 __attribute__((ext_vector_type(4)));

__device__ __forceinline__ void split4(f4 a, s4& hi, s4& lo) {
    #pragma unroll
    for (int r = 0; r < 4; ++r) {
        unsigned u = __builtin_bit_cast(unsigned, a[r]);
        hi[r] = (short)(u >> 16);
        float l = a[r] - __builtin_bit_cast(float, u & 0xffff0000u);
        lo[r] = (short)(__builtin_bit_cast(unsigned, l) >> 16);
    }
}

// ---------------------------------------------------------------------------
// Fused input-projection (group-major bf16x2 xb) + weight repack + a2m init.
// Blocks 0..639: xb. Blocks 640..783: Wb. Block 784: a2m = 0.
__global__ __launch_bounds__(256) void k_xw(const float* __restrict__ x,
                                            const float* __restrict__ Win,
                                            const float* __restrict__ bin,
                                            const float* __restrict__ Wq,
                                            const float* __restrict__ Wk,
                                            const float* __restrict__ Wv,
                                            unsigned short* __restrict__ xb,
                                            unsigned short* __restrict__ Wb,
                                            float* __restrict__ a2m) {
    int b = blockIdx.x;
    if (b == 784) {
        a2m[threadIdx.x] = 0.f;        // 256 = NB*CIN; k_conv cv==3 accumulates
        return;
    }
    if (b < 640) {
        int bx = b % 10, n = (b / 10) & 3, ocg = b / 40;
        int cell = bx * 256 + threadIdx.x;
        if (cell >= 2500) return;
        int cy = cell / 50, cx = cell - cy * 50;
        float a[4] = {0.f, 0.f, 0.f, 0.f};
        if (cy >= 1 && cy <= 48 && cx >= 1 && cx <= 48) {
            int px = (cy - 1) * 48 + (cx - 1);
            const float* xp = x + (size_t)(n * CIN) * HW + px;
            #pragma unroll
            for (int j = 0; j < 4; ++j) a[j] = bin[ocg * 4 + j];
            #pragma unroll 8
            for (int ic = 0; ic < CIN; ++ic) {
                float xv = xp[ic * HW];
                a[0] += Win[(ocg * 4 + 0) * CIN + ic] * xv;
                a[1] += Win[(ocg * 4 + 1) * CIN + ic] * xv;
                a[2] += Win[(ocg * 4 + 2) * CIN + ic] * xv;
                a[3] += Win[(ocg * 4 + 3) * CIN + ic] * xv;
            }
        }
        s8 st;
        #pragma unroll
        for (int j = 0; j < 4; ++j) {
            unsigned u = __builtin_bit_cast(unsigned, a[j]);
            st[j] = (short)(u >> 16);
            float lo = a[j] - __builtin_bit_cast(float, u & 0xffff0000u);
            st[4 + j] = (short)(__builtin_bit_cast(unsigned, lo) >> 16);
        }
        *(s8*)(xb + ((size_t)(n * 16 + ocg) * 2500 + cell) * 8) = st;
    } else {
        int bx = b - 640;
        int cq = bx / 9, tap = bx - cq * 9;
        int cv = cq >> 2, ocq = cq & 3;
        const float* src = (cv == 0) ? Wq : (cv == 1) ? Wk : (cv == 2) ? Wv
                                                          : (Wv + 2 * CIN * CIN * 9);
        int t = threadIdx.x;
        int m = t >> 4, kl = t & 15, quad = kl >> 2, j = kl & 3;
        #pragma unroll
        for (int kq = 0; kq < 4; ++kq) {
            float v = src[((size_t)(ocq * 16 + m) * CIN + kq * 16 + kl) * 9 + tap];
            unsigned u = __builtin_bit_cast(unsigned, v);
            float lo = v - __builtin_bit_cast(float, u & 0xffff0000u);
            size_t base = ((size_t)(cq * 9 + tap) * 4 + kq) * 512 + m * 32 + quad * 8 + j;
            Wb[base]     = (unsigned short)(u >> 16);
            Wb[base + 4] = (unsigned short)(__builtin_bit_cast(unsigned, lo) >> 16);
        }
    }
}

// ---------------------------------------------------------------------------
// Round-15 conv (coalesced group-major loads, SGB-pinned pipeline, fused Q
// store — validated) with ONE new change (bisect step 2): cv==3 no longer
// materializes v2; it reduces each channel's row-sum in-wave (xor-butterfly
// over the 16 px lanes, cols 46/47 masked) and atomicAdds into a2m.
// cv=1/2 keep the round-13 fp32 epilogue (k0/v0, 46-grid).
// grid (48 y, 4 n, 4 cv), block 256 = 4 waves = 4 oc-groups.
__global__ __launch_bounds__(256, 3) void k_conv(const unsigned short* __restrict__ xb,
                                                 const unsigned short* __restrict__ Wb,
                                                 unsigned short* __restrict__ Qb,
                                                 float* __restrict__ k0,
                                                 float* __restrict__ v0,
                                                 float* __restrict__ a2m) {
    int y = blockIdx.x, n = blockIdx.y, cv = blockIdx.z;
    int outw = (cv == 0) ? 48 : 46;
    int pd   = (cv == 0) ? 0 : 1;
    if (y >= outw) return;
    int lane = threadIdx.x & 63, wv = threadIdx.x >> 6;
    int m16 = lane & 15, quad = lane >> 4;
    const unsigned short* Wt = Wb + (size_t)(cv * 4 + wv) * 9 * 2048 + m16 * 32 + quad * 8;
    // OOB impossible: worst cell 48*50+50 = 2450 < 2500.
    const unsigned short* B0 = xb + (size_t)(n * 16 + quad) * GS
                                  + ((size_t)(y + pd) * 50 + pd + m16) * 8;

    f4 a0 = {0.f, 0.f, 0.f, 0.f}, a1 = a0, a2 = a0;

    s8 w[4], c0[4], c1[4], c2[4];
    #pragma unroll
    for (int kq = 0; kq < 4; ++kq) {       // tap 0 prefetch
        w[kq]  = *(const s8*)(Wt + kq * 512);
        c0[kq] = *(const s8*)(B0 + (size_t)kq * 4 * GS);
        c1[kq] = *(const s8*)(B0 + (size_t)kq * 4 * GS + 128);
        c2[kq] = *(const s8*)(B0 + (size_t)kq * 4 * GS + 256);
    }
    __builtin_amdgcn_sched_group_barrier(0x020, 16, 0);

    #pragma unroll
    for (int tap = 0; tap < 9; ++tap) {
        s8 wn[4], n0[4], n1[4], n2[4];
        if (tap < 8) {
            int tn = tap + 1;
            int dy = tn / 3, dx = tn - dy * 3;
            const unsigned short* bq = B0 + (size_t)(dy * 50 + dx) * 8;
            const unsigned short* wp = Wt + tn * 2048;
            #pragma unroll
            for (int kq = 0; kq < 4; ++kq) {
                wn[kq] = *(const s8*)(wp + kq * 512);
                n0[kq] = *(const s8*)(bq + (size_t)kq * 4 * GS);
                n1[kq] = *(const s8*)(bq + (size_t)kq * 4 * GS + 128);
                n2[kq] = *(const s8*)(bq + (size_t)kq * 4 * GS + 256);
            }
        }
        #pragma unroll
        for (int kq = 0; kq < 4; ++kq) {
            s4 ah  = __builtin_shufflevector(w[kq], w[kq], 0, 1, 2, 3);
            s4 al  = __builtin_shufflevector(w[kq], w[kq], 4, 5, 6, 7);
            s4 bh0 = __builtin_shufflevector(c0[kq], c0[kq], 0, 1, 2, 3);
            s4 bl0 = __builtin_shufflevector(c0[kq], c0[kq], 4, 5, 6, 7);
            s4 bh1 = __builtin_shufflevector(c1[kq], c1[kq], 0, 1, 2, 3);
            s4 bl1 = __builtin_shufflevector(c1[kq], c1[kq], 4, 5, 6, 7);
            s4 bh2 = __builtin_shufflevector(c2[kq], c2[kq], 0, 1, 2, 3);
            s4 bl2 = __builtin_shufflevector(c2[kq], c2[kq], 4, 5, 6, 7);
            a0 = __builtin_amdgcn_mfma_f32_16x16x16bf16_1k(ah, bh0, a0, 0, 0, 0);
            a1 = __builtin_amdgcn_mfma_f32_16x16x16bf16_1k(ah, bh1, a1, 0, 0, 0);
            a2 = __builtin_amdgcn_mfma_f32_16x16x16bf16_1k(ah, bh2, a2, 0, 0, 0);
            a0 = __builtin_amdgcn_mfma_f32_16x16x16bf16_1k(al, bh0, a0, 0, 0, 0);
            a1 = __builtin_amdgcn_mfma_f32_16x16x16bf16_1k(al, bh1, a1, 0, 0, 0);
            a2 = __builtin_amdgcn_mfma_f32_16x16x16bf16_1k(al, bh2, a2, 0, 0, 0);
            a0 = __builtin_amdgcn_mfma_f32_16x16x16bf16_1k(ah, bl0, a0, 0, 0, 0);
            a1 = __builtin_amdgcn_mfma_f32_16x16x16bf16_1k(ah, bl1, a1, 0, 0, 0);
            a2 = __builtin_amdgcn_mfma_f32_16x16x16bf16_1k(ah, bl2, a2, 0, 0, 0);
        }
        if (tap < 8) __builtin_amdgcn_sched_group_barrier(0x020, 16, 0);
        __builtin_amdgcn_sched_group_barrier(0x008, 36, 0);
        if (tap < 8) {
            #pragma unroll
            for (int kq = 0; kq < 4; ++kq) {
                w[kq] = wn[kq]; c0[kq] = n0[kq]; c1[kq] = n1[kq]; c2[kq] = n2[kq];
            }
        }
    }

    if (cv == 0) {
        // acc[r] = C[oc=quad*4+r][px=m16]; Qb tile [q][c] at m16*16+quad*4+r.
        int nh = n * 4 + wv;
        unsigned short* dst = Qb + ((size_t)(nh * QTL + y * 3)) * 512 + m16 * 16 + quad * 4;
        f4 accs[3] = {a0, a1, a2};
        #pragma unroll
        for (int xt = 0; xt < 3; ++xt) {
            s4 hi, lo;
            split4(accs[xt], hi, lo);
            *(s4*)(dst + xt * 512) = hi;
            *(s4*)(dst + xt * 512 + 256) = lo;
        }
    } else if (cv == 3) {
        // v2 row-sums -> a2m (sums; k_gates divides by 2116)
        #pragma unroll
        for (int r = 0; r < 4; ++r) {
            float t = a0[r] + a1[r] + ((m16 < 14) ? a2[r] : 0.f);
            t += __shfl_xor(t, 1); t += __shfl_xor(t, 2);
            t += __shfl_xor(t, 4); t += __shfl_xor(t, 8);
            if (m16 == 0)
                atomicAdd(&a2m[n * CIN + wv * 16 + quad * 4 + r], t);
        }
    } else {
        float* ob = (cv == 1) ? k0 : v0;
        size_t outsz = (size_t)DD;
        float* opb = ob + (size_t)(n * CIN + wv * 16 + quad * 4) * outsz + (size_t)y * DW;
        {   // tiles 0,1 always in-bounds
            float* op = opb + m16;
            op[0] = a0.x; op[outsz] = a0.y; op[2 * outsz] = a0.z; op[3 * outsz] = a0.w;
            op = opb + 16 + m16;
            op[0] = a1.x; op[outsz] = a1.y; op[2 * outsz] = a1.z; op[3 * outsz] = a1.w;
        }
        if (32 + m16 < DW) {
            float* op = opb + 32 + m16;
            op[0] = a2.x; op[outsz] = a2.y; op[2 * outsz] = a2.z; op[3 * outsz] = a2.w;
        }
    }
}

// ---------------------------------------------------------------------------
// Convert k0/v0 fp32 -> MFMA-tiled bf16x2 (round-15 exact).
// grid (136, 16 nh), block 256.
__global__ __launch_bounds__(256) void k_cvt(const float* __restrict__ k0,
                                             const float* __restrict__ v0,
                                             unsigned short* __restrict__ Kb,
                                             unsigned short* __restrict__ Vb) {
    __shared__ float sm[272];            // 16x16 transpose pad 17
    int bx = blockIdx.x, nh = blockIdx.y;
    int n = nh >> 2, h = nh & 3;
    int t = threadIdx.x;
    int c = t >> 4, d = t & 15;
    int dgl = bx * 16 + d;
    float kv = (dgl < DD) ? k0[(size_t)(n * CIN + h * HC + c) * DD + dgl] : 0.f;
    sm[c * 17 + d] = kv;
    __syncthreads();
    {
        int d2 = t >> 4, c2 = t & 15;
        float v = sm[c2 * 17 + d2];
        unsigned u = __builtin_bit_cast(unsigned, v);
        unsigned short* dst = Kb + (size_t)(nh * NT + bx) * 512;
        dst[t] = (unsigned short)(u >> 16);
        float lo = v - __builtin_bit_cast(float, u & 0xffff0000u);
        dst[256 + t] = (unsigned short)(__builtin_bit_cast(unsigned, lo) >> 16);
    }
    {
        float vv = (dgl < DD) ? v0[(size_t)(n * CIN + h * HC + c) * DD + dgl] : 0.f;
        unsigned u = __builtin_bit_cast(unsigned, vv);
        unsigned short* dst = Vb + (size_t)(nh * NT + bx) * 512;
        dst[t] = (unsigned short)(u >> 16);
        float lo = vv - __builtin_bit_cast(float, u & 0xffff0000u);
        dst[256 + t] = (unsigned short)(__builtin_bit_cast(unsigned, lo) >> 16);
    }
}

// ---------------------------------------------------------------------------
// MFMA attention (round-15 exact: NT=136, 17 iters). grid (72, 16), block 256.
__global__ __launch_bounds__(256) void k_mattn(const unsigned short* __restrict__ Qb,
                                               const unsigned short* __restrict__ Kb,
                                               const unsigned short* __restrict__ Vb,
                                               float* __restrict__ part) {
    __shared__ float sO[4][4][256];
    __shared__ float sl[4][4][64];
    int strip = blockIdx.x >> 1, hb = blockIdx.x & 1, nh = blockIdx.y;
    int lane = threadIdx.x & 63, wv = threadIdx.x >> 6;
    int ds = hb * 4 + wv;
    int q16 = lane & 15, quad = lane >> 4;
    int foff = q16 * 16 + quad * 4;

    s4 qh[4], ql[4];
    #pragma unroll
    for (int j = 0; j < 4; ++j) {
        const unsigned short* Qp = Qb + (size_t)(nh * QTL + strip * 4 + j) * 512 + foff;
        qh[j] = *(const s4*)(Qp);
        ql[j] = *(const s4*)(Qp + 256);
    }
    f4 O[4];
    float l[4];
    #pragma unroll
    for (int j = 0; j < 4; ++j) { O[j] = (f4){0.f, 0.f, 0.f, 0.f}; l[j] = 0.f; }

    const unsigned short* Kp = Kb + (size_t)(nh * NT + ds * 17) * 512 + foff;
    const unsigned short* Vp = Vb + (size_t)(nh * NT + ds * 17) * 512 + foff;
    s4 khi = *(const s4*)(Kp);
    s4 klo = *(const s4*)(Kp + 256);
    s4 vhi = *(const s4*)(Vp);
    s4 vlo = *(const s4*)(Vp + 256);

    for (int it = 0; it < 17; ++it) {
        int nxt = (it < 16) ? (it + 1) * 512 : 0;
        s4 nkhi = *(const s4*)(Kp + nxt);
        s4 nklo = *(const s4*)(Kp + nxt + 256);
        s4 nvhi = *(const s4*)(Vp + nxt);
        s4 nvlo = *(const s4*)(Vp + nxt + 256);

        #pragma unroll
        for (int j = 0; j < 4; ++j) {
            f4 c1 = (f4){0.f, 0.f, 0.f, 0.f};
            c1 = __builtin_amdgcn_mfma_f32_16x16x16bf16_1k(khi, qh[j], c1, 0, 0, 0);
            c1 = __builtin_amdgcn_mfma_f32_16x16x16bf16_1k(klo, qh[j], c1, 0, 0, 0);
            c1 = __builtin_amdgcn_mfma_f32_16x16x16bf16_1k(khi, ql[j], c1, 0, 0, 0);
            float p0 = __expf(c1.x), p1 = __expf(c1.y);
            float p2 = __expf(c1.z), p3 = __expf(c1.w);
            l[j] += (p0 + p1) + (p2 + p3);
            unsigned u0 = __builtin_bit_cast(unsigned, p0);
            unsigned u1 = __builtin_bit_cast(unsigned, p1);
            unsigned u2 = __builtin_bit_cast(unsigned, p2);
            unsigned u3 = __builtin_bit_cast(unsigned, p3);
            s4 ph;
            ph.x = (short)(u0 >> 16); ph.y = (short)(u1 >> 16);
            ph.z = (short)(u2 >> 16); ph.w = (short)(u3 >> 16);
            float r0 = p0 - __builtin_bit_cast(float, u0 & 0xffff0000u);
            float r1 = p1 - __builtin_bit_cast(float, u1 & 0xffff0000u);
            float r2 = p2 - __builtin_bit_cast(float, u2 & 0xffff0000u);
            float r3 = p3 - __builtin_bit_cast(float, u3 & 0xffff0000u);
            s4 pl;
            pl.x = (short)(__builtin_bit_cast(unsigned, r0) >> 16);
            pl.y = (short)(__builtin_bit_cast(unsigned, r1) >> 16);
            pl.z = (short)(__builtin_bit_cast(unsigned, r2) >> 16);
            pl.w = (short)(__builtin_bit_cast(unsigned, r3) >> 16);
            O[j] = __builtin_amdgcn_mfma_f32_16x16x16bf16_1k(vhi, ph, O[j], 0, 0, 0);
            O[j] = __builtin_amdgcn_mfma_f32_16x16x16bf16_1k(vlo, ph, O[j], 0, 0, 0);
            O[j] = __builtin_amdgcn_mfma_f32_16x16x16bf16_1k(vhi, pl, O[j], 0, 0, 0);
        }
        khi = nkhi; klo = nklo; vhi = nvhi; vlo = nvlo;
    }

    #pragma unroll
    for (int j = 0; j < 4; ++j) {
        sO[wv][j][(quad * 4 + 0) * 16 + q16] = O[j].x;
        sO[wv][j][(quad * 4 + 1) * 16 + q16] = O[j].y;
        sO[wv][j][(quad * 4 + 2) * 16 + q16] = O[j].z;
        sO[wv][j][(quad * 4 + 3) * 16 + q16] = O[j].w;
        sl[wv][j][quad * 16 + q16] = l[j];
    }
    __syncthreads();
    int t = threadIdx.x;
    float* pb = part + (size_t)((nh * 36 + strip) * 2 + hb) * 1280;
    #pragma unroll
    for (int j = 0; j < 4; ++j)
        pb[j * 256 + t] = (sO[0][j][t] + sO[1][j][t]) + (sO[2][j][t] + sO[3][j][t]);
    {
        int j2 = t >> 6, i2 = t & 63;
        pb[1024 + t] = (sl[0][j2][i2] + sl[1][j2][i2]) + (sl[2][j2][i2] + sl[3][j2][i2]);
    }
}

// ---------------------------------------------------------------------------
// Gates + LSTM + output 1x1 conv, fused with attention combine (-60) and
// constant-gate projection (a2m holds SUMS; scale by 1/2116 here).
__global__ __launch_bounds__(256) void k_gates(const float* __restrict__ part,
                                               const float* __restrict__ a2m,
                                               const float* __restrict__ Wproj,
                                               const float* __restrict__ bg,
                                               const float* __restrict__ Wout,
                                               const float* __restrict__ bout,
                                               float* __restrict__ out) {
    __shared__ float a0s[64][16];
    __shared__ float wps[3][64][64];   // [gi][c][o]
    __shared__ float hs[16][68];
    __shared__ float invs[4][16];      // [h][px] softmax denominators
    __shared__ float c2s[3][64];       // constant gate pre-activations
    int n = blockIdx.y;
    int pt = blockIdx.x;
    int strip = pt >> 2, jq = pt & 3;
    int p0 = pt * 16;
    int tid = threadIdx.x;

    if (tid < 64) {                    // denominators
        int h = tid >> 4, q = tid & 15;
        const float* b0 = part + (size_t)(((n * 4 + h) * 36 + strip) * 2) * 1280;
        const float* b1 = b0 + 1280;
        float s = 0.f;
        #pragma unroll
        for (int quad = 0; quad < 4; ++quad)
            s += b0[1024 + jq * 64 + quad * 16 + q] + b1[1024 + jq * 64 + quad * 16 + q];
        invs[h][q] = 1.f / (s - 60.f);
    } else {                           // constant gates
        int gi = (tid - 64) >> 6, o = tid & 63;
        int g = (gi == 0) ? 0 : (gi == 1) ? 2 : 3;
        float acc = bg[g * CIN + o];
        const float* wp = Wproj + ((size_t)(g * 4 + 2) * CIN + o) * CIN;
        const float* am = a2m + n * CIN;
        #pragma unroll 8
        for (int c = 0; c < CIN; ++c) acc += wp[c] * (am[c] * (1.f / 2116.f));
        c2s[gi][o] = acc;
    }
    __syncthreads();

    for (int idx = tid; idx < 1024; idx += 256) {   // a0 tile from part
        int c = idx >> 4, px = idx & 15;
        int h = c >> 4, c16 = c & 15;
        const float* b0 = part + (size_t)(((n * 4 + h) * 36 + strip) * 2) * 1280;
        const float* b1 = b0 + 1280;
        int off = jq * 256 + c16 * 16 + px;
        a0s[c][px] = (b0[off] + b1[off]) * invs[h][px];
    }
    for (int idx = tid; idx < 12288; idx += 256) {
        int o = idx & 63; int rest = idx >> 6; int c = rest & 63; int gi = rest >> 6;
        int g = (gi == 0) ? 0 : (gi == 1) ? 2 : 3;
        wps[gi][c][o] = Wproj[((size_t)(g * 4 + 0) * CIN + o) * CIN + c];
    }
    __syncthreads();

    int o = tid & 63, pg = tid >> 6;
    float pi[4], pgt[4], po[4];
    {
        float ci = c2s[0][o], cg = c2s[1][o], co = c2s[2][o];
        #pragma unroll
        for (int j = 0; j < 4; ++j) { pi[j] = ci; pgt[j] = cg; po[j] = co; }
    }
    const float4* a4 = (const float4*)&a0s[0][0];
    #pragma unroll 4
    for (int c = 0; c < 64; ++c) {
        float4 av = a4[c * 4 + pg];
        float w0 = wps[0][c][o], w1 = wps[1][c][o], w2 = wps[2][c][o];
        pi[0]  += w0 * av.x; pi[1]  += w0 * av.y; pi[2]  += w0 * av.z; pi[3]  += w0 * av.w;
        pgt[0] += w1 * av.x; pgt[1] += w1 * av.y; pgt[2] += w1 * av.z; pgt[3] += w1 * av.w;
        po[0]  += w2 * av.x; po[1]  += w2 * av.y; po[2]  += w2 * av.z; po[3]  += w2 * av.w;
    }
    #pragma unroll
    for (int j = 0; j < 4; ++j) {
        float ii = 1.f / (1.f + __expf(-pi[j]));
        float gg = tanhf(pgt[j]);
        float oo = 1.f / (1.f + __expf(-po[j]));
        float cc = ii * gg;
        hs[pg * 4 + j][o] = oo * tanhf(cc);
    }
    __syncthreads();
    float acc[4];
    float bo = bout[o];
    #pragma unroll
    for (int j = 0; j < 4; ++j) acc[j] = bo;
    const float* wo = Wout + o * CIN;
    #pragma unroll 2
    for (int cg_ = 0; cg_ < 16; ++cg_) {
        float w0 = wo[cg_ * 4 + 0], w1 = wo[cg_ * 4 + 1], w2 = wo[cg_ * 4 + 2], w3 = wo[cg_ * 4 + 3];
        #pragma unroll
        for (int j = 0; j < 4; ++j) {
            const float4 hv = *(const float4*)&hs[pg * 4 + j][cg_ * 4];
            acc[j] += w0 * hv.x + w1 * hv.y + w2 * hv.z + w3 * hv.w;
        }
    }
    #pragma unroll
    for (int j = 0; j < 4; ++j)
        out[(size_t)(n * CIN + o) * HW + p0 + pg * 4 + j] = acc[j];
}

// ---------------------------------------------------------------------------
extern "C" void kernel_launch(void* const* d_in, const int* in_sizes, int n_in,
                              void* d_out, int out_size, void* d_ws, size_t ws_size,
                              hipStream_t stream) {
    const float* x     = (const float*)d_in[0];
    const float* W_in  = (const float*)d_in[1];
    const float* b_in  = (const float*)d_in[2];
    const float* Wq    = (const float*)d_in[3];
    const float* Wk    = (const float*)d_in[4];
    const float* Wv    = (const float*)d_in[5];
    const float* Wproj = (const float*)d_in[6];
    const float* b_g   = (const float*)d_in[7];
    const float* W_out = (const float*)d_in[8];
    const float* b_out = (const float*)d_in[9];
    float* out = (float*)d_out;

    float* k0   = (float*)d_ws;          // 541696
    float* v0   = k0 + 541696;           // 541696
    float* a2m  = v0 + 541696;           // 256
    float* part = a2m + 256;             // 16*36*2*1280 = 1474560
    unsigned short* Qb = (unsigned short*)(part + 1474560);  // 16*144*512
    unsigned short* Kb = Qb + (size_t)16 * QTL * 512;        // 16*136*512
    unsigned short* Vb = Kb + (size_t)16 * NT * 512;         // 16*136*512
    unsigned short* xb = Vb + (size_t)16 * NT * 512;         // 4*16*2500*8
    unsigned short* Wb = xb + (size_t)4 * 16 * 2500 * 8;     // 16*9*4*512
    // total ~23 MB of workspace

    k_xw    <<<dim3(785), 256, 0, stream>>>(x, W_in, b_in, Wq, Wk, Wv, xb, Wb, a2m);
    k_conv  <<<dim3(48, 4, 4), 256, 0, stream>>>(xb, Wb, Qb, k0, v0, a2m);
    k_cvt   <<<dim3(136, 16), 256, 0, stream>>>(k0, v0, Kb, Vb);
    k_mattn <<<dim3(72, 16), 256, 0, stream>>>(Qb, Kb, Vb, part);
    k_gates <<<dim3(144, 4), 256, 0, stream>>>(part, a2m, Wproj, b_g, W_out, b_out, out);
}